// Round 6
// baseline (807.893 us; speedup 1.0000x reference)
//
#include <hip/hip_runtime.h>
#include <math.h>

// ---------------------------------------------------------------------------
// MoE layer, round 13.
// R12 profile: gemm_gu_g 195us @ MfmaUtil 49 / VALUBusy 38 / bank-conflict
// 1.68e7; stage->barrier drains vmcnt(0) with zero compute to hide it (m233).
// Changes:
//  1. gu/dn: T3 minimum-2-phase: double-buffered LDS (64KB), stage k+1 BEFORE
//     computing k, ONE barrier per k-step. Plain __syncthreads (loads have the
//     MFMA phase to land before the drain).
//  2. chunk swizzle f(r): (r&3) -> ((r>>1)&3). Old left rows r,r+4 on same
//     banks (4-way, 1.58x); new gives exact 2-way = free (m136).
//  3. MODE4 RMW eliminated algebraically: out += 0.1*(adpre*wsum)@(Wd@Wap)^T
//     folded into the final K=256 concat GEMM (hw2=[hw|adpreS],
//     Mb2=[Mb|WdWap]). Removes 128MB of hidden RMW traffic.
// B=4, S=2048, D=1024, H=2048, A=128, E=8, N=8192.
// ---------------------------------------------------------------------------

typedef __bf16 bf16_t;
typedef __attribute__((ext_vector_type(8))) __bf16 bf16x8;
typedef __attribute__((ext_vector_type(4))) float f32x4;

__device__ __forceinline__ float b2f(bf16_t v) { return (float)v; }
__device__ __forceinline__ bf16_t f2b(float v) { return (bf16_t)v; }
__device__ __forceinline__ float siluf(float v) { return v / (1.f + expf(-v)); }

static constexpr int Bb = 4, S = 2048, D = 1024, H = 2048, A = 128, E = 8;
static constexpr int N = Bb * S;

// async global->LDS, 16B per lane; LDS dest = wave-uniform base + lane*16
typedef __attribute__((address_space(1))) void gvoid;
typedef __attribute__((address_space(3))) void svoid;
__device__ __forceinline__ void gll16(const bf16_t* g, bf16_t* l) {
  __builtin_amdgcn_global_load_lds((gvoid*)g, (svoid*)l, 16, 0, 0);
}

// tiled-chunk element index: layout [R/TR][K/32][TR][4 chunks x 8]
// chunk slot p holds source chunk q = p ^ ((r>>1)&3)  (XOR involution; 2-way
// bank aliasing only -- rows r, r+8 alias, which is free on 32-bank LDS)
__device__ __forceinline__ long tidx(int row, int k, int K, int lgTR) {
  int TRm = (1 << lgTR) - 1;
  int q = (k >> 3) & 3;
  int p = q ^ ((row >> 1) & 3);
  return ((((long)(row >> lgTR) * (K >> 5) + (k >> 5)) << lgTR) + (row & TRm)) * 32 +
         ((long)p << 3);
}

// 8 consecutive f32 -> bf16 (plain round)
__device__ __forceinline__ bf16x8 ld8f(const float* p) {
  float4 a = *reinterpret_cast<const float4*>(p);
  float4 b = *reinterpret_cast<const float4*>(p + 4);
  bf16x8 r;
  r[0] = f2b(a.x); r[1] = f2b(a.y); r[2] = f2b(a.z); r[3] = f2b(a.w);
  r[4] = f2b(b.x); r[5] = f2b(b.y); r[6] = f2b(b.z); r[7] = f2b(b.w);
  return r;
}
// 8 consecutive f32 -> hi/lo bf16 split
__device__ __forceinline__ void split8(const float* p, bf16x8& h, bf16x8& l) {
  float4 a = *reinterpret_cast<const float4*>(p);
  float4 b = *reinterpret_cast<const float4*>(p + 4);
  float v[8] = {a.x, a.y, a.z, a.w, b.x, b.y, b.z, b.w};
#pragma unroll
  for (int j = 0; j < 8; j++) {
    bf16_t hh = f2b(v[j]);
    h[j] = hh;
    l[j] = f2b(v[j] - b2f(hh));
  }
}
// staging loader: 0 = bf16 row-major, 1 = f32 row-major, 2 = tiled bf16 TR=128
__device__ __forceinline__ bf16x8 ld8m(const void* p, int row, int k, int K, int m) {
  if (m == 1) return ld8f(reinterpret_cast<const float*>(p) + (long)row * K + k);
  if (m == 2)
    return *reinterpret_cast<const bf16x8*>(
        reinterpret_cast<const bf16_t*>(p) + tidx(row, k, K, 7));
  return *reinterpret_cast<const bf16x8*>(
      reinterpret_cast<const bf16_t*>(p) + (long)row * K + k);
}

// ---------------------------------------------------------------------------
// f32 -> hi/lo bf16 split into TILED chunk-swizzled layout.
// ---------------------------------------------------------------------------
template <int LGTR, int LGNKS>
__global__ __launch_bounds__(256) void split_tiled(
    const float* __restrict__ in, bf16_t* __restrict__ hi,
    bf16_t* __restrict__ lo, long total, int K) {
  long stride = (long)gridDim.x * 256;
  for (long o = (long)blockIdx.x * 256 + threadIdx.x; o < total; o += stride) {
    int p = (int)(o & 3);
    long t = o >> 2;
    int r = (int)(t & ((1 << LGTR) - 1));
    long t2 = t >> LGTR;
    int ks = (int)(t2 & ((1 << LGNKS) - 1));
    long rt = t2 >> LGNKS;
    long row = (rt << LGTR) + r;
    int k = (ks << 5) + ((p ^ ((r >> 1) & 3)) << 3);
    bf16x8 h, l;
    split8(in + row * K + k, h, l);
    reinterpret_cast<bf16x8*>(hi)[o] = h;
    reinterpret_cast<bf16x8*>(lo)[o] = l;
  }
}

// ---------------------------------------------------------------------------
// Plain-bf16 NT GEMM (verified layout).
// MODE: 0 bf16 store; 1 silu(clip(v,-5,5)) bf16; 2 f32 RMW C += 0.1*v;
//       3 f32 RMW C = C*aux[row] + 0.1*v
// ---------------------------------------------------------------------------
template <int WM, int WN, int MODE>
__global__ __launch_bounds__(256) void gemm_nt_b(
    const void* __restrict__ Ag, const void* __restrict__ Bg,
    void* __restrict__ Cv, int M, int Nn, int K,
    const float* __restrict__ aux, int aF, int bF) {
  constexpr int BM = 2 * WM, BN = 2 * WN, AM = WM / 16, AN = WN / 16;
  constexpr int LDT = 40;
  __shared__ alignas(16) bf16_t As[BM * LDT];
  __shared__ alignas(16) bf16_t Bs[BN * LDT];

  const int tid = threadIdx.x;
  const int wave = tid >> 6, lane = tid & 63;
  const int wr = wave >> 1, wc = wave & 1;
  const int quad = lane >> 4, l16 = lane & 15;
  const int rowA0 = blockIdx.y * BM, rowB0 = blockIdx.x * BN;

  f32x4 acc[AM][AN] = {};

  for (int k0 = 0; k0 < K; k0 += 32) {
    for (int c = tid; c < BM * 4; c += 256) {
      int r = c >> 2, kc = c & 3;
      *reinterpret_cast<bf16x8*>(&As[r * LDT + kc * 8]) =
          ld8m(Ag, rowA0 + r, k0 + kc * 8, K, aF);
    }
    for (int c = tid; c < BN * 4; c += 256) {
      int r = c >> 2, kc = c & 3;
      *reinterpret_cast<bf16x8*>(&Bs[r * LDT + kc * 8]) =
          ld8m(Bg, rowB0 + r, k0 + kc * 8, K, bF);
    }
    __syncthreads();
    bf16x8 af[AM], bfv[AN];
#pragma unroll
    for (int i = 0; i < AM; i++)
      af[i] = *reinterpret_cast<bf16x8*>(&As[(wr * WM + i * 16 + l16) * LDT + quad * 8]);
#pragma unroll
    for (int j = 0; j < AN; j++)
      bfv[j] = *reinterpret_cast<bf16x8*>(&Bs[(wc * WN + j * 16 + l16) * LDT + quad * 8]);
#pragma unroll
    for (int i = 0; i < AM; i++)
#pragma unroll
      for (int j = 0; j < AN; j++)
        acc[i][j] = __builtin_amdgcn_mfma_f32_16x16x32_bf16(af[i], bfv[j], acc[i][j], 0, 0, 0);
    __syncthreads();
  }

  // C/D: col = lane&15, row = quad*4 + reg
#pragma unroll
  for (int i = 0; i < AM; i++)
#pragma unroll
    for (int j = 0; j < AN; j++)
#pragma unroll
      for (int r = 0; r < 4; r++) {
        int row = rowA0 + wr * WM + i * 16 + quad * 4 + r;
        int col = rowB0 + wc * WN + j * 16 + l16;
        long o = (long)row * Nn + col;
        float v = acc[i][j][r];
        if constexpr (MODE == 0) {
          reinterpret_cast<bf16_t*>(Cv)[o] = f2b(v);
        } else if constexpr (MODE == 1) {
          v = fminf(fmaxf(v, -5.f), 5.f);
          reinterpret_cast<bf16_t*>(Cv)[o] = f2b(siluf(v));
        } else if constexpr (MODE == 2) {
          float* C = reinterpret_cast<float*>(Cv);
          C[o] = C[o] + 0.1f * v;
        } else {
          float* C = reinterpret_cast<float*>(Cv);
          C[o] = C[o] * aux[row] + 0.1f * v;
        }
      }
}

// ---------------------------------------------------------------------------
// Fused gate/up, TILED inputs, gll16 staging, 2-phase double-buffer.
// ---------------------------------------------------------------------------
__global__ __launch_bounds__(256) void gemm_gu_g(
    const bf16_t* __restrict__ xhT, const bf16_t* __restrict__ xlT,
    const bf16_t* __restrict__ WghT, const bf16_t* __restrict__ WglT,
    const bf16_t* __restrict__ WuhT, const bf16_t* __restrict__ WulT,
    bf16_t* __restrict__ Hh, bf16_t* __restrict__ Hl) {
  __shared__ alignas(16) bf16_t Ah[2][128 * 32];
  __shared__ alignas(16) bf16_t Al[2][128 * 32];
  __shared__ alignas(16) bf16_t B1h[2][64 * 32];
  __shared__ alignas(16) bf16_t B1l[2][64 * 32];
  __shared__ alignas(16) bf16_t B2h[2][64 * 32];
  __shared__ alignas(16) bf16_t B2l[2][64 * 32];

  const int tid = threadIdx.x;
  const int wave = tid >> 6, lane = tid & 63;
  const int wr = wave >> 1, wc = wave & 1;
  const int quad = lane >> 4, l16 = lane & 15;
  const int sw = (quad ^ ((l16 >> 1) & 3)) << 3;
  const int bm = blockIdx.y, bn = blockIdx.x;
  constexpr int nks = D / 32;
  const int wo = wave << 9;

  auto stage = [&](int buf, int ks) {
    long ao = (((long)bm * nks + ks) << 12) + wo + lane * 8;
    long bo = (((long)bn * nks + ks) << 11) + wo + lane * 8;
    gll16(xhT + ao, &Ah[buf][wo]);
    gll16(xhT + ao + 2048, &Ah[buf][wo + 2048]);
    gll16(xlT + ao, &Al[buf][wo]);
    gll16(xlT + ao + 2048, &Al[buf][wo + 2048]);
    gll16(WghT + bo, &B1h[buf][wo]);
    gll16(WglT + bo, &B1l[buf][wo]);
    gll16(WuhT + bo, &B2h[buf][wo]);
    gll16(WulT + bo, &B2l[buf][wo]);
  };

  f32x4 ag[4][2] = {}, au[4][2] = {};

  stage(0, 0);
  __syncthreads();
  int cur = 0;
  for (int ks = 0; ks < nks; ks++) {
    if (ks + 1 < nks) stage(cur ^ 1, ks + 1);  // issue next tile's loads
    bf16x8 afh[4], afl[4], b1h[2], b1l[2], b2h[2], b2l[2];
#pragma unroll
    for (int i = 0; i < 4; i++) {
      int ro = (wr * 64 + i * 16 + l16) * 32 + sw;
      afh[i] = *reinterpret_cast<bf16x8*>(&Ah[cur][ro]);
      afl[i] = *reinterpret_cast<bf16x8*>(&Al[cur][ro]);
    }
#pragma unroll
    for (int j = 0; j < 2; j++) {
      int ro = (wc * 32 + j * 16 + l16) * 32 + sw;
      b1h[j] = *reinterpret_cast<bf16x8*>(&B1h[cur][ro]);
      b1l[j] = *reinterpret_cast<bf16x8*>(&B1l[cur][ro]);
      b2h[j] = *reinterpret_cast<bf16x8*>(&B2h[cur][ro]);
      b2l[j] = *reinterpret_cast<bf16x8*>(&B2l[cur][ro]);
    }
#pragma unroll
    for (int i = 0; i < 4; i++)
#pragma unroll
      for (int j = 0; j < 2; j++) {
        ag[i][j] = __builtin_amdgcn_mfma_f32_16x16x32_bf16(afh[i], b1h[j], ag[i][j], 0, 0, 0);
        ag[i][j] = __builtin_amdgcn_mfma_f32_16x16x32_bf16(afh[i], b1l[j], ag[i][j], 0, 0, 0);
        ag[i][j] = __builtin_amdgcn_mfma_f32_16x16x32_bf16(afl[i], b1h[j], ag[i][j], 0, 0, 0);
        au[i][j] = __builtin_amdgcn_mfma_f32_16x16x32_bf16(afh[i], b2h[j], au[i][j], 0, 0, 0);
        au[i][j] = __builtin_amdgcn_mfma_f32_16x16x32_bf16(afh[i], b2l[j], au[i][j], 0, 0, 0);
        au[i][j] = __builtin_amdgcn_mfma_f32_16x16x32_bf16(afl[i], b2h[j], au[i][j], 0, 0, 0);
      }
    __syncthreads();  // drains this iter's stage (landed under MFMA) + fences reads
    cur ^= 1;
  }

#pragma unroll
  for (int i = 0; i < 4; i++)
#pragma unroll
    for (int j = 0; j < 2; j++)
#pragma unroll
      for (int r = 0; r < 4; r++) {
        int row = bm * 128 + wr * 64 + i * 16 + quad * 4 + r;
        int col = bn * 64 + wc * 32 + j * 16 + l16;
        long o = tidx(row, col, H, 7) + (col & 7);
        float v = siluf(ag[i][j][r]) * au[i][j][r];
        bf16_t hh = f2b(v);
        Hh[o] = hh;
        Hl[o] = f2b(v - b2f(hh));
      }
}

// ---------------------------------------------------------------------------
// Down-proj, TILED inputs, gll16 staging, 2-phase double-buffer.
// ---------------------------------------------------------------------------
__global__ __launch_bounds__(256) void gemm_dn_g(
    const bf16_t* __restrict__ HhT, const bf16_t* __restrict__ HlT,
    const bf16_t* __restrict__ WdhT, const bf16_t* __restrict__ WdlT,
    float* __restrict__ Cg) {
  __shared__ alignas(16) bf16_t Ah[2][128 * 32];
  __shared__ alignas(16) bf16_t Al[2][128 * 32];
  __shared__ alignas(16) bf16_t Bh[2][128 * 32];
  __shared__ alignas(16) bf16_t Bl[2][128 * 32];

  const int tid = threadIdx.x;
  const int wave = tid >> 6, lane = tid & 63;
  const int wr = wave >> 1, wc = wave & 1;
  const int quad = lane >> 4, l16 = lane & 15;
  const int sw = (quad ^ ((l16 >> 1) & 3)) << 3;
  const int by = blockIdx.y, bx = blockIdx.x;
  constexpr int nks = H / 32;
  const int wo = wave << 9;

  auto stage = [&](int buf, int ks) {
    long ao = (((long)by * nks + ks) << 12) + wo + lane * 8;
    long bo = (((long)bx * nks + ks) << 12) + wo + lane * 8;
    gll16(HhT + ao, &Ah[buf][wo]);
    gll16(HhT + ao + 2048, &Ah[buf][wo + 2048]);
    gll16(HlT + ao, &Al[buf][wo]);
    gll16(HlT + ao + 2048, &Al[buf][wo + 2048]);
    gll16(WdhT + bo, &Bh[buf][wo]);
    gll16(WdhT + bo + 2048, &Bh[buf][wo + 2048]);
    gll16(WdlT + bo, &Bl[buf][wo]);
    gll16(WdlT + bo + 2048, &Bl[buf][wo + 2048]);
  };

  f32x4 acc[4][4] = {};

  stage(0, 0);
  __syncthreads();
  int cur = 0;
  for (int ks = 0; ks < nks; ks++) {
    if (ks + 1 < nks) stage(cur ^ 1, ks + 1);
    bf16x8 afh[4], afl[4], bfh[4], bfl[4];
#pragma unroll
    for (int i = 0; i < 4; i++) {
      int ro = (wr * 64 + i * 16 + l16) * 32 + sw;
      afh[i] = *reinterpret_cast<bf16x8*>(&Ah[cur][ro]);
      afl[i] = *reinterpret_cast<bf16x8*>(&Al[cur][ro]);
    }
#pragma unroll
    for (int j = 0; j < 4; j++) {
      int ro = (wc * 64 + j * 16 + l16) * 32 + sw;
      bfh[j] = *reinterpret_cast<bf16x8*>(&Bh[cur][ro]);
      bfl[j] = *reinterpret_cast<bf16x8*>(&Bl[cur][ro]);
    }
#pragma unroll
    for (int i = 0; i < 4; i++)
#pragma unroll
      for (int j = 0; j < 4; j++) {
        acc[i][j] = __builtin_amdgcn_mfma_f32_16x16x32_bf16(afh[i], bfh[j], acc[i][j], 0, 0, 0);
        acc[i][j] = __builtin_amdgcn_mfma_f32_16x16x32_bf16(afh[i], bfl[j], acc[i][j], 0, 0, 0);
        acc[i][j] = __builtin_amdgcn_mfma_f32_16x16x32_bf16(afl[i], bfh[j], acc[i][j], 0, 0, 0);
      }
    __syncthreads();
    cur ^= 1;
  }

#pragma unroll
  for (int i = 0; i < 4; i++)
#pragma unroll
    for (int j = 0; j < 4; j++)
#pragma unroll
      for (int r = 0; r < 4; r++) {
        int row = by * 128 + wr * 64 + i * 16 + quad * 4 + r;
        int col = bx * 128 + wc * 64 + j * 16 + l16;
        Cg[(long)row * D + col] = acc[i][j][r];
      }
}

// ---------------------------------------------------------------------------
// Fused adapt attention: outp[token][oOff+col] = (silu(clip(ai@ao^T))@ai)
//   * (wsum ? wsum[token] : 1)   -- scaled form feeds the K=256 concat GEMM.
// ---------------------------------------------------------------------------
__global__ __launch_bounds__(256) void fused_adapt(
    const bf16_t* __restrict__ aib, const bf16_t* __restrict__ aob,
    const bf16_t* __restrict__ aiT, bf16_t* __restrict__ outp,
    int oLd, int oOff, const float* __restrict__ wsum) {
  constexpr int LDQ = 136;
  constexpr int LDP = 72;
  __shared__ alignas(16) bf16_t Qs[64 * LDQ];
  __shared__ alignas(16) bf16_t Os[64 * LDQ];
  __shared__ alignas(16) bf16_t Ps[64 * LDP];
  __shared__ alignas(16) bf16_t Vs[128 * LDP];

  const int tid = threadIdx.x;
  const int wave = tid >> 6, lane = tid & 63;
  const int wr = wave >> 1, wc = wave & 1;
  const int quad = lane >> 4, l16 = lane & 15;
  const int b = blockIdx.y;
  const int q0 = blockIdx.x * 64;

  for (int c = tid; c < 1024; c += 256) {
    int r = c >> 4, cc = c & 15;
    *reinterpret_cast<bf16x8*>(&Qs[r * LDQ + cc * 8]) =
        *reinterpret_cast<const bf16x8*>(&aib[((long)b * S + q0 + r) * A + cc * 8]);
  }

  f32x4 o[2][4] = {};

  for (int tt = 0; tt < S / 64; tt++) {
    const int t0 = tt * 64;
    __syncthreads();
    for (int c = tid; c < 1024; c += 256) {
      int r = c >> 4, cc = c & 15;
      *reinterpret_cast<bf16x8*>(&Os[r * LDQ + cc * 8]) =
          *reinterpret_cast<const bf16x8*>(&aob[((long)b * S + t0 + r) * A + cc * 8]);
    }
    for (int c = tid; c < 1024; c += 256) {
      int r = c >> 3, cc = c & 7;
      *reinterpret_cast<bf16x8*>(&Vs[r * LDP + cc * 8]) =
          *reinterpret_cast<const bf16x8*>(&aiT[((long)b * A + r) * S + t0 + cc * 8]);
    }
    __syncthreads();
    f32x4 p[2][2] = {};
#pragma unroll
    for (int ks = 0; ks < 4; ks++) {
      bf16x8 af[2], bfv[2];
#pragma unroll
      for (int i = 0; i < 2; i++)
        af[i] = *reinterpret_cast<bf16x8*>(&Qs[(wr * 32 + i * 16 + l16) * LDQ + ks * 32 + quad * 8]);
#pragma unroll
      for (int j = 0; j < 2; j++)
        bfv[j] = *reinterpret_cast<bf16x8*>(&Os[(wc * 32 + j * 16 + l16) * LDQ + ks * 32 + quad * 8]);
#pragma unroll
      for (int i = 0; i < 2; i++)
#pragma unroll
        for (int j = 0; j < 2; j++)
          p[i][j] = __builtin_amdgcn_mfma_f32_16x16x32_bf16(af[i], bfv[j], p[i][j], 0, 0, 0);
    }
#pragma unroll
    for (int i = 0; i < 2; i++)
#pragma unroll
      for (int j = 0; j < 2; j++)
#pragma unroll
        for (int r = 0; r < 4; r++) {
          int row = wr * 32 + i * 16 + quad * 4 + r;
          int col = wc * 32 + j * 16 + l16;
          float v = fminf(fmaxf(p[i][j][r], -5.f), 5.f);
          Ps[row * LDP + col] = f2b(siluf(v));
        }
    __syncthreads();
#pragma unroll
    for (int ks = 0; ks < 2; ks++) {
      bf16x8 paf[2], vbf[4];
#pragma unroll
      for (int i = 0; i < 2; i++)
        paf[i] = *reinterpret_cast<bf16x8*>(&Ps[(wr * 32 + i * 16 + l16) * LDP + ks * 32 + quad * 8]);
#pragma unroll
      for (int j = 0; j < 4; j++)
        vbf[j] = *reinterpret_cast<bf16x8*>(&Vs[(wc * 64 + j * 16 + l16) * LDP + ks * 32 + quad * 8]);
#pragma unroll
      for (int i = 0; i < 2; i++)
#pragma unroll
        for (int j = 0; j < 4; j++)
          o[i][j] = __builtin_amdgcn_mfma_f32_16x16x32_bf16(paf[i], vbf[j], o[i][j], 0, 0, 0);
    }
  }

#pragma unroll
  for (int i = 0; i < 2; i++)
#pragma unroll
    for (int j = 0; j < 4; j++)
#pragma unroll
      for (int r = 0; r < 4; r++) {
        int row = q0 + wr * 32 + i * 16 + quad * 4 + r;
        int col = wc * 64 + j * 16 + l16;
        long token = (long)b * S + row;
        float sc = wsum ? wsum[token] : 1.f;
        outp[token * oLd + oOff + col] = f2b(o[i][j][r] * sc);
      }
}

// ---------------------------------------------------------------------------
// [D,A] = Af32 @ Bbf16^T, split-K x8 into f32 partials (Mb and WdWap).
// ---------------------------------------------------------------------------
__global__ __launch_bounds__(256) void gemm_mb_splitk(
    const float* __restrict__ Ag, const bf16_t* __restrict__ Bg,
    float* __restrict__ Mp, int M, int Nn, int K) {
  constexpr int BM = 64, BN = 64, LDT = 40;
  __shared__ alignas(16) bf16_t As[BM * LDT];
  __shared__ alignas(16) bf16_t Bs[BN * LDT];
  const int tid = threadIdx.x;
  const int wave = tid >> 6, lane = tid & 63;
  const int wr = wave >> 1, wc = wave & 1;
  const int quad = lane >> 4, l16 = lane & 15;
  const int rowA0 = blockIdx.y * BM, rowB0 = blockIdx.x * BN;
  const int kz = blockIdx.z;
  const int ks0 = kz * (K / 8), ks1 = ks0 + K / 8;

  f32x4 acc[2][2] = {};
  for (int k0 = ks0; k0 < ks1; k0 += 32) {
    for (int c = tid; c < BM * 4; c += 256) {
      int r = c >> 2, kc = c & 3;
      *reinterpret_cast<bf16x8*>(&As[r * LDT + kc * 8]) =
          ld8f(Ag + (long)(rowA0 + r) * K + k0 + kc * 8);
    }
    for (int c = tid; c < BN * 4; c += 256) {
      int r = c >> 2, kc = c & 3;
      *reinterpret_cast<bf16x8*>(&Bs[r * LDT + kc * 8]) =
          *reinterpret_cast<const bf16x8*>(&Bg[(long)(rowB0 + r) * K + k0 + kc * 8]);
    }
    __syncthreads();
    bf16x8 af[2], bfv[2];
#pragma unroll
    for (int i = 0; i < 2; i++)
      af[i] = *reinterpret_cast<bf16x8*>(&As[(wr * 32 + i * 16 + l16) * LDT + quad * 8]);
#pragma unroll
    for (int j = 0; j < 2; j++)
      bfv[j] = *reinterpret_cast<bf16x8*>(&Bs[(wc * 32 + j * 16 + l16) * LDT + quad * 8]);
#pragma unroll
    for (int i = 0; i < 2; i++)
#pragma unroll
      for (int j = 0; j < 2; j++)
        acc[i][j] = __builtin_amdgcn_mfma_f32_16x16x32_bf16(af[i], bfv[j], acc[i][j], 0, 0, 0);
    __syncthreads();
  }
#pragma unroll
  for (int i = 0; i < 2; i++)
#pragma unroll
    for (int j = 0; j < 2; j++)
#pragma unroll
      for (int r = 0; r < 4; r++) {
        int row = rowA0 + wr * 32 + i * 16 + quad * 4 + r;
        int col = rowB0 + wc * 32 + j * 16 + l16;
        Mp[(long)kz * M * Nn + (long)row * Nn + col] = acc[i][j][r];
      }
}

// combine partials into strided bf16 destination: out[(i>>7)*ld + coff + (i&127)]
__global__ __launch_bounds__(256) void mb_combine(
    const float* __restrict__ Mp, bf16_t* __restrict__ outp, int total,
    int ld, int coff) {
  int i = blockIdx.x * 256 + threadIdx.x;
  if (i >= total) return;
  float s = 0.f;
#pragma unroll
  for (int z = 0; z < 8; z++) s += Mp[(long)z * total + i];
  outp[(long)(i >> 7) * ld + coff + (i & 127)] = f2b(s);
}

// ---------------------------------------------------------------------------
// Fallback-path kernels (f32 inputs, in-loop split) — unchanged, proven.
// ---------------------------------------------------------------------------
__global__ __launch_bounds__(256) void gemm_dn_hl(
    const float* __restrict__ Ag, const float* __restrict__ Bg,
    float* __restrict__ Cg, int M, int Nn, int K) {
  constexpr int BM = 128, BN = 128, LDT = 40;
  __shared__ alignas(16) bf16_t Ah[BM * LDT];
  __shared__ alignas(16) bf16_t Al[BM * LDT];
  __shared__ alignas(16) bf16_t Bh[BN * LDT];
  __shared__ alignas(16) bf16_t Bl[BN * LDT];

  const int tid = threadIdx.x;
  const int wave = tid >> 6, lane = tid & 63;
  const int wr = wave >> 1, wc = wave & 1;
  const int quad = lane >> 4, l16 = lane & 15;
  const int rowA0 = blockIdx.y * BM, rowB0 = blockIdx.x * BN;

  f32x4 acc[4][4] = {};

  for (int k0 = 0; k0 < K; k0 += 32) {
    for (int c = tid; c < BM * 4; c += 256) {
      int r = c >> 2, kc = c & 3;
      bf16x8 h, l;
      split8(&Ag[(long)(rowA0 + r) * K + k0 + kc * 8], h, l);
      *reinterpret_cast<bf16x8*>(&Ah[r * LDT + kc * 8]) = h;
      *reinterpret_cast<bf16x8*>(&Al[r * LDT + kc * 8]) = l;
    }
    for (int c = tid; c < BN * 4; c += 256) {
      int r = c >> 2, kc = c & 3;
      bf16x8 h, l;
      split8(&Bg[(long)(rowB0 + r) * K + k0 + kc * 8], h, l);
      *reinterpret_cast<bf16x8*>(&Bh[r * LDT + kc * 8]) = h;
      *reinterpret_cast<bf16x8*>(&Bl[r * LDT + kc * 8]) = l;
    }
    __syncthreads();
    bf16x8 afh[4], afl[4], bfh[4], bfl[4];
#pragma unroll
    for (int i = 0; i < 4; i++) {
      int ro = (wr * 64 + i * 16 + l16) * LDT + quad * 8;
      afh[i] = *reinterpret_cast<bf16x8*>(&Ah[ro]);
      afl[i] = *reinterpret_cast<bf16x8*>(&Al[ro]);
    }
#pragma unroll
    for (int j = 0; j < 4; j++) {
      int ro = (wc * 64 + j * 16 + l16) * LDT + quad * 8;
      bfh[j] = *reinterpret_cast<bf16x8*>(&Bh[ro]);
      bfl[j] = *reinterpret_cast<bf16x8*>(&Bl[ro]);
    }
#pragma unroll
    for (int i = 0; i < 4; i++)
#pragma unroll
      for (int j = 0; j < 4; j++) {
        acc[i][j] = __builtin_amdgcn_mfma_f32_16x16x32_bf16(afh[i], bfh[j], acc[i][j], 0, 0, 0);
        acc[i][j] = __builtin_amdgcn_mfma_f32_16x16x32_bf16(afh[i], bfl[j], acc[i][j], 0, 0, 0);
        acc[i][j] = __builtin_amdgcn_mfma_f32_16x16x32_bf16(afl[i], bfh[j], acc[i][j], 0, 0, 0);
      }
    __syncthreads();
  }

#pragma unroll
  for (int i = 0; i < 4; i++)
#pragma unroll
    for (int j = 0; j < 4; j++)
#pragma unroll
      for (int r = 0; r < 4; r++) {
        int row = rowA0 + wr * 64 + i * 16 + quad * 4 + r;
        int col = rowB0 + wc * 64 + j * 16 + l16;
        Cg[(long)row * Nn + col] = acc[i][j][r];
      }
}

__global__ __launch_bounds__(256) void gemm_gu_hl(
    const float* __restrict__ x, const float* __restrict__ Wg,
    const float* __restrict__ Wu, float* __restrict__ Cg, int M, int Nn, int K) {
  constexpr int BM = 128, BN = 64, LDT = 40;
  __shared__ alignas(16) bf16_t Ah[BM * LDT];
  __shared__ alignas(16) bf16_t Al[BM * LDT];
  __shared__ alignas(16) bf16_t B1h[BN * LDT];
  __shared__ alignas(16) bf16_t B1l[BN * LDT];
  __shared__ alignas(16) bf16_t B2h[BN * LDT];
  __shared__ alignas(16) bf16_t B2l[BN * LDT];

  const int tid = threadIdx.x;
  const int wave = tid >> 6, lane = tid & 63;
  const int wr = wave >> 1, wc = wave & 1;
  const int quad = lane >> 4, l16 = lane & 15;
  const int rowA0 = blockIdx.y * BM, rowB0 = blockIdx.x * BN;

  f32x4 ag[4][2] = {}, au[4][2] = {};

  for (int k0 = 0; k0 < K; k0 += 32) {
    for (int c = tid; c < BM * 4; c += 256) {
      int r = c >> 2, kc = c & 3;
      bf16x8 h, l;
      split8(&x[(long)(rowA0 + r) * K + k0 + kc * 8], h, l);
      *reinterpret_cast<bf16x8*>(&Ah[r * LDT + kc * 8]) = h;
      *reinterpret_cast<bf16x8*>(&Al[r * LDT + kc * 8]) = l;
    }
    for (int c = tid; c < BN * 4; c += 256) {
      int r = c >> 2, kc = c & 3;
      long idx = (long)(rowB0 + r) * K + k0 + kc * 8;
      bf16x8 h, l;
      split8(&Wg[idx], h, l);
      *reinterpret_cast<bf16x8*>(&B1h[r * LDT + kc * 8]) = h;
      *reinterpret_cast<bf16x8*>(&B1l[r * LDT + kc * 8]) = l;
      split8(&Wu[idx], h, l);
      *reinterpret_cast<bf16x8*>(&B2h[r * LDT + kc * 8]) = h;
      *reinterpret_cast<bf16x8*>(&B2l[r * LDT + kc * 8]) = l;
    }
    __syncthreads();
    bf16x8 afh[4], afl[4], b1h[2], b1l[2], b2h[2], b2l[2];
#pragma unroll
    for (int i = 0; i < 4; i++) {
      int ro = (wr * 64 + i * 16 + l16) * LDT + quad * 8;
      afh[i] = *reinterpret_cast<bf16x8*>(&Ah[ro]);
      afl[i] = *reinterpret_cast<bf16x8*>(&Al[ro]);
    }
#pragma unroll
    for (int j = 0; j < 2; j++) {
      int ro = (wc * 32 + j * 16 + l16) * LDT + quad * 8;
      b1h[j] = *reinterpret_cast<bf16x8*>(&B1h[ro]);
      b1l[j] = *reinterpret_cast<bf16x8*>(&B1l[ro]);
      b2h[j] = *reinterpret_cast<bf16x8*>(&B2h[ro]);
      b2l[j] = *reinterpret_cast<bf16x8*>(&B2l[ro]);
    }
#pragma unroll
    for (int i = 0; i < 4; i++)
#pragma unroll
      for (int j = 0; j < 2; j++) {
        ag[i][j] = __builtin_amdgcn_mfma_f32_16x16x32_bf16(afh[i], b1h[j], ag[i][j], 0, 0, 0);
        ag[i][j] = __builtin_amdgcn_mfma_f32_16x16x32_bf16(afh[i], b1l[j], ag[i][j], 0, 0, 0);
        ag[i][j] = __builtin_amdgcn_mfma_f32_16x16x32_bf16(afl[i], b1h[j], ag[i][j], 0, 0, 0);
        au[i][j] = __builtin_amdgcn_mfma_f32_16x16x32_bf16(afh[i], b2h[j], au[i][j], 0, 0, 0);
        au[i][j] = __builtin_amdgcn_mfma_f32_16x16x32_bf16(afh[i], b2l[j], au[i][j], 0, 0, 0);
        au[i][j] = __builtin_amdgcn_mfma_f32_16x16x32_bf16(afl[i], b2h[j], au[i][j], 0, 0, 0);
      }
    __syncthreads();
  }

#pragma unroll
  for (int i = 0; i < 4; i++)
#pragma unroll
    for (int j = 0; j < 2; j++)
#pragma unroll
      for (int r = 0; r < 4; r++) {
        int row = rowA0 + wr * 64 + i * 16 + quad * 4 + r;
        int col = rowB0 + wc * 32 + j * 16 + l16;
        Cg[(long)row * Nn + col] = siluf(ag[i][j][r]) * au[i][j][r];
      }
}

// ---------------------------------------------------------------------------
// Router (no global atomics, per-block partials).
// ---------------------------------------------------------------------------
__global__ __launch_bounds__(256) void router_kernel(
    const float* __restrict__ x, const float* __restrict__ Wgr,
    const float* __restrict__ Wer, int* __restrict__ eidx,
    float* __restrict__ fw, float* __restrict__ wsum,
    float* __restrict__ lpart) {
  __shared__ float part[4][12];
  const int wv = threadIdx.x >> 6;
  const int lane = threadIdx.x & 63;
  const int token = blockIdx.x * 4 + wv;
  if (lane < 12) part[wv][lane] = 0.f;
  const float* xp = x + (long)token * D;
  float xr[16];
#pragma unroll
  for (int i = 0; i < 16; i++) xr[i] = xp[lane + i * 64];
  float dots[6];
#pragma unroll
  for (int w = 0; w < 6; w++) {
    const float* wp = (w < 2) ? (Wgr + (long)w * D) : (Wer + (long)(w - 2) * D);
    float s = 0.f;
#pragma unroll
    for (int i = 0; i < 16; i++) s += xr[i] * wp[lane + i * 64];
#pragma unroll
    for (int off = 32; off; off >>= 1) s += __shfl_xor(s, off);
    dots[w] = s;
  }
  if (lane == 0) {
    float gl0 = dots[0], gl1 = dots[1];
    float mg = fmaxf(gl0, gl1);
    float e0 = expf(gl0 - mg), e1 = expf(gl1 - mg);
    float inv = 1.f / (e0 + e1);
    float gp0 = e0 * inv, gp1 = e1 * inv;
    int gi = (gp1 > gp0) ? 1 : 0;
    float gw = gi ? gp1 : gp0;
    float el[4] = {dots[2], dots[3], dots[4], dots[5]};
    float me = fmaxf(fmaxf(el[0], el[1]), fmaxf(el[2], el[3]));
    float ep[4], es = 0.f;
#pragma unroll
    for (int j = 0; j < 4; j++) { ep[j] = expf(el[j] - me); es += ep[j]; }
    float inve = 1.f / es;
#pragma unroll
    for (int j = 0; j < 4; j++) ep[j] *= inve;
    int i1 = 0;
    for (int j = 1; j < 4; j++) if (ep[j] > ep[i1]) i1 = j;
    int i2 = (i1 == 0) ? 1 : 0;
    for (int j = 0; j < 4; j++) if (j != i1 && j != i2 && ep[j] > ep[i2]) i2 = j;
    float l1 = ep[i1], l2 = ep[i2];
    float ils = 1.f / (l1 + l2 + 1e-7f);
    float f1 = gw * l1 * ils, f2 = gw * l2 * ils;
    eidx[token * 2] = gi * 4 + i1;
    eidx[token * 2 + 1] = gi * 4 + i2;
    fw[token * 2] = f1;
    fw[token * 2 + 1] = f2;
    wsum[token] = f1 + f2;
    part[wv][gi * 4 + i1] = f1;
    part[wv][gi * 4 + i2] = f2;
    part[wv][8] = gl0 * gl0 + gl1 * gl1;
    part[wv][9] = el[0] * el[0] + el[1] * el[1] + el[2] * el[2] + el[3] * el[3];
  }
  __syncthreads();
  if (threadIdx.x < 12) {
    lpart[(long)blockIdx.x * 12 + threadIdx.x] =
        part[0][threadIdx.x] + part[1][threadIdx.x] +
        part[2][threadIdx.x] + part[3][threadIdx.x];
  }
}

// ---------------------------------------------------------------------------
// Row LayerNorm over A=128 (bf16 in ws, f32 g/b, bf16 out).
// ---------------------------------------------------------------------------
__global__ __launch_bounds__(256) void ln_rows(
    const bf16_t* __restrict__ in, const float* __restrict__ g,
    const float* __restrict__ b, bf16_t* __restrict__ out) {
  const int row = blockIdx.x * 4 + (threadIdx.x >> 6);
  const int lane = threadIdx.x & 63;
  const bf16_t* p = in + (long)row * A;
  float x0 = b2f(p[lane]), x1 = b2f(p[lane + 64]);
  float s = x0 + x1;
#pragma unroll
  for (int off = 32; off; off >>= 1) s += __shfl_xor(s, off);
  float mean = s * (1.f / 128.f);
  float d0 = x0 - mean, d1 = x1 - mean;
  float q = d0 * d0 + d1 * d1;
#pragma unroll
  for (int off = 32; off; off >>= 1) q += __shfl_xor(q, off);
  float r = rsqrtf(q * (1.f / 128.f) + 1e-5f);
  bf16_t* po = out + (long)row * A;
  po[lane] = f2b(d0 * r * g[lane] + b[lane]);
  po[lane + 64] = f2b(d1 * r * g[lane + 64] + b[lane + 64]);
}

// ---------------------------------------------------------------------------
// Transpose [z,R,C] -> [z,C,R], bf16 out; input f32 (isf=1) or bf16.
// ---------------------------------------------------------------------------
__global__ __launch_bounds__(256) void transpose2d(
    const void* __restrict__ in, bf16_t* __restrict__ out, int R, int C, int isf) {
  __shared__ bf16_t t[32][33];
  const long zb = blockIdx.z;
  const long ib = zb * (long)R * C;
  bf16_t* op = out + zb * (long)R * C;
  const int r0 = blockIdx.y * 32, c0 = blockIdx.x * 32;
  const int tx = threadIdx.x & 31, ty = threadIdx.x >> 5;
#pragma unroll
  for (int i = 0; i < 4; i++) {
    long idx = ib + (long)(r0 + ty + i * 8) * C + c0 + tx;
    t[ty + i * 8][tx] = isf ? f2b(reinterpret_cast<const float*>(in)[idx])
                            : reinterpret_cast<const bf16_t*>(in)[idx];
  }
  __syncthreads();
#pragma unroll
  for (int i = 0; i < 4; i++) op[(long)(c0 + ty + i * 8) * R + r0 + tx] = t[tx][ty + i * 8];
}

// ---------------------------------------------------------------------------
// Expert branch: coalesced via pre-transposed WeaT[e][a][c] (bf16).
// Writes into hw2 row stride ld (cols 0..127).
// ---------------------------------------------------------------------------
__global__ __launch_bounds__(128) void expert_adapt(
    const bf16_t* __restrict__ h0, const bf16_t* __restrict__ WeaT,
    const float* __restrict__ ln_eg, const float* __restrict__ ln_eb,
    const int* __restrict__ eidx, const float* __restrict__ fw,
    bf16_t* __restrict__ hw, int ld) {
  const int n = blockIdx.x;
  const int c = threadIdx.x;
  __shared__ float h0s[128];
  __shared__ float red[4];
  h0s[c] = b2f(h0[(long)n * A + c]);
  __syncthreads();
  float out = 0.f;
  for (int k = 0; k < 2; k++) {
    int e = eidx[n * 2 + k];
    e = min(max(e, 0), E - 1);
    float w = fw[n * 2 + k];
    const bf16_t* Wc = WeaT + (long)e * A * A + c;
    float t = 0.f;
#pragma unroll 8
    for (int a = 0; a < 128; a++) t += b2f(Wc[(long)a * A]) * h0s[a];
    float s = t, q = t * t;
#pragma unroll
    for (int off = 32; off; off >>= 1) { s += __shfl_xor(s, off); q += __shfl_xor(q, off); }
    if ((c & 63) == 0) { red[(c >> 6) * 2] = s; red[(c >> 6) * 2 + 1] = q; }
    __syncthreads();
    float Sx = red[0] + red[2], Qx = red[1] + red[3];
    float mean = Sx * (1.f / 128.f);
    float var = Qx * (1.f / 128.f) - mean * mean;
    float r = rsqrtf(var + 1e-5f);
    out += w * ((t - mean) * r * ln_eg[e * A + c] + ln_eb[e * A + c]);
    __syncthreads();
  }
  hw[(long)n * ld + c] = f2b(out);
}

// ---------------------------------------------------------------------------
// Loss finalize.
// ---------------------------------------------------------------------------
__global__ __launch_bounds__(256) void finalize_loss(
    const float* __restrict__ lpart, int nblk, float* __restrict__ outv) {
  float acc[10] = {};
  for (int b = threadIdx.x; b < nblk; b += 256) {
    const float* p = lpart + (long)b * 12;
#pragma unroll
    for (int c = 0; c < 10; c++) acc[c] += p[c];
  }
  __shared__ float red[10][4];
  const int lane = threadIdx.x & 63, wv = threadIdx.x >> 6;
#pragma unroll
  for (int c = 0; c < 10; c++) {
    float s = acc[c];
#pragma unroll
    for (int off = 32; off; off >>= 1) s += __shfl_xor(s, off);
    if (lane == 0) red[c][wv] = s;
  }
  __syncthreads();
  if (threadIdx.x == 0) {
    float loss[10];
#pragma unroll
    for (int c = 0; c < 10; c++)
      loss[c] = red[c][0] + red[c][1] + red[c][2] + red[c][3];
    float tl = 0.f;
    for (int e = 0; e < 8; e++) tl += loss[e];
    float target = tl / 8.f;
    float mse = 0.f;
    for (int e = 0; e < 8; e++) { float d = loss[e] - target; mse += d * d; }
    mse *= (1.f / 8.f);
    outv[0] = 0.001f * (mse + loss[8] / (float)(N * 2) + loss[9] / (float)(N * 4));
  }
}

// ---------------------------------------------------------------------------
extern "C" void kernel_launch(void* const* d_in, const int* in_sizes, int n_in,
                              void* d_out, int out_size, void* d_ws, size_t ws_size,
                              hipStream_t stream) {
  const float* x = (const float*)d_in[0];
  const float* Wu = (const float*)d_in[1];
  const float* Wg = (const float*)d_in[2];
  const float* Wd = (const float*)d_in[3];
  const float* Wpre = (const float*)d_in[4];
  const float* Wpost = (const float*)d_in[5];
  const float* ln_g = (const float*)d_in[6];
  const float* ln_b = (const float*)d_in[7];
  const float* Wap = (const float*)d_in[8];
  const float* Wea = (const float*)d_in[9];
  const float* ln_eg = (const float*)d_in[10];
  const float* ln_eb = (const float*)d_in[11];
  const float* Wep = (const float*)d_in[12];
  const float* Wop = (const float*)d_in[13];
  const float* Wgr = (const float*)d_in[14];
  const float* Wer = (const float*)d_in[15];
  float* out = (float*)d_out;

  char* ws = (char*)d_ws;
  size_t off = 0;
  auto alloc = [&](size_t bytes) { char* p = ws + off; off += (bytes + 255) & ~size_t(255); return p; };
  // Common allocations (~18 MB)
  float* lpart = (float*)alloc((size_t)(N / 4) * 12 * 4);
  float* wsum = (float*)alloc((size_t)N * 4);
  float* fwb = (float*)alloc((size_t)N * 2 * 4);
  int* eidx = (int*)alloc((size_t)N * 2 * 4);
  bf16_t* Mb2 = (bf16_t*)alloc((size_t)D * 256 * 2);   // [D,256] = [Mb | WdWap]
  float* Mp = (float*)alloc((size_t)8 * D * A * 4);    // split-K partials (reused)
  bf16_t* WepT = (bf16_t*)alloc((size_t)H * A * 2);
  bf16_t* WapT = (bf16_t*)alloc((size_t)H * A * 2);
  bf16_t* hw2 = (bf16_t*)alloc((size_t)N * 256 * 2);   // [N,256] = [hw | adpreS]
  bf16_t* h0b = (bf16_t*)alloc((size_t)N * A * 2);
  bf16_t* aib = (bf16_t*)alloc((size_t)N * A * 2);
  bf16_t* scrA = (bf16_t*)alloc((size_t)N * A * 2);
  bf16_t* aob = (bf16_t*)alloc((size_t)N * A * 2);
  bf16_t* WeaT = (bf16_t*)alloc((size_t)E * A * A * 2);
  bf16_t* aopre = scrA;
  bf16_t* aiT = scrA;

  // Big path: pre-split TILED hi/lo buffers (+120 MB; total ~138.5 MiB).
  const bool big = ws_size >= ((size_t)140 << 20);
  float* hiddenF = nullptr;
  bf16_t *xh = nullptr, *xl = nullptr;
  bf16_t *Wgh = nullptr, *Wgl = nullptr, *Wuh = nullptr, *Wul = nullptr;
  bf16_t *Wdh = nullptr, *Wdl = nullptr, *Hh = nullptr, *Hl = nullptr;
  if (big) {
    xh = (bf16_t*)alloc((size_t)N * D * 2);
    xl = (bf16_t*)alloc((size_t)N * D * 2);
    Wgh = (bf16_t*)alloc((size_t)H * D * 2);
    Wgl = (bf16_t*)alloc((size_t)H * D * 2);
    Wuh = (bf16_t*)alloc((size_t)H * D * 2);
    Wul = (bf16_t*)alloc((size_t)H * D * 2);
    Wdh = (bf16_t*)alloc((size_t)D * H * 2);
    Wdl = (bf16_t*)alloc((size_t)D * H * 2);
    Hh = (bf16_t*)alloc((size_t)N * H * 2);
    Hl = (bf16_t*)alloc((size_t)N * H * 2);
  } else {
    hiddenF = (float*)alloc((size_t)N * H * 4);
  }
  (void)ws_size; (void)in_sizes; (void)n_in; (void)out_size;

  const dim3 blk(256);

  router_kernel<<<dim3(N / 4), blk, 0, stream>>>(x, Wgr, Wer, eidx, fwb, wsum, lpart);
  transpose2d<<<dim3(A / 32, A / 32, E), blk, 0, stream>>>(Wea, WeaT, A, A, 1);

  if (big) {
    // tiled splits: x TR=128 K=D; Wg/Wu TR=64 K=D; Wd TR=128 K=H
    split_tiled<7, 5><<<dim3(2048), blk, 0, stream>>>(x, xh, xl, (long)N * D / 8, D);
    split_tiled<6, 5><<<dim3(512), blk, 0, stream>>>(Wg, Wgh, Wgl, (long)H * D / 8, D);
    split_tiled<6, 5><<<dim3(512), blk, 0, stream>>>(Wu, Wuh, Wul, (long)H * D / 8, D);
    split_tiled<7, 6><<<dim3(512), blk, 0, stream>>>(Wd, Wdh, Wdl, (long)D * H / 8, H);
    // hidden0 (tiled Hh/Hl) = silu(x@Wg^T)*(x@Wu^T)
    gemm_gu_g<<<dim3(H / 64, N / 128), blk, 0, stream>>>(
        xh, xl, Wgh, Wgl, Wuh, Wul, Hh, Hl);
    // h0 = x@Wpre^T  (A from tiled xh)
    gemm_nt_b<16, 32, 0><<<dim3(A / 64, N / 32), blk, 0, stream>>>(
        xh, Wpre, h0b, N, A, D, nullptr, 2, 1);
    ln_rows<<<dim3(N / 4), blk, 0, stream>>>(h0b, ln_g, ln_b, aib);
    // ao_pre = hidden0@Wpost^T (pre-adapt hidden, matches reference)
    gemm_nt_b<16, 32, 0><<<dim3(A / 64, N / 32), blk, 0, stream>>>(
        Hh, Wpost, aopre, N, A, H, nullptr, 2, 1);
    ln_rows<<<dim3(N / 4), blk, 0, stream>>>(aopre, ln_g, ln_b, aob);
    transpose2d<<<dim3(A / 32, S / 32, Bb), blk, 0, stream>>>(aib, aiT, S, A, 0);
    // adpreS = wsum * (silu(clip(ai@ao^T)) @ ai) -> hw2 cols 128..255
    fused_adapt<<<dim3(S / 64, Bb), blk, 0, stream>>>(
        aib, aob, aiT, hw2, 256, 128, wsum);
    // out = hidden0@Wd^T (adapt contribution folded into final GEMM)
    gemm_dn_g<<<dim3(D / 128, N / 128), blk, 0, stream>>>(Hh, Hl, Wdh, Wdl, out);
    // Mb2 = [Wop@Wep | Wd@Wap]
    transpose2d<<<dim3(A / 32, H / 32, 1), blk, 0, stream>>>(Wep, WepT, H, A, 1);
    transpose2d<<<dim3(A / 32, H / 32, 1), blk, 0, stream>>>(Wap, WapT, H, A, 1);
    gemm_mb_splitk<<<dim3(A / 64, D / 64, 8), blk, 0, stream>>>(Wop, WepT, Mp, D, A, H);
    mb_combine<<<dim3((D * A + 255) / 256), blk, 0, stream>>>(Mp, Mb2, D * A, 256, 0);
    gemm_mb_splitk<<<dim3(A / 64, D / 64, 8), blk, 0, stream>>>(Wd, WapT, Mp, D, A, H);
    mb_combine<<<dim3((D * A + 255) / 256), blk, 0, stream>>>(Mp, Mb2, D * A, 256, 128);
    // hw -> hw2 cols 0..127
    expert_adapt<<<dim3(N), dim3(128), 0, stream>>>(
        h0b, WeaT, ln_eg, ln_eb, eidx, fwb, hw2, 256);
    // out = out*wsum + 0.1*(hw@Mb^T + adpreS@WdWap^T)   K=256 concat
    gemm_nt_b<64, 64, 3><<<dim3(D / 128, N / 128), blk, 0, stream>>>(
        hw2, Mb2, out, N, D, 256, wsum, 0, 0);
  } else {
    bf16_t* adpreb = hw2 + (size_t)N * A;  // second half of hw2 as [N,A]
    gemm_gu_hl<<<dim3(H / 64, N / 128), blk, 0, stream>>>(x, Wg, Wu, hiddenF, N, H, D);
    gemm_nt_b<16, 32, 0><<<dim3(A / 64, N / 32), blk, 0, stream>>>(
        x, Wpre, h0b, N, A, D, nullptr, 1, 1);
    ln_rows<<<dim3(N / 4), blk, 0, stream>>>(h0b, ln_g, ln_b, aib);
    gemm_nt_b<16, 32, 0><<<dim3(A / 64, N / 32), blk, 0, stream>>>(
        hiddenF, Wpost, aopre, N, A, H, nullptr, 1, 1);
    ln_rows<<<dim3(N / 4), blk, 0, stream>>>(aopre, ln_g, ln_b, aob);
    transpose2d<<<dim3(A / 32, S / 32, Bb), blk, 0, stream>>>(aib, aiT, S, A, 0);
    fused_adapt<<<dim3(S / 64, Bb), blk, 0, stream>>>(
        aib, aob, aiT, adpreb, 128, 0, nullptr);
    gemm_nt_b<64, 64, 2><<<dim3(H / 128, N / 128), blk, 0, stream>>>(
        adpreb, Wap, hiddenF, N, H, A, nullptr, 0, 1);
    gemm_dn_hl<<<dim3(D / 128, N / 128), blk, 0, stream>>>(hiddenF, Wd, out, N, D, H);
    transpose2d<<<dim3(A / 32, H / 32, 1), blk, 0, stream>>>(Wep, WepT, H, A, 1);
    gemm_mb_splitk<<<dim3(A / 64, D / 64, 8), blk, 0, stream>>>(Wop, WepT, Mp, D, A, H);
    mb_combine<<<dim3((D * A + 255) / 256), blk, 0, stream>>>(Mp, Mb2, D * A, 128, 0);
    expert_adapt<<<dim3(N), dim3(128), 0, stream>>>(
        h0b, WeaT, ln_eg, ln_eb, eidx, fwb, hw2, 128);
    gemm_nt_b<64, 64, 3><<<dim3(D / 128, N / 128), blk, 0, stream>>>(
        hw2, Mb2, out, N, D, A, wsum, 0, 0);
  }

  finalize_loss<<<dim3(1), blk, 0, stream>>>(lpart, N / 4, out + (size_t)N * D);
}

// Round 7
// 772.878 us; speedup vs baseline: 1.0453x; 1.0453x over previous
//
#include <hip/hip_runtime.h>
#include <math.h>

// ---------------------------------------------------------------------------
// MoE layer, round 14 = R13 with the gu/dn buffering REVERTED to R12's
// single-buffer schedule.
// R13 post-mortem: 2-phase dbuf doubled LDS 32->64KB, cutting blocks/CU 5->2;
// MfmaUtil 49->39, gu 195->233us. Inter-block TLP (m114) was already hiding
// the stage drain; explicit dbuf at the 2-barrier structure is null-to-neg
// (m99/m100) and here traded away cross-block hiding. KEPT from R13:
//  - zero-conflict chunk swizzle (r>>1)&3  (SQ_LDS_BANK_CONFLICT -> 0)
//  - MODE4 RMW eliminated algebraically (out += 0.1*(adpre*wsum)@(Wd@Wap)^T
//    folded into final K=256 concat GEMM)
// B=4, S=2048, D=1024, H=2048, A=128, E=8, N=8192.
// ---------------------------------------------------------------------------

typedef __bf16 bf16_t;
typedef __attribute__((ext_vector_type(8))) __bf16 bf16x8;
typedef __attribute__((ext_vector_type(4))) float f32x4;

__device__ __forceinline__ float b2f(bf16_t v) { return (float)v; }
__device__ __forceinline__ bf16_t f2b(float v) { return (bf16_t)v; }
__device__ __forceinline__ float siluf(float v) { return v / (1.f + expf(-v)); }

static constexpr int Bb = 4, S = 2048, D = 1024, H = 2048, A = 128, E = 8;
static constexpr int N = Bb * S;

// async global->LDS, 16B per lane; LDS dest = wave-uniform base + lane*16
typedef __attribute__((address_space(1))) void gvoid;
typedef __attribute__((address_space(3))) void svoid;
__device__ __forceinline__ void gll16(const bf16_t* g, bf16_t* l) {
  __builtin_amdgcn_global_load_lds((gvoid*)g, (svoid*)l, 16, 0, 0);
}

// tiled-chunk element index: layout [R/TR][K/32][TR][4 chunks x 8]
// chunk slot p holds source chunk q = p ^ ((r>>1)&3)  (XOR involution; 2-way
// bank aliasing only -- free on 32-bank LDS, m136)
__device__ __forceinline__ long tidx(int row, int k, int K, int lgTR) {
  int TRm = (1 << lgTR) - 1;
  int q = (k >> 3) & 3;
  int p = q ^ ((row >> 1) & 3);
  return ((((long)(row >> lgTR) * (K >> 5) + (k >> 5)) << lgTR) + (row & TRm)) * 32 +
         ((long)p << 3);
}

// 8 consecutive f32 -> bf16 (plain round)
__device__ __forceinline__ bf16x8 ld8f(const float* p) {
  float4 a = *reinterpret_cast<const float4*>(p);
  float4 b = *reinterpret_cast<const float4*>(p + 4);
  bf16x8 r;
  r[0] = f2b(a.x); r[1] = f2b(a.y); r[2] = f2b(a.z); r[3] = f2b(a.w);
  r[4] = f2b(b.x); r[5] = f2b(b.y); r[6] = f2b(b.z); r[7] = f2b(b.w);
  return r;
}
// 8 consecutive f32 -> hi/lo bf16 split
__device__ __forceinline__ void split8(const float* p, bf16x8& h, bf16x8& l) {
  float4 a = *reinterpret_cast<const float4*>(p);
  float4 b = *reinterpret_cast<const float4*>(p + 4);
  float v[8] = {a.x, a.y, a.z, a.w, b.x, b.y, b.z, b.w};
#pragma unroll
  for (int j = 0; j < 8; j++) {
    bf16_t hh = f2b(v[j]);
    h[j] = hh;
    l[j] = f2b(v[j] - b2f(hh));
  }
}
// staging loader: 0 = bf16 row-major, 1 = f32 row-major, 2 = tiled bf16 TR=128
__device__ __forceinline__ bf16x8 ld8m(const void* p, int row, int k, int K, int m) {
  if (m == 1) return ld8f(reinterpret_cast<const float*>(p) + (long)row * K + k);
  if (m == 2)
    return *reinterpret_cast<const bf16x8*>(
        reinterpret_cast<const bf16_t*>(p) + tidx(row, k, K, 7));
  return *reinterpret_cast<const bf16x8*>(
      reinterpret_cast<const bf16_t*>(p) + (long)row * K + k);
}

// ---------------------------------------------------------------------------
// f32 -> hi/lo bf16 split into TILED chunk-swizzled layout.
// ---------------------------------------------------------------------------
template <int LGTR, int LGNKS>
__global__ __launch_bounds__(256) void split_tiled(
    const float* __restrict__ in, bf16_t* __restrict__ hi,
    bf16_t* __restrict__ lo, long total, int K) {
  long stride = (long)gridDim.x * 256;
  for (long o = (long)blockIdx.x * 256 + threadIdx.x; o < total; o += stride) {
    int p = (int)(o & 3);
    long t = o >> 2;
    int r = (int)(t & ((1 << LGTR) - 1));
    long t2 = t >> LGTR;
    int ks = (int)(t2 & ((1 << LGNKS) - 1));
    long rt = t2 >> LGNKS;
    long row = (rt << LGTR) + r;
    int k = (ks << 5) + ((p ^ ((r >> 1) & 3)) << 3);
    bf16x8 h, l;
    split8(in + row * K + k, h, l);
    reinterpret_cast<bf16x8*>(hi)[o] = h;
    reinterpret_cast<bf16x8*>(lo)[o] = l;
  }
}

// ---------------------------------------------------------------------------
// Plain-bf16 NT GEMM (verified layout).
// MODE: 0 bf16 store; 1 silu(clip(v,-5,5)) bf16; 2 f32 RMW C += 0.1*v;
//       3 f32 RMW C = C*aux[row] + 0.1*v
// ---------------------------------------------------------------------------
template <int WM, int WN, int MODE>
__global__ __launch_bounds__(256) void gemm_nt_b(
    const void* __restrict__ Ag, const void* __restrict__ Bg,
    void* __restrict__ Cv, int M, int Nn, int K,
    const float* __restrict__ aux, int aF, int bF) {
  constexpr int BM = 2 * WM, BN = 2 * WN, AM = WM / 16, AN = WN / 16;
  constexpr int LDT = 40;
  __shared__ alignas(16) bf16_t As[BM * LDT];
  __shared__ alignas(16) bf16_t Bs[BN * LDT];

  const int tid = threadIdx.x;
  const int wave = tid >> 6, lane = tid & 63;
  const int wr = wave >> 1, wc = wave & 1;
  const int quad = lane >> 4, l16 = lane & 15;
  const int rowA0 = blockIdx.y * BM, rowB0 = blockIdx.x * BN;

  f32x4 acc[AM][AN] = {};

  for (int k0 = 0; k0 < K; k0 += 32) {
    for (int c = tid; c < BM * 4; c += 256) {
      int r = c >> 2, kc = c & 3;
      *reinterpret_cast<bf16x8*>(&As[r * LDT + kc * 8]) =
          ld8m(Ag, rowA0 + r, k0 + kc * 8, K, aF);
    }
    for (int c = tid; c < BN * 4; c += 256) {
      int r = c >> 2, kc = c & 3;
      *reinterpret_cast<bf16x8*>(&Bs[r * LDT + kc * 8]) =
          ld8m(Bg, rowB0 + r, k0 + kc * 8, K, bF);
    }
    __syncthreads();
    bf16x8 af[AM], bfv[AN];
#pragma unroll
    for (int i = 0; i < AM; i++)
      af[i] = *reinterpret_cast<bf16x8*>(&As[(wr * WM + i * 16 + l16) * LDT + quad * 8]);
#pragma unroll
    for (int j = 0; j < AN; j++)
      bfv[j] = *reinterpret_cast<bf16x8*>(&Bs[(wc * WN + j * 16 + l16) * LDT + quad * 8]);
#pragma unroll
    for (int i = 0; i < AM; i++)
#pragma unroll
      for (int j = 0; j < AN; j++)
        acc[i][j] = __builtin_amdgcn_mfma_f32_16x16x32_bf16(af[i], bfv[j], acc[i][j], 0, 0, 0);
    __syncthreads();
  }

  // C/D: col = lane&15, row = quad*4 + reg
#pragma unroll
  for (int i = 0; i < AM; i++)
#pragma unroll
    for (int j = 0; j < AN; j++)
#pragma unroll
      for (int r = 0; r < 4; r++) {
        int row = rowA0 + wr * WM + i * 16 + quad * 4 + r;
        int col = rowB0 + wc * WN + j * 16 + l16;
        long o = (long)row * Nn + col;
        float v = acc[i][j][r];
        if constexpr (MODE == 0) {
          reinterpret_cast<bf16_t*>(Cv)[o] = f2b(v);
        } else if constexpr (MODE == 1) {
          v = fminf(fmaxf(v, -5.f), 5.f);
          reinterpret_cast<bf16_t*>(Cv)[o] = f2b(siluf(v));
        } else if constexpr (MODE == 2) {
          float* C = reinterpret_cast<float*>(Cv);
          C[o] = C[o] + 0.1f * v;
        } else {
          float* C = reinterpret_cast<float*>(Cv);
          C[o] = C[o] * aux[row] + 0.1f * v;
        }
      }
}

// ---------------------------------------------------------------------------
// Fused gate/up, TILED inputs, gll16 staging, SINGLE buffer (R12 schedule:
// stage -> barrier -> compute -> barrier; 32KB LDS -> 5 blocks/CU TLP).
// ---------------------------------------------------------------------------
__global__ __launch_bounds__(256) void gemm_gu_g(
    const bf16_t* __restrict__ xhT, const bf16_t* __restrict__ xlT,
    const bf16_t* __restrict__ WghT, const bf16_t* __restrict__ WglT,
    const bf16_t* __restrict__ WuhT, const bf16_t* __restrict__ WulT,
    bf16_t* __restrict__ Hh, bf16_t* __restrict__ Hl) {
  __shared__ alignas(16) bf16_t Ah[128 * 32];
  __shared__ alignas(16) bf16_t Al[128 * 32];
  __shared__ alignas(16) bf16_t B1h[64 * 32];
  __shared__ alignas(16) bf16_t B1l[64 * 32];
  __shared__ alignas(16) bf16_t B2h[64 * 32];
  __shared__ alignas(16) bf16_t B2l[64 * 32];

  const int tid = threadIdx.x;
  const int wave = tid >> 6, lane = tid & 63;
  const int wr = wave >> 1, wc = wave & 1;
  const int quad = lane >> 4, l16 = lane & 15;
  const int sw = (quad ^ ((l16 >> 1) & 3)) << 3;
  const int bm = blockIdx.y, bn = blockIdx.x;
  constexpr int nks = D / 32;
  const int wo = wave << 9;

  f32x4 ag[4][2] = {}, au[4][2] = {};

  for (int ks = 0; ks < nks; ks++) {
    long ao = (((long)bm * nks + ks) << 12) + wo + lane * 8;
    long bo = (((long)bn * nks + ks) << 11) + wo + lane * 8;
    gll16(xhT + ao, Ah + wo);
    gll16(xhT + ao + 2048, Ah + wo + 2048);
    gll16(xlT + ao, Al + wo);
    gll16(xlT + ao + 2048, Al + wo + 2048);
    gll16(WghT + bo, B1h + wo);
    gll16(WglT + bo, B1l + wo);
    gll16(WuhT + bo, B2h + wo);
    gll16(WulT + bo, B2l + wo);
    __syncthreads();  // drains vmcnt -> LDS ready
    bf16x8 afh[4], afl[4], b1h[2], b1l[2], b2h[2], b2l[2];
#pragma unroll
    for (int i = 0; i < 4; i++) {
      int ro = (wr * 64 + i * 16 + l16) * 32 + sw;
      afh[i] = *reinterpret_cast<bf16x8*>(&Ah[ro]);
      afl[i] = *reinterpret_cast<bf16x8*>(&Al[ro]);
    }
#pragma unroll
    for (int j = 0; j < 2; j++) {
      int ro = (wc * 32 + j * 16 + l16) * 32 + sw;
      b1h[j] = *reinterpret_cast<bf16x8*>(&B1h[ro]);
      b1l[j] = *reinterpret_cast<bf16x8*>(&B1l[ro]);
      b2h[j] = *reinterpret_cast<bf16x8*>(&B2h[ro]);
      b2l[j] = *reinterpret_cast<bf16x8*>(&B2l[ro]);
    }
#pragma unroll
    for (int i = 0; i < 4; i++)
#pragma unroll
      for (int j = 0; j < 2; j++) {
        ag[i][j] = __builtin_amdgcn_mfma_f32_16x16x32_bf16(afh[i], b1h[j], ag[i][j], 0, 0, 0);
        ag[i][j] = __builtin_amdgcn_mfma_f32_16x16x32_bf16(afh[i], b1l[j], ag[i][j], 0, 0, 0);
        ag[i][j] = __builtin_amdgcn_mfma_f32_16x16x32_bf16(afl[i], b1h[j], ag[i][j], 0, 0, 0);
        au[i][j] = __builtin_amdgcn_mfma_f32_16x16x32_bf16(afh[i], b2h[j], au[i][j], 0, 0, 0);
        au[i][j] = __builtin_amdgcn_mfma_f32_16x16x32_bf16(afh[i], b2l[j], au[i][j], 0, 0, 0);
        au[i][j] = __builtin_amdgcn_mfma_f32_16x16x32_bf16(afl[i], b2h[j], au[i][j], 0, 0, 0);
      }
    __syncthreads();  // reads done before next-iter staging overwrites
  }

#pragma unroll
  for (int i = 0; i < 4; i++)
#pragma unroll
    for (int j = 0; j < 2; j++)
#pragma unroll
      for (int r = 0; r < 4; r++) {
        int row = bm * 128 + wr * 64 + i * 16 + quad * 4 + r;
        int col = bn * 64 + wc * 32 + j * 16 + l16;
        long o = tidx(row, col, H, 7) + (col & 7);
        float v = siluf(ag[i][j][r]) * au[i][j][r];
        bf16_t hh = f2b(v);
        Hh[o] = hh;
        Hl[o] = f2b(v - b2f(hh));
      }
}

// ---------------------------------------------------------------------------
// Down-proj, TILED inputs, gll16 staging, SINGLE buffer (R12 schedule).
// ---------------------------------------------------------------------------
__global__ __launch_bounds__(256) void gemm_dn_g(
    const bf16_t* __restrict__ HhT, const bf16_t* __restrict__ HlT,
    const bf16_t* __restrict__ WdhT, const bf16_t* __restrict__ WdlT,
    float* __restrict__ Cg) {
  __shared__ alignas(16) bf16_t Ah[128 * 32];
  __shared__ alignas(16) bf16_t Al[128 * 32];
  __shared__ alignas(16) bf16_t Bh[128 * 32];
  __shared__ alignas(16) bf16_t Bl[128 * 32];

  const int tid = threadIdx.x;
  const int wave = tid >> 6, lane = tid & 63;
  const int wr = wave >> 1, wc = wave & 1;
  const int quad = lane >> 4, l16 = lane & 15;
  const int sw = (quad ^ ((l16 >> 1) & 3)) << 3;
  const int by = blockIdx.y, bx = blockIdx.x;
  constexpr int nks = H / 32;
  const int wo = wave << 9;

  f32x4 acc[4][4] = {};

  for (int ks = 0; ks < nks; ks++) {
    long ao = (((long)by * nks + ks) << 12) + wo + lane * 8;
    long bo = (((long)bx * nks + ks) << 12) + wo + lane * 8;
    gll16(HhT + ao, Ah + wo);
    gll16(HhT + ao + 2048, Ah + wo + 2048);
    gll16(HlT + ao, Al + wo);
    gll16(HlT + ao + 2048, Al + wo + 2048);
    gll16(WdhT + bo, Bh + wo);
    gll16(WdhT + bo + 2048, Bh + wo + 2048);
    gll16(WdlT + bo, Bl + wo);
    gll16(WdlT + bo + 2048, Bl + wo + 2048);
    __syncthreads();
    bf16x8 afh[4], afl[4], bfh[4], bfl[4];
#pragma unroll
    for (int i = 0; i < 4; i++) {
      int ro = (wr * 64 + i * 16 + l16) * 32 + sw;
      afh[i] = *reinterpret_cast<bf16x8*>(&Ah[ro]);
      afl[i] = *reinterpret_cast<bf16x8*>(&Al[ro]);
    }
#pragma unroll
    for (int j = 0; j < 4; j++) {
      int ro = (wc * 64 + j * 16 + l16) * 32 + sw;
      bfh[j] = *reinterpret_cast<bf16x8*>(&Bh[ro]);
      bfl[j] = *reinterpret_cast<bf16x8*>(&Bl[ro]);
    }
#pragma unroll
    for (int i = 0; i < 4; i++)
#pragma unroll
      for (int j = 0; j < 4; j++) {
        acc[i][j] = __builtin_amdgcn_mfma_f32_16x16x32_bf16(afh[i], bfh[j], acc[i][j], 0, 0, 0);
        acc[i][j] = __builtin_amdgcn_mfma_f32_16x16x32_bf16(afh[i], bfl[j], acc[i][j], 0, 0, 0);
        acc[i][j] = __builtin_amdgcn_mfma_f32_16x16x32_bf16(afl[i], bfh[j], acc[i][j], 0, 0, 0);
      }
    __syncthreads();
  }

#pragma unroll
  for (int i = 0; i < 4; i++)
#pragma unroll
    for (int j = 0; j < 4; j++)
#pragma unroll
      for (int r = 0; r < 4; r++) {
        int row = by * 128 + wr * 64 + i * 16 + quad * 4 + r;
        int col = bx * 128 + wc * 64 + j * 16 + l16;
        Cg[(long)row * D + col] = acc[i][j][r];
      }
}

// ---------------------------------------------------------------------------
// Fused adapt attention: outp[token][oOff+col] = (silu(clip(ai@ao^T))@ai)
//   * (wsum ? wsum[token] : 1)
// ---------------------------------------------------------------------------
__global__ __launch_bounds__(256) void fused_adapt(
    const bf16_t* __restrict__ aib, const bf16_t* __restrict__ aob,
    const bf16_t* __restrict__ aiT, bf16_t* __restrict__ outp,
    int oLd, int oOff, const float* __restrict__ wsum) {
  constexpr int LDQ = 136;
  constexpr int LDP = 72;
  __shared__ alignas(16) bf16_t Qs[64 * LDQ];
  __shared__ alignas(16) bf16_t Os[64 * LDQ];
  __shared__ alignas(16) bf16_t Ps[64 * LDP];
  __shared__ alignas(16) bf16_t Vs[128 * LDP];

  const int tid = threadIdx.x;
  const int wave = tid >> 6, lane = tid & 63;
  const int wr = wave >> 1, wc = wave & 1;
  const int quad = lane >> 4, l16 = lane & 15;
  const int b = blockIdx.y;
  const int q0 = blockIdx.x * 64;

  for (int c = tid; c < 1024; c += 256) {
    int r = c >> 4, cc = c & 15;
    *reinterpret_cast<bf16x8*>(&Qs[r * LDQ + cc * 8]) =
        *reinterpret_cast<const bf16x8*>(&aib[((long)b * S + q0 + r) * A + cc * 8]);
  }

  f32x4 o[2][4] = {};

  for (int tt = 0; tt < S / 64; tt++) {
    const int t0 = tt * 64;
    __syncthreads();
    for (int c = tid; c < 1024; c += 256) {
      int r = c >> 4, cc = c & 15;
      *reinterpret_cast<bf16x8*>(&Os[r * LDQ + cc * 8]) =
          *reinterpret_cast<const bf16x8*>(&aob[((long)b * S + t0 + r) * A + cc * 8]);
    }
    for (int c = tid; c < 1024; c += 256) {
      int r = c >> 3, cc = c & 7;
      *reinterpret_cast<bf16x8*>(&Vs[r * LDP + cc * 8]) =
          *reinterpret_cast<const bf16x8*>(&aiT[((long)b * A + r) * S + t0 + cc * 8]);
    }
    __syncthreads();
    f32x4 p[2][2] = {};
#pragma unroll
    for (int ks = 0; ks < 4; ks++) {
      bf16x8 af[2], bfv[2];
#pragma unroll
      for (int i = 0; i < 2; i++)
        af[i] = *reinterpret_cast<bf16x8*>(&Qs[(wr * 32 + i * 16 + l16) * LDQ + ks * 32 + quad * 8]);
#pragma unroll
      for (int j = 0; j < 2; j++)
        bfv[j] = *reinterpret_cast<bf16x8*>(&Os[(wc * 32 + j * 16 + l16) * LDQ + ks * 32 + quad * 8]);
#pragma unroll
      for (int i = 0; i < 2; i++)
#pragma unroll
        for (int j = 0; j < 2; j++)
          p[i][j] = __builtin_amdgcn_mfma_f32_16x16x32_bf16(af[i], bfv[j], p[i][j], 0, 0, 0);
    }
#pragma unroll
    for (int i = 0; i < 2; i++)
#pragma unroll
      for (int j = 0; j < 2; j++)
#pragma unroll
        for (int r = 0; r < 4; r++) {
          int row = wr * 32 + i * 16 + quad * 4 + r;
          int col = wc * 32 + j * 16 + l16;
          float v = fminf(fmaxf(p[i][j][r], -5.f), 5.f);
          Ps[row * LDP + col] = f2b(siluf(v));
        }
    __syncthreads();
#pragma unroll
    for (int ks = 0; ks < 2; ks++) {
      bf16x8 paf[2], vbf[4];
#pragma unroll
      for (int i = 0; i < 2; i++)
        paf[i] = *reinterpret_cast<bf16x8*>(&Ps[(wr * 32 + i * 16 + l16) * LDP + ks * 32 + quad * 8]);
#pragma unroll
      for (int j = 0; j < 4; j++)
        vbf[j] = *reinterpret_cast<bf16x8*>(&Vs[(wc * 64 + j * 16 + l16) * LDP + ks * 32 + quad * 8]);
#pragma unroll
      for (int i = 0; i < 2; i++)
#pragma unroll
        for (int j = 0; j < 4; j++)
          o[i][j] = __builtin_amdgcn_mfma_f32_16x16x32_bf16(paf[i], vbf[j], o[i][j], 0, 0, 0);
    }
  }

#pragma unroll
  for (int i = 0; i < 2; i++)
#pragma unroll
    for (int j = 0; j < 4; j++)
#pragma unroll
      for (int r = 0; r < 4; r++) {
        int row = q0 + wr * 32 + i * 16 + quad * 4 + r;
        int col = wc * 64 + j * 16 + l16;
        long token = (long)b * S + row;
        float sc = wsum ? wsum[token] : 1.f;
        outp[token * oLd + oOff + col] = f2b(o[i][j][r] * sc);
      }
}

// ---------------------------------------------------------------------------
// [D,A] = Af32 @ Bbf16^T, split-K x8 into f32 partials (Mb and WdWap).
// ---------------------------------------------------------------------------
__global__ __launch_bounds__(256) void gemm_mb_splitk(
    const float* __restrict__ Ag, const bf16_t* __restrict__ Bg,
    float* __restrict__ Mp, int M, int Nn, int K) {
  constexpr int BM = 64, BN = 64, LDT = 40;
  __shared__ alignas(16) bf16_t As[BM * LDT];
  __shared__ alignas(16) bf16_t Bs[BN * LDT];
  const int tid = threadIdx.x;
  const int wave = tid >> 6, lane = tid & 63;
  const int wr = wave >> 1, wc = wave & 1;
  const int quad = lane >> 4, l16 = lane & 15;
  const int rowA0 = blockIdx.y * BM, rowB0 = blockIdx.x * BN;
  const int kz = blockIdx.z;
  const int ks0 = kz * (K / 8), ks1 = ks0 + K / 8;

  f32x4 acc[2][2] = {};
  for (int k0 = ks0; k0 < ks1; k0 += 32) {
    for (int c = tid; c < BM * 4; c += 256) {
      int r = c >> 2, kc = c & 3;
      *reinterpret_cast<bf16x8*>(&As[r * LDT + kc * 8]) =
          ld8f(Ag + (long)(rowA0 + r) * K + k0 + kc * 8);
    }
    for (int c = tid; c < BN * 4; c += 256) {
      int r = c >> 2, kc = c & 3;
      *reinterpret_cast<bf16x8*>(&Bs[r * LDT + kc * 8]) =
          *reinterpret_cast<const bf16x8*>(&Bg[(long)(rowB0 + r) * K + k0 + kc * 8]);
    }
    __syncthreads();
    bf16x8 af[2], bfv[2];
#pragma unroll
    for (int i = 0; i < 2; i++)
      af[i] = *reinterpret_cast<bf16x8*>(&As[(wr * 32 + i * 16 + l16) * LDT + quad * 8]);
#pragma unroll
    for (int j = 0; j < 2; j++)
      bfv[j] = *reinterpret_cast<bf16x8*>(&Bs[(wc * 32 + j * 16 + l16) * LDT + quad * 8]);
#pragma unroll
    for (int i = 0; i < 2; i++)
#pragma unroll
      for (int j = 0; j < 2; j++)
        acc[i][j] = __builtin_amdgcn_mfma_f32_16x16x32_bf16(af[i], bfv[j], acc[i][j], 0, 0, 0);
    __syncthreads();
  }
#pragma unroll
  for (int i = 0; i < 2; i++)
#pragma unroll
    for (int j = 0; j < 2; j++)
#pragma unroll
      for (int r = 0; r < 4; r++) {
        int row = rowA0 + wr * 32 + i * 16 + quad * 4 + r;
        int col = rowB0 + wc * 32 + j * 16 + l16;
        Mp[(long)kz * M * Nn + (long)row * Nn + col] = acc[i][j][r];
      }
}

// combine partials into strided bf16 destination: out[(i>>7)*ld + coff + (i&127)]
__global__ __launch_bounds__(256) void mb_combine(
    const float* __restrict__ Mp, bf16_t* __restrict__ outp, int total,
    int ld, int coff) {
  int i = blockIdx.x * 256 + threadIdx.x;
  if (i >= total) return;
  float s = 0.f;
#pragma unroll
  for (int z = 0; z < 8; z++) s += Mp[(long)z * total + i];
  outp[(long)(i >> 7) * ld + coff + (i & 127)] = f2b(s);
}

// ---------------------------------------------------------------------------
// Fallback-path kernels (f32 inputs, in-loop split) — unchanged, proven.
// ---------------------------------------------------------------------------
__global__ __launch_bounds__(256) void gemm_dn_hl(
    const float* __restrict__ Ag, const float* __restrict__ Bg,
    float* __restrict__ Cg, int M, int Nn, int K) {
  constexpr int BM = 128, BN = 128, LDT = 40;
  __shared__ alignas(16) bf16_t Ah[BM * LDT];
  __shared__ alignas(16) bf16_t Al[BM * LDT];
  __shared__ alignas(16) bf16_t Bh[BN * LDT];
  __shared__ alignas(16) bf16_t Bl[BN * LDT];

  const int tid = threadIdx.x;
  const int wave = tid >> 6, lane = tid & 63;
  const int wr = wave >> 1, wc = wave & 1;
  const int quad = lane >> 4, l16 = lane & 15;
  const int rowA0 = blockIdx.y * BM, rowB0 = blockIdx.x * BN;

  f32x4 acc[4][4] = {};

  for (int k0 = 0; k0 < K; k0 += 32) {
    for (int c = tid; c < BM * 4; c += 256) {
      int r = c >> 2, kc = c & 3;
      bf16x8 h, l;
      split8(&Ag[(long)(rowA0 + r) * K + k0 + kc * 8], h, l);
      *reinterpret_cast<bf16x8*>(&Ah[r * LDT + kc * 8]) = h;
      *reinterpret_cast<bf16x8*>(&Al[r * LDT + kc * 8]) = l;
    }
    for (int c = tid; c < BN * 4; c += 256) {
      int r = c >> 2, kc = c & 3;
      bf16x8 h, l;
      split8(&Bg[(long)(rowB0 + r) * K + k0 + kc * 8], h, l);
      *reinterpret_cast<bf16x8*>(&Bh[r * LDT + kc * 8]) = h;
      *reinterpret_cast<bf16x8*>(&Bl[r * LDT + kc * 8]) = l;
    }
    __syncthreads();
    bf16x8 afh[4], afl[4], bfh[4], bfl[4];
#pragma unroll
    for (int i = 0; i < 4; i++) {
      int ro = (wr * 64 + i * 16 + l16) * LDT + quad * 8;
      afh[i] = *reinterpret_cast<bf16x8*>(&Ah[ro]);
      afl[i] = *reinterpret_cast<bf16x8*>(&Al[ro]);
    }
#pragma unroll
    for (int j = 0; j < 4; j++) {
      int ro = (wc * 64 + j * 16 + l16) * LDT + quad * 8;
      bfh[j] = *reinterpret_cast<bf16x8*>(&Bh[ro]);
      bfl[j] = *reinterpret_cast<bf16x8*>(&Bl[ro]);
    }
#pragma unroll
    for (int i = 0; i < 4; i++)
#pragma unroll
      for (int j = 0; j < 4; j++) {
        acc[i][j] = __builtin_amdgcn_mfma_f32_16x16x32_bf16(afh[i], bfh[j], acc[i][j], 0, 0, 0);
        acc[i][j] = __builtin_amdgcn_mfma_f32_16x16x32_bf16(afh[i], bfl[j], acc[i][j], 0, 0, 0);
        acc[i][j] = __builtin_amdgcn_mfma_f32_16x16x32_bf16(afl[i], bfh[j], acc[i][j], 0, 0, 0);
      }
    __syncthreads();
  }

#pragma unroll
  for (int i = 0; i < 4; i++)
#pragma unroll
    for (int j = 0; j < 4; j++)
#pragma unroll
      for (int r = 0; r < 4; r++) {
        int row = rowA0 + wr * 64 + i * 16 + quad * 4 + r;
        int col = rowB0 + wc * 64 + j * 16 + l16;
        Cg[(long)row * Nn + col] = acc[i][j][r];
      }
}

__global__ __launch_bounds__(256) void gemm_gu_hl(
    const float* __restrict__ x, const float* __restrict__ Wg,
    const float* __restrict__ Wu, float* __restrict__ Cg, int M, int Nn, int K) {
  constexpr int BM = 128, BN = 64, LDT = 40;
  __shared__ alignas(16) bf16_t Ah[BM * LDT];
  __shared__ alignas(16) bf16_t Al[BM * LDT];
  __shared__ alignas(16) bf16_t B1h[BN * LDT];
  __shared__ alignas(16) bf16_t B1l[BN * LDT];
  __shared__ alignas(16) bf16_t B2h[BN * LDT];
  __shared__ alignas(16) bf16_t B2l[BN * LDT];

  const int tid = threadIdx.x;
  const int wave = tid >> 6, lane = tid & 63;
  const int wr = wave >> 1, wc = wave & 1;
  const int quad = lane >> 4, l16 = lane & 15;
  const int rowA0 = blockIdx.y * BM, rowB0 = blockIdx.x * BN;

  f32x4 ag[4][2] = {}, au[4][2] = {};

  for (int k0 = 0; k0 < K; k0 += 32) {
    for (int c = tid; c < BM * 4; c += 256) {
      int r = c >> 2, kc = c & 3;
      bf16x8 h, l;
      split8(&x[(long)(rowA0 + r) * K + k0 + kc * 8], h, l);
      *reinterpret_cast<bf16x8*>(&Ah[r * LDT + kc * 8]) = h;
      *reinterpret_cast<bf16x8*>(&Al[r * LDT + kc * 8]) = l;
    }
    for (int c = tid; c < BN * 4; c += 256) {
      int r = c >> 2, kc = c & 3;
      long idx = (long)(rowB0 + r) * K + k0 + kc * 8;
      bf16x8 h, l;
      split8(&Wg[idx], h, l);
      *reinterpret_cast<bf16x8*>(&B1h[r * LDT + kc * 8]) = h;
      *reinterpret_cast<bf16x8*>(&B1l[r * LDT + kc * 8]) = l;
      split8(&Wu[idx], h, l);
      *reinterpret_cast<bf16x8*>(&B2h[r * LDT + kc * 8]) = h;
      *reinterpret_cast<bf16x8*>(&B2l[r * LDT + kc * 8]) = l;
    }
    __syncthreads();
    bf16x8 afh[4], afl[4], b1h[2], b1l[2], b2h[2], b2l[2];
#pragma unroll
    for (int i = 0; i < 4; i++) {
      int ro = (wr * 64 + i * 16 + l16) * LDT + quad * 8;
      afh[i] = *reinterpret_cast<bf16x8*>(&Ah[ro]);
      afl[i] = *reinterpret_cast<bf16x8*>(&Al[ro]);
    }
#pragma unroll
    for (int j = 0; j < 2; j++) {
      int ro = (wc * 32 + j * 16 + l16) * LDT + quad * 8;
      b1h[j] = *reinterpret_cast<bf16x8*>(&B1h[ro]);
      b1l[j] = *reinterpret_cast<bf16x8*>(&B1l[ro]);
      b2h[j] = *reinterpret_cast<bf16x8*>(&B2h[ro]);
      b2l[j] = *reinterpret_cast<bf16x8*>(&B2l[ro]);
    }
#pragma unroll
    for (int i = 0; i < 4; i++)
#pragma unroll
      for (int j = 0; j < 2; j++) {
        ag[i][j] = __builtin_amdgcn_mfma_f32_16x16x32_bf16(afh[i], b1h[j], ag[i][j], 0, 0, 0);
        ag[i][j] = __builtin_amdgcn_mfma_f32_16x16x32_bf16(afh[i], b1l[j], ag[i][j], 0, 0, 0);
        ag[i][j] = __builtin_amdgcn_mfma_f32_16x16x32_bf16(afl[i], b1h[j], ag[i][j], 0, 0, 0);
        au[i][j] = __builtin_amdgcn_mfma_f32_16x16x32_bf16(afh[i], b2h[j], au[i][j], 0, 0, 0);
        au[i][j] = __builtin_amdgcn_mfma_f32_16x16x32_bf16(afh[i], b2l[j], au[i][j], 0, 0, 0);
        au[i][j] = __builtin_amdgcn_mfma_f32_16x16x32_bf16(afl[i], b2h[j], au[i][j], 0, 0, 0);
      }
    __syncthreads();
  }

#pragma unroll
  for (int i = 0; i < 4; i++)
#pragma unroll
    for (int j = 0; j < 2; j++)
#pragma unroll
      for (int r = 0; r < 4; r++) {
        int row = rowA0 + wr * 64 + i * 16 + quad * 4 + r;
        int col = rowB0 + wc * 32 + j * 16 + l16;
        Cg[(long)row * Nn + col] = siluf(ag[i][j][r]) * au[i][j][r];
      }
}

// ---------------------------------------------------------------------------
// Router (no global atomics, per-block partials).
// ---------------------------------------------------------------------------
__global__ __launch_bounds__(256) void router_kernel(
    const float* __restrict__ x, const float* __restrict__ Wgr,
    const float* __restrict__ Wer, int* __restrict__ eidx,
    float* __restrict__ fw, float* __restrict__ wsum,
    float* __restrict__ lpart) {
  __shared__ float part[4][12];
  const int wv = threadIdx.x >> 6;
  const int lane = threadIdx.x & 63;
  const int token = blockIdx.x * 4 + wv;
  if (lane < 12) part[wv][lane] = 0.f;
  const float* xp = x + (long)token * D;
  float xr[16];
#pragma unroll
  for (int i = 0; i < 16; i++) xr[i] = xp[lane + i * 64];
  float dots[6];
#pragma unroll
  for (int w = 0; w < 6; w++) {
    const float* wp = (w < 2) ? (Wgr + (long)w * D) : (Wer + (long)(w - 2) * D);
    float s = 0.f;
#pragma unroll
    for (int i = 0; i < 16; i++) s += xr[i] * wp[lane + i * 64];
#pragma unroll
    for (int off = 32; off; off >>= 1) s += __shfl_xor(s, off);
    dots[w] = s;
  }
  if (lane == 0) {
    float gl0 = dots[0], gl1 = dots[1];
    float mg = fmaxf(gl0, gl1);
    float e0 = expf(gl0 - mg), e1 = expf(gl1 - mg);
    float inv = 1.f / (e0 + e1);
    float gp0 = e0 * inv, gp1 = e1 * inv;
    int gi = (gp1 > gp0) ? 1 : 0;
    float gw = gi ? gp1 : gp0;
    float el[4] = {dots[2], dots[3], dots[4], dots[5]};
    float me = fmaxf(fmaxf(el[0], el[1]), fmaxf(el[2], el[3]));
    float ep[4], es = 0.f;
#pragma unroll
    for (int j = 0; j < 4; j++) { ep[j] = expf(el[j] - me); es += ep[j]; }
    float inve = 1.f / es;
#pragma unroll
    for (int j = 0; j < 4; j++) ep[j] *= inve;
    int i1 = 0;
    for (int j = 1; j < 4; j++) if (ep[j] > ep[i1]) i1 = j;
    int i2 = (i1 == 0) ? 1 : 0;
    for (int j = 0; j < 4; j++) if (j != i1 && j != i2 && ep[j] > ep[i2]) i2 = j;
    float l1 = ep[i1], l2 = ep[i2];
    float ils = 1.f / (l1 + l2 + 1e-7f);
    float f1 = gw * l1 * ils, f2 = gw * l2 * ils;
    eidx[token * 2] = gi * 4 + i1;
    eidx[token * 2 + 1] = gi * 4 + i2;
    fw[token * 2] = f1;
    fw[token * 2 + 1] = f2;
    wsum[token] = f1 + f2;
    part[wv][gi * 4 + i1] = f1;
    part[wv][gi * 4 + i2] = f2;
    part[wv][8] = gl0 * gl0 + gl1 * gl1;
    part[wv][9] = el[0] * el[0] + el[1] * el[1] + el[2] * el[2] + el[3] * el[3];
  }
  __syncthreads();
  if (threadIdx.x < 12) {
    lpart[(long)blockIdx.x * 12 + threadIdx.x] =
        part[0][threadIdx.x] + part[1][threadIdx.x] +
        part[2][threadIdx.x] + part[3][threadIdx.x];
  }
}

// ---------------------------------------------------------------------------
// Row LayerNorm over A=128 (bf16 in ws, f32 g/b, bf16 out).
// ---------------------------------------------------------------------------
__global__ __launch_bounds__(256) void ln_rows(
    const bf16_t* __restrict__ in, const float* __restrict__ g,
    const float* __restrict__ b, bf16_t* __restrict__ out) {
  const int row = blockIdx.x * 4 + (threadIdx.x >> 6);
  const int lane = threadIdx.x & 63;
  const bf16_t* p = in + (long)row * A;
  float x0 = b2f(p[lane]), x1 = b2f(p[lane + 64]);
  float s = x0 + x1;
#pragma unroll
  for (int off = 32; off; off >>= 1) s += __shfl_xor(s, off);
  float mean = s * (1.f / 128.f);
  float d0 = x0 - mean, d1 = x1 - mean;
  float q = d0 * d0 + d1 * d1;
#pragma unroll
  for (int off = 32; off; off >>= 1) q += __shfl_xor(q, off);
  float r = rsqrtf(q * (1.f / 128.f) + 1e-5f);
  bf16_t* po = out + (long)row * A;
  po[lane] = f2b(d0 * r * g[lane] + b[lane]);
  po[lane + 64] = f2b(d1 * r * g[lane + 64] + b[lane + 64]);
}

// ---------------------------------------------------------------------------
// Transpose [z,R,C] -> [z,C,R], bf16 out; input f32 (isf=1) or bf16.
// ---------------------------------------------------------------------------
__global__ __launch_bounds__(256) void transpose2d(
    const void* __restrict__ in, bf16_t* __restrict__ out, int R, int C, int isf) {
  __shared__ bf16_t t[32][33];
  const long zb = blockIdx.z;
  const long ib = zb * (long)R * C;
  bf16_t* op = out + zb * (long)R * C;
  const int r0 = blockIdx.y * 32, c0 = blockIdx.x * 32;
  const int tx = threadIdx.x & 31, ty = threadIdx.x >> 5;
#pragma unroll
  for (int i = 0; i < 4; i++) {
    long idx = ib + (long)(r0 + ty + i * 8) * C + c0 + tx;
    t[ty + i * 8][tx] = isf ? f2b(reinterpret_cast<const float*>(in)[idx])
                            : reinterpret_cast<const bf16_t*>(in)[idx];
  }
  __syncthreads();
#pragma unroll
  for (int i = 0; i < 4; i++) op[(long)(c0 + ty + i * 8) * R + r0 + tx] = t[tx][ty + i * 8];
}

// ---------------------------------------------------------------------------
// Expert branch: coalesced via pre-transposed WeaT[e][a][c] (bf16).
// ---------------------------------------------------------------------------
__global__ __launch_bounds__(128) void expert_adapt(
    const bf16_t* __restrict__ h0, const bf16_t* __restrict__ WeaT,
    const float* __restrict__ ln_eg, const float* __restrict__ ln_eb,
    const int* __restrict__ eidx, const float* __restrict__ fw,
    bf16_t* __restrict__ hw, int ld) {
  const int n = blockIdx.x;
  const int c = threadIdx.x;
  __shared__ float h0s[128];
  __shared__ float red[4];
  h0s[c] = b2f(h0[(long)n * A + c]);
  __syncthreads();
  float out = 0.f;
  for (int k = 0; k < 2; k++) {
    int e = eidx[n * 2 + k];
    e = min(max(e, 0), E - 1);
    float w = fw[n * 2 + k];
    const bf16_t* Wc = WeaT + (long)e * A * A + c;
    float t = 0.f;
#pragma unroll 8
    for (int a = 0; a < 128; a++) t += b2f(Wc[(long)a * A]) * h0s[a];
    float s = t, q = t * t;
#pragma unroll
    for (int off = 32; off; off >>= 1) { s += __shfl_xor(s, off); q += __shfl_xor(q, off); }
    if ((c & 63) == 0) { red[(c >> 6) * 2] = s; red[(c >> 6) * 2 + 1] = q; }
    __syncthreads();
    float Sx = red[0] + red[2], Qx = red[1] + red[3];
    float mean = Sx * (1.f / 128.f);
    float var = Qx * (1.f / 128.f) - mean * mean;
    float r = rsqrtf(var + 1e-5f);
    out += w * ((t - mean) * r * ln_eg[e * A + c] + ln_eb[e * A + c]);
    __syncthreads();
  }
  hw[(long)n * ld + c] = f2b(out);
}

// ---------------------------------------------------------------------------
// Loss finalize.
// ---------------------------------------------------------------------------
__global__ __launch_bounds__(256) void finalize_loss(
    const float* __restrict__ lpart, int nblk, float* __restrict__ outv) {
  float acc[10] = {};
  for (int b = threadIdx.x; b < nblk; b += 256) {
    const float* p = lpart + (long)b * 12;
#pragma unroll
    for (int c = 0; c < 10; c++) acc[c] += p[c];
  }
  __shared__ float red[10][4];
  const int lane = threadIdx.x & 63, wv = threadIdx.x >> 6;
#pragma unroll
  for (int c = 0; c < 10; c++) {
    float s = acc[c];
#pragma unroll
    for (int off = 32; off; off >>= 1) s += __shfl_xor(s, off);
    if (lane == 0) red[c][wv] = s;
  }
  __syncthreads();
  if (threadIdx.x == 0) {
    float loss[10];
#pragma unroll
    for (int c = 0; c < 10; c++)
      loss[c] = red[c][0] + red[c][1] + red[c][2] + red[c][3];
    float tl = 0.f;
    for (int e = 0; e < 8; e++) tl += loss[e];
    float target = tl / 8.f;
    float mse = 0.f;
    for (int e = 0; e < 8; e++) { float d = loss[e] - target; mse += d * d; }
    mse *= (1.f / 8.f);
    outv[0] = 0.001f * (mse + loss[8] / (float)(N * 2) + loss[9] / (float)(N * 4));
  }
}

// ---------------------------------------------------------------------------
extern "C" void kernel_launch(void* const* d_in, const int* in_sizes, int n_in,
                              void* d_out, int out_size, void* d_ws, size_t ws_size,
                              hipStream_t stream) {
  const float* x = (const float*)d_in[0];
  const float* Wu = (const float*)d_in[1];
  const float* Wg = (const float*)d_in[2];
  const float* Wd = (const float*)d_in[3];
  const float* Wpre = (const float*)d_in[4];
  const float* Wpost = (const float*)d_in[5];
  const float* ln_g = (const float*)d_in[6];
  const float* ln_b = (const float*)d_in[7];
  const float* Wap = (const float*)d_in[8];
  const float* Wea = (const float*)d_in[9];
  const float* ln_eg = (const float*)d_in[10];
  const float* ln_eb = (const float*)d_in[11];
  const float* Wep = (const float*)d_in[12];
  const float* Wop = (const float*)d_in[13];
  const float* Wgr = (const float*)d_in[14];
  const float* Wer = (const float*)d_in[15];
  float* out = (float*)d_out;

  char* ws = (char*)d_ws;
  size_t off = 0;
  auto alloc = [&](size_t bytes) { char* p = ws + off; off += (bytes + 255) & ~size_t(255); return p; };
  // Common allocations (~18 MB)
  float* lpart = (float*)alloc((size_t)(N / 4) * 12 * 4);
  float* wsum = (float*)alloc((size_t)N * 4);
  float* fwb = (float*)alloc((size_t)N * 2 * 4);
  int* eidx = (int*)alloc((size_t)N * 2 * 4);
  bf16_t* Mb2 = (bf16_t*)alloc((size_t)D * 256 * 2);   // [D,256] = [Mb | WdWap]
  float* Mp = (float*)alloc((size_t)8 * D * A * 4);    // split-K partials (reused)
  bf16_t* WepT = (bf16_t*)alloc((size_t)H * A * 2);
  bf16_t* WapT = (bf16_t*)alloc((size_t)H * A * 2);
  bf16_t* hw2 = (bf16_t*)alloc((size_t)N * 256 * 2);   // [N,256] = [hw | adpreS]
  bf16_t* h0b = (bf16_t*)alloc((size_t)N * A * 2);
  bf16_t* aib = (bf16_t*)alloc((size_t)N * A * 2);
  bf16_t* scrA = (bf16_t*)alloc((size_t)N * A * 2);
  bf16_t* aob = (bf16_t*)alloc((size_t)N * A * 2);
  bf16_t* WeaT = (bf16_t*)alloc((size_t)E * A * A * 2);
  bf16_t* aopre = scrA;
  bf16_t* aiT = scrA;

  // Big path: pre-split TILED hi/lo buffers (+120 MB; total ~138.5 MiB).
  const bool big = ws_size >= ((size_t)140 << 20);
  float* hiddenF = nullptr;
  bf16_t *xh = nullptr, *xl = nullptr;
  bf16_t *Wgh = nullptr, *Wgl = nullptr, *Wuh = nullptr, *Wul = nullptr;
  bf16_t *Wdh = nullptr, *Wdl = nullptr, *Hh = nullptr, *Hl = nullptr;
  if (big) {
    xh = (bf16_t*)alloc((size_t)N * D * 2);
    xl = (bf16_t*)alloc((size_t)N * D * 2);
    Wgh = (bf16_t*)alloc((size_t)H * D * 2);
    Wgl = (bf16_t*)alloc((size_t)H * D * 2);
    Wuh = (bf16_t*)alloc((size_t)H * D * 2);
    Wul = (bf16_t*)alloc((size_t)H * D * 2);
    Wdh = (bf16_t*)alloc((size_t)D * H * 2);
    Wdl = (bf16_t*)alloc((size_t)D * H * 2);
    Hh = (bf16_t*)alloc((size_t)N * H * 2);
    Hl = (bf16_t*)alloc((size_t)N * H * 2);
  } else {
    hiddenF = (float*)alloc((size_t)N * H * 4);
  }
  (void)ws_size; (void)in_sizes; (void)n_in; (void)out_size;

  const dim3 blk(256);

  router_kernel<<<dim3(N / 4), blk, 0, stream>>>(x, Wgr, Wer, eidx, fwb, wsum, lpart);
  transpose2d<<<dim3(A / 32, A / 32, E), blk, 0, stream>>>(Wea, WeaT, A, A, 1);

  if (big) {
    // tiled splits: x TR=128 K=D; Wg/Wu TR=64 K=D; Wd TR=128 K=H
    split_tiled<7, 5><<<dim3(2048), blk, 0, stream>>>(x, xh, xl, (long)N * D / 8, D);
    split_tiled<6, 5><<<dim3(512), blk, 0, stream>>>(Wg, Wgh, Wgl, (long)H * D / 8, D);
    split_tiled<6, 5><<<dim3(512), blk, 0, stream>>>(Wu, Wuh, Wul, (long)H * D / 8, D);
    split_tiled<7, 6><<<dim3(512), blk, 0, stream>>>(Wd, Wdh, Wdl, (long)D * H / 8, H);
    // hidden0 (tiled Hh/Hl) = silu(x@Wg^T)*(x@Wu^T)
    gemm_gu_g<<<dim3(H / 64, N / 128), blk, 0, stream>>>(
        xh, xl, Wgh, Wgl, Wuh, Wul, Hh, Hl);
    // h0 = x@Wpre^T  (A from tiled xh)
    gemm_nt_b<16, 32, 0><<<dim3(A / 64, N / 32), blk, 0, stream>>>(
        xh, Wpre, h0b, N, A, D, nullptr, 2, 1);
    ln_rows<<<dim3(N / 4), blk, 0, stream>>>(h0b, ln_g, ln_b, aib);
    // ao_pre = hidden0@Wpost^T (pre-adapt hidden, matches reference)
    gemm_nt_b<16, 32, 0><<<dim3(A / 64, N / 32), blk, 0, stream>>>(
        Hh, Wpost, aopre, N, A, H, nullptr, 2, 1);
    ln_rows<<<dim3(N / 4), blk, 0, stream>>>(aopre, ln_g, ln_b, aob);
    transpose2d<<<dim3(A / 32, S / 32, Bb), blk, 0, stream>>>(aib, aiT, S, A, 0);
    // adpreS = wsum * (silu(clip(ai@ao^T)) @ ai) -> hw2 cols 128..255
    fused_adapt<<<dim3(S / 64, Bb), blk, 0, stream>>>(
        aib, aob, aiT, hw2, 256, 128, wsum);
    // out = hidden0@Wd^T (adapt contribution folded into final GEMM)
    gemm_dn_g<<<dim3(D / 128, N / 128), blk, 0, stream>>>(Hh, Hl, Wdh, Wdl, out);
    // Mb2 = [Wop@Wep | Wd@Wap]
    transpose2d<<<dim3(A / 32, H / 32, 1), blk, 0, stream>>>(Wep, WepT, H, A, 1);
    transpose2d<<<dim3(A / 32, H / 32, 1), blk, 0, stream>>>(Wap, WapT, H, A, 1);
    gemm_mb_splitk<<<dim3(A / 64, D / 64, 8), blk, 0, stream>>>(Wop, WepT, Mp, D, A, H);
    mb_combine<<<dim3((D * A + 255) / 256), blk, 0, stream>>>(Mp, Mb2, D * A, 256, 0);
    gemm_mb_splitk<<<dim3(A / 64, D / 64, 8), blk, 0, stream>>>(Wd, WapT, Mp, D, A, H);
    mb_combine<<<dim3((D * A + 255) / 256), blk, 0, stream>>>(Mp, Mb2, D * A, 256, 128);
    // hw -> hw2 cols 0..127
    expert_adapt<<<dim3(N), dim3(128), 0, stream>>>(
        h0b, WeaT, ln_eg, ln_eb, eidx, fwb, hw2, 256);
    // out = out*wsum + 0.1*(hw@Mb^T + adpreS@WdWap^T)   K=256 concat
    gemm_nt_b<64, 64, 3><<<dim3(D / 128, N / 128), blk, 0, stream>>>(
        hw2, Mb2, out, N, D, 256, wsum, 0, 0);
  } else {
    bf16_t* adpreb = hw2 + (size_t)N * A;  // second half of hw2 as [N,A]
    gemm_gu_hl<<<dim3(H / 64, N / 128), blk, 0, stream>>>(x, Wg, Wu, hiddenF, N, H, D);
    gemm_nt_b<16, 32, 0><<<dim3(A / 64, N / 32), blk, 0, stream>>>(
        x, Wpre, h0b, N, A, D, nullptr, 1, 1);
    ln_rows<<<dim3(N / 4), blk, 0, stream>>>(h0b, ln_g, ln_b, aib);
    gemm_nt_b<16, 32, 0><<<dim3(A / 64, N / 32), blk, 0, stream>>>(
        hiddenF, Wpost, aopre, N, A, H, nullptr, 1, 1);
    ln_rows<<<dim3(N / 4), blk, 0, stream>>>(aopre, ln_g, ln_b, aob);
    transpose2d<<<dim3(A / 32, S / 32, Bb), blk, 0, stream>>>(aib, aiT, S, A, 0);
    fused_adapt<<<dim3(S / 64, Bb), blk, 0, stream>>>(
        aib, aob, aiT, adpreb, 128, 0, nullptr);
    gemm_nt_b<64, 64, 2><<<dim3(H / 128, N / 128), blk, 0, stream>>>(
        adpreb, Wap, hiddenF, N, H, A, nullptr, 0, 1);
    gemm_dn_hl<<<dim3(D / 128, N / 128), blk, 0, stream>>>(hiddenF, Wd, out, N, D, H);
    transpose2d<<<dim3(A / 32, H / 32, 1), blk, 0, stream>>>(Wep, WepT, H, A, 1);
    gemm_mb_splitk<<<dim3(A / 64, D / 64, 8), blk, 0, stream>>>(Wop, WepT, Mp, D, A, H);
    mb_combine<<<dim3((D * A + 255) / 256), blk, 0, stream>>>(Mp, Mb2, D * A, 128, 0);
    expert_adapt<<<dim3(N), dim3(128), 0, stream>>>(
        h0b, WeaT, ln_eg, ln_eb, eidx, fwb, hw2, 128);
    gemm_nt_b<64, 64, 3><<<dim3(D / 128, N / 128), blk, 0, stream>>>(
        hw2, Mb2, out, N, D, A, wsum, 0, 0);
  }

  finalize_loss<<<dim3(1), blk, 0, stream>>>(lpart, N / 4, out + (size_t)N * D);
}

// Round 8
// 731.526 us; speedup vs baseline: 1.1044x; 1.0565x over previous
//
#include <hip/hip_runtime.h>
#include <math.h>

// ---------------------------------------------------------------------------
// MoE layer, round 15. Base = R14 (772.9us).
// Changes (TLP-preserving only; R13 lesson: don't trade occupancy):
//  1. T1 XCD-aware block swizzle in gu/dn (grids 2048/512, both %8==0):
//     each XCD owns contiguous bm rows -> A-panel L2 reuse. gu FETCH was
//     164MB vs ~50MB compulsory (3.3x over-fetch from cross-XCD round-robin).
//  2. Final K=256 concat GEMM folded into dn with the SAME accumulator:
//     out = wsum*(hidden@Wd^T + hw2'@Mb2^T), hw2' = [0.1/wsum*hw | 0.1*adpre]
//     (producers pre-scale). dn appends 8 plain-bf16 ksteps staged from
//     row-major hw2/Mb2 via gll16 with per-lane pre-swizzled global source
//     (rule #21). Kills 64MB f32 RMW + 1 dispatch. No extra VGPR.
//  3. Wg/Wu splits merged via grid.z.
// B=4, S=2048, D=1024, H=2048, A=128, E=8, N=8192.
// ---------------------------------------------------------------------------

typedef __bf16 bf16_t;
typedef __attribute__((ext_vector_type(8))) __bf16 bf16x8;
typedef __attribute__((ext_vector_type(4))) float f32x4;

__device__ __forceinline__ float b2f(bf16_t v) { return (float)v; }
__device__ __forceinline__ bf16_t f2b(float v) { return (bf16_t)v; }
__device__ __forceinline__ float siluf(float v) { return v / (1.f + expf(-v)); }

static constexpr int Bb = 4, S = 2048, D = 1024, H = 2048, A = 128, E = 8;
static constexpr int N = Bb * S;

// async global->LDS, 16B per lane; LDS dest = wave-uniform base + lane*16
typedef __attribute__((address_space(1))) void gvoid;
typedef __attribute__((address_space(3))) void svoid;
__device__ __forceinline__ void gll16(const bf16_t* g, bf16_t* l) {
  __builtin_amdgcn_global_load_lds((gvoid*)g, (svoid*)l, 16, 0, 0);
}

// tiled-chunk element index: layout [R/TR][K/32][TR][4 chunks x 8]
// chunk slot p holds source chunk q = p ^ ((r>>1)&3)  (XOR involution)
__device__ __forceinline__ long tidx(int row, int k, int K, int lgTR) {
  int TRm = (1 << lgTR) - 1;
  int q = (k >> 3) & 3;
  int p = q ^ ((row >> 1) & 3);
  return ((((long)(row >> lgTR) * (K >> 5) + (k >> 5)) << lgTR) + (row & TRm)) * 32 +
         ((long)p << 3);
}

// 8 consecutive f32 -> bf16 (plain round)
__device__ __forceinline__ bf16x8 ld8f(const float* p) {
  float4 a = *reinterpret_cast<const float4*>(p);
  float4 b = *reinterpret_cast<const float4*>(p + 4);
  bf16x8 r;
  r[0] = f2b(a.x); r[1] = f2b(a.y); r[2] = f2b(a.z); r[3] = f2b(a.w);
  r[4] = f2b(b.x); r[5] = f2b(b.y); r[6] = f2b(b.z); r[7] = f2b(b.w);
  return r;
}
// 8 consecutive f32 -> hi/lo bf16 split
__device__ __forceinline__ void split8(const float* p, bf16x8& h, bf16x8& l) {
  float4 a = *reinterpret_cast<const float4*>(p);
  float4 b = *reinterpret_cast<const float4*>(p + 4);
  float v[8] = {a.x, a.y, a.z, a.w, b.x, b.y, b.z, b.w};
#pragma unroll
  for (int j = 0; j < 8; j++) {
    bf16_t hh = f2b(v[j]);
    h[j] = hh;
    l[j] = f2b(v[j] - b2f(hh));
  }
}
// staging loader: 0 = bf16 row-major, 1 = f32 row-major, 2 = tiled bf16 TR=128
__device__ __forceinline__ bf16x8 ld8m(const void* p, int row, int k, int K, int m) {
  if (m == 1) return ld8f(reinterpret_cast<const float*>(p) + (long)row * K + k);
  if (m == 2)
    return *reinterpret_cast<const bf16x8*>(
        reinterpret_cast<const bf16_t*>(p) + tidx(row, k, K, 7));
  return *reinterpret_cast<const bf16x8*>(
      reinterpret_cast<const bf16_t*>(p) + (long)row * K + k);
}

// ---------------------------------------------------------------------------
// f32 -> hi/lo bf16 split into TILED chunk-swizzled layout.
// ---------------------------------------------------------------------------
template <int LGTR, int LGNKS>
__global__ __launch_bounds__(256) void split_tiled(
    const float* __restrict__ in, bf16_t* __restrict__ hi,
    bf16_t* __restrict__ lo, long total, int K) {
  long stride = (long)gridDim.x * 256;
  for (long o = (long)blockIdx.x * 256 + threadIdx.x; o < total; o += stride) {
    int p = (int)(o & 3);
    long t = o >> 2;
    int r = (int)(t & ((1 << LGTR) - 1));
    long t2 = t >> LGTR;
    int ks = (int)(t2 & ((1 << LGNKS) - 1));
    long rt = t2 >> LGNKS;
    long row = (rt << LGTR) + r;
    int k = (ks << 5) + ((p ^ ((r >> 1) & 3)) << 3);
    bf16x8 h, l;
    split8(in + row * K + k, h, l);
    reinterpret_cast<bf16x8*>(hi)[o] = h;
    reinterpret_cast<bf16x8*>(lo)[o] = l;
  }
}

// two equally-shaped splits in one launch (Wg, Wu), selected by blockIdx.z
template <int LGTR, int LGNKS>
__global__ __launch_bounds__(256) void split_tiled2(
    const float* __restrict__ s0, bf16_t* __restrict__ h0, bf16_t* __restrict__ l0,
    const float* __restrict__ s1, bf16_t* __restrict__ h1, bf16_t* __restrict__ l1,
    long total, int K) {
  const float* in = blockIdx.z ? s1 : s0;
  bf16_t* hi = blockIdx.z ? h1 : h0;
  bf16_t* lo = blockIdx.z ? l1 : l0;
  long stride = (long)gridDim.x * 256;
  for (long o = (long)blockIdx.x * 256 + threadIdx.x; o < total; o += stride) {
    int p = (int)(o & 3);
    long t = o >> 2;
    int r = (int)(t & ((1 << LGTR) - 1));
    long t2 = t >> LGTR;
    int ks = (int)(t2 & ((1 << LGNKS) - 1));
    long rt = t2 >> LGNKS;
    long row = (rt << LGTR) + r;
    int k = (ks << 5) + ((p ^ ((r >> 1) & 3)) << 3);
    bf16x8 h, l;
    split8(in + row * K + k, h, l);
    reinterpret_cast<bf16x8*>(hi)[o] = h;
    reinterpret_cast<bf16x8*>(lo)[o] = l;
  }
}

// ---------------------------------------------------------------------------
// Plain-bf16 NT GEMM (verified layout).
// MODE: 0 bf16 store; 1 silu(clip(v,-5,5)) bf16; 2 f32 RMW C += 0.1*v;
//       3 f32 RMW C = C*aux[row] + 0.1*v
// ---------------------------------------------------------------------------
template <int WM, int WN, int MODE>
__global__ __launch_bounds__(256) void gemm_nt_b(
    const void* __restrict__ Ag, const void* __restrict__ Bg,
    void* __restrict__ Cv, int M, int Nn, int K,
    const float* __restrict__ aux, int aF, int bF) {
  constexpr int BM = 2 * WM, BN = 2 * WN, AM = WM / 16, AN = WN / 16;
  constexpr int LDT = 40;
  __shared__ alignas(16) bf16_t As[BM * LDT];
  __shared__ alignas(16) bf16_t Bs[BN * LDT];

  const int tid = threadIdx.x;
  const int wave = tid >> 6, lane = tid & 63;
  const int wr = wave >> 1, wc = wave & 1;
  const int quad = lane >> 4, l16 = lane & 15;
  const int rowA0 = blockIdx.y * BM, rowB0 = blockIdx.x * BN;

  f32x4 acc[AM][AN] = {};

  for (int k0 = 0; k0 < K; k0 += 32) {
    for (int c = tid; c < BM * 4; c += 256) {
      int r = c >> 2, kc = c & 3;
      *reinterpret_cast<bf16x8*>(&As[r * LDT + kc * 8]) =
          ld8m(Ag, rowA0 + r, k0 + kc * 8, K, aF);
    }
    for (int c = tid; c < BN * 4; c += 256) {
      int r = c >> 2, kc = c & 3;
      *reinterpret_cast<bf16x8*>(&Bs[r * LDT + kc * 8]) =
          ld8m(Bg, rowB0 + r, k0 + kc * 8, K, bF);
    }
    __syncthreads();
    bf16x8 af[AM], bfv[AN];
#pragma unroll
    for (int i = 0; i < AM; i++)
      af[i] = *reinterpret_cast<bf16x8*>(&As[(wr * WM + i * 16 + l16) * LDT + quad * 8]);
#pragma unroll
    for (int j = 0; j < AN; j++)
      bfv[j] = *reinterpret_cast<bf16x8*>(&Bs[(wc * WN + j * 16 + l16) * LDT + quad * 8]);
#pragma unroll
    for (int i = 0; i < AM; i++)
#pragma unroll
      for (int j = 0; j < AN; j++)
        acc[i][j] = __builtin_amdgcn_mfma_f32_16x16x32_bf16(af[i], bfv[j], acc[i][j], 0, 0, 0);
    __syncthreads();
  }

  // C/D: col = lane&15, row = quad*4 + reg
#pragma unroll
  for (int i = 0; i < AM; i++)
#pragma unroll
    for (int j = 0; j < AN; j++)
#pragma unroll
      for (int r = 0; r < 4; r++) {
        int row = rowA0 + wr * WM + i * 16 + quad * 4 + r;
        int col = rowB0 + wc * WN + j * 16 + l16;
        long o = (long)row * Nn + col;
        float v = acc[i][j][r];
        if constexpr (MODE == 0) {
          reinterpret_cast<bf16_t*>(Cv)[o] = f2b(v);
        } else if constexpr (MODE == 1) {
          v = fminf(fmaxf(v, -5.f), 5.f);
          reinterpret_cast<bf16_t*>(Cv)[o] = f2b(siluf(v));
        } else if constexpr (MODE == 2) {
          float* C = reinterpret_cast<float*>(Cv);
          C[o] = C[o] + 0.1f * v;
        } else {
          float* C = reinterpret_cast<float*>(Cv);
          C[o] = C[o] * aux[row] + 0.1f * v;
        }
      }
}

// ---------------------------------------------------------------------------
// Fused gate/up, TILED inputs, gll16 staging, single buffer + XCD swizzle.
// ---------------------------------------------------------------------------
__global__ __launch_bounds__(256) void gemm_gu_g(
    const bf16_t* __restrict__ xhT, const bf16_t* __restrict__ xlT,
    const bf16_t* __restrict__ WghT, const bf16_t* __restrict__ WglT,
    const bf16_t* __restrict__ WuhT, const bf16_t* __restrict__ WulT,
    bf16_t* __restrict__ Hh, bf16_t* __restrict__ Hl) {
  __shared__ alignas(16) bf16_t Ah[128 * 32];
  __shared__ alignas(16) bf16_t Al[128 * 32];
  __shared__ alignas(16) bf16_t B1h[64 * 32];
  __shared__ alignas(16) bf16_t B1l[64 * 32];
  __shared__ alignas(16) bf16_t B2h[64 * 32];
  __shared__ alignas(16) bf16_t B2l[64 * 32];

  const int tid = threadIdx.x;
  const int wave = tid >> 6, lane = tid & 63;
  const int wr = wave >> 1, wc = wave & 1;
  const int quad = lane >> 4, l16 = lane & 15;
  const int sw = (quad ^ ((l16 >> 1) & 3)) << 3;
  // XCD swizzle: each XCD gets contiguous bm rows (grid 32x64=2048, %8==0)
  const int lid = blockIdx.y * gridDim.x + blockIdx.x;
  const int nper = (gridDim.x * gridDim.y) >> 3;
  const int nl = (lid & 7) * nper + (lid >> 3);
  const int bm = nl >> 5, bn = nl & 31;  // gridDim.x == 32
  constexpr int nks = D / 32;
  const int wo = wave << 9;

  f32x4 ag[4][2] = {}, au[4][2] = {};

  for (int ks = 0; ks < nks; ks++) {
    long ao = (((long)bm * nks + ks) << 12) + wo + lane * 8;
    long bo = (((long)bn * nks + ks) << 11) + wo + lane * 8;
    gll16(xhT + ao, Ah + wo);
    gll16(xhT + ao + 2048, Ah + wo + 2048);
    gll16(xlT + ao, Al + wo);
    gll16(xlT + ao + 2048, Al + wo + 2048);
    gll16(WghT + bo, B1h + wo);
    gll16(WglT + bo, B1l + wo);
    gll16(WuhT + bo, B2h + wo);
    gll16(WulT + bo, B2l + wo);
    __syncthreads();  // drains vmcnt -> LDS ready
    bf16x8 afh[4], afl[4], b1h[2], b1l[2], b2h[2], b2l[2];
#pragma unroll
    for (int i = 0; i < 4; i++) {
      int ro = (wr * 64 + i * 16 + l16) * 32 + sw;
      afh[i] = *reinterpret_cast<bf16x8*>(&Ah[ro]);
      afl[i] = *reinterpret_cast<bf16x8*>(&Al[ro]);
    }
#pragma unroll
    for (int j = 0; j < 2; j++) {
      int ro = (wc * 32 + j * 16 + l16) * 32 + sw;
      b1h[j] = *reinterpret_cast<bf16x8*>(&B1h[ro]);
      b1l[j] = *reinterpret_cast<bf16x8*>(&B1l[ro]);
      b2h[j] = *reinterpret_cast<bf16x8*>(&B2h[ro]);
      b2l[j] = *reinterpret_cast<bf16x8*>(&B2l[ro]);
    }
#pragma unroll
    for (int i = 0; i < 4; i++)
#pragma unroll
      for (int j = 0; j < 2; j++) {
        ag[i][j] = __builtin_amdgcn_mfma_f32_16x16x32_bf16(afh[i], b1h[j], ag[i][j], 0, 0, 0);
        ag[i][j] = __builtin_amdgcn_mfma_f32_16x16x32_bf16(afh[i], b1l[j], ag[i][j], 0, 0, 0);
        ag[i][j] = __builtin_amdgcn_mfma_f32_16x16x32_bf16(afl[i], b1h[j], ag[i][j], 0, 0, 0);
        au[i][j] = __builtin_amdgcn_mfma_f32_16x16x32_bf16(afh[i], b2h[j], au[i][j], 0, 0, 0);
        au[i][j] = __builtin_amdgcn_mfma_f32_16x16x32_bf16(afh[i], b2l[j], au[i][j], 0, 0, 0);
        au[i][j] = __builtin_amdgcn_mfma_f32_16x16x32_bf16(afl[i], b2h[j], au[i][j], 0, 0, 0);
      }
    __syncthreads();
  }

#pragma unroll
  for (int i = 0; i < 4; i++)
#pragma unroll
    for (int j = 0; j < 2; j++)
#pragma unroll
      for (int r = 0; r < 4; r++) {
        int row = bm * 128 + wr * 64 + i * 16 + quad * 4 + r;
        int col = bn * 64 + wc * 32 + j * 16 + l16;
        long o = tidx(row, col, H, 7) + (col & 7);
        float v = siluf(ag[i][j][r]) * au[i][j][r];
        bf16_t hh = f2b(v);
        Hh[o] = hh;
        Hl[o] = f2b(v - b2f(hh));
      }
}

// ---------------------------------------------------------------------------
// Down-proj + folded concat, XCD swizzle.
// out[n,d] = wsum[n] * ( hidden@Wd^T  +  hw2'@Mb2'^T )
// hw2' = [0.1/wsum*hw | 0.1*adpre] (pre-scaled by producers), K2=256.
// Concat k-steps stage row-major hw2/Mb2 via gll16 with per-lane
// pre-swizzled GLOBAL source (linear LDS dest), read with same sw.
// ---------------------------------------------------------------------------
__global__ __launch_bounds__(256) void gemm_dn_g(
    const bf16_t* __restrict__ HhT, const bf16_t* __restrict__ HlT,
    const bf16_t* __restrict__ WdhT, const bf16_t* __restrict__ WdlT,
    const bf16_t* __restrict__ hw2, const bf16_t* __restrict__ Mb2,
    const float* __restrict__ wsum, float* __restrict__ Cg) {
  __shared__ alignas(16) bf16_t Ah[128 * 32];
  __shared__ alignas(16) bf16_t Al[128 * 32];
  __shared__ alignas(16) bf16_t Bh[128 * 32];
  __shared__ alignas(16) bf16_t Bl[128 * 32];

  const int tid = threadIdx.x;
  const int wave = tid >> 6, lane = tid & 63;
  const int wr = wave >> 1, wc = wave & 1;
  const int quad = lane >> 4, l16 = lane & 15;
  const int sw = (quad ^ ((l16 >> 1) & 3)) << 3;
  // XCD swizzle (grid 8x64=512, %8==0)
  const int lid = blockIdx.y * gridDim.x + blockIdx.x;
  const int nper = (gridDim.x * gridDim.y) >> 3;
  const int nl = (lid & 7) * nper + (lid >> 3);
  const int by = nl >> 3, bx = nl & 7;  // gridDim.x == 8
  constexpr int nks = H / 32;
  const int wo = wave << 9;

  f32x4 acc[4][4] = {};

  for (int ks = 0; ks < nks; ks++) {
    long ao = (((long)by * nks + ks) << 12) + wo + lane * 8;
    long bo = (((long)bx * nks + ks) << 12) + wo + lane * 8;
    gll16(HhT + ao, Ah + wo);
    gll16(HhT + ao + 2048, Ah + wo + 2048);
    gll16(HlT + ao, Al + wo);
    gll16(HlT + ao + 2048, Al + wo + 2048);
    gll16(WdhT + bo, Bh + wo);
    gll16(WdhT + bo + 2048, Bh + wo + 2048);
    gll16(WdlT + bo, Bl + wo);
    gll16(WdlT + bo + 2048, Bl + wo + 2048);
    __syncthreads();
    bf16x8 afh[4], afl[4], bfh[4], bfl[4];
#pragma unroll
    for (int i = 0; i < 4; i++) {
      int ro = (wr * 64 + i * 16 + l16) * 32 + sw;
      afh[i] = *reinterpret_cast<bf16x8*>(&Ah[ro]);
      afl[i] = *reinterpret_cast<bf16x8*>(&Al[ro]);
    }
#pragma unroll
    for (int j = 0; j < 4; j++) {
      int ro = (wc * 64 + j * 16 + l16) * 32 + sw;
      bfh[j] = *reinterpret_cast<bf16x8*>(&Bh[ro]);
      bfl[j] = *reinterpret_cast<bf16x8*>(&Bl[ro]);
    }
#pragma unroll
    for (int i = 0; i < 4; i++)
#pragma unroll
      for (int j = 0; j < 4; j++) {
        acc[i][j] = __builtin_amdgcn_mfma_f32_16x16x32_bf16(afh[i], bfh[j], acc[i][j], 0, 0, 0);
        acc[i][j] = __builtin_amdgcn_mfma_f32_16x16x32_bf16(afh[i], bfl[j], acc[i][j], 0, 0, 0);
        acc[i][j] = __builtin_amdgcn_mfma_f32_16x16x32_bf16(afl[i], bfh[j], acc[i][j], 0, 0, 0);
      }
    __syncthreads();
  }

  // --- concat phase: 8 ksteps over K2=256, single-MFMA (plain bf16) ---
  {
    const int rrow = wave * 16 + (lane >> 2);  // LDS row this lane fills
    const int pp = lane & 3;                   // LDS chunk slot
    for (int ck = 0; ck < 8; ck++) {
      int r0 = rrow, r1 = rrow + 64;
      int q0 = (pp ^ ((r0 >> 1) & 3)) << 3;
      int q1 = (pp ^ ((r1 >> 1) & 3)) << 3;
      gll16(hw2 + ((long)(by * 128 + r0) * 256 + ck * 32 + q0), Ah + wo);
      gll16(hw2 + ((long)(by * 128 + r1) * 256 + ck * 32 + q1), Ah + wo + 2048);
      gll16(Mb2 + ((long)(bx * 128 + r0) * 256 + ck * 32 + q0), Bh + wo);
      gll16(Mb2 + ((long)(bx * 128 + r1) * 256 + ck * 32 + q1), Bh + wo + 2048);
      __syncthreads();
      bf16x8 af2[4], bf2[4];
#pragma unroll
      for (int i = 0; i < 4; i++)
        af2[i] = *reinterpret_cast<bf16x8*>(&Ah[(wr * 64 + i * 16 + l16) * 32 + sw]);
#pragma unroll
      for (int j = 0; j < 4; j++)
        bf2[j] = *reinterpret_cast<bf16x8*>(&Bh[(wc * 64 + j * 16 + l16) * 32 + sw]);
#pragma unroll
      for (int i = 0; i < 4; i++)
#pragma unroll
        for (int j = 0; j < 4; j++)
          acc[i][j] = __builtin_amdgcn_mfma_f32_16x16x32_bf16(af2[i], bf2[j], acc[i][j], 0, 0, 0);
      __syncthreads();
    }
  }

#pragma unroll
  for (int i = 0; i < 4; i++)
#pragma unroll
    for (int j = 0; j < 4; j++)
#pragma unroll
      for (int r = 0; r < 4; r++) {
        int row = by * 128 + wr * 64 + i * 16 + quad * 4 + r;
        int col = bx * 128 + wc * 64 + j * 16 + l16;
        Cg[(long)row * D + col] = wsum[row] * acc[i][j][r];
      }
}

// ---------------------------------------------------------------------------
// Fused adapt attention: outp[token][oOff+col] = cscale * (silu(clip(ai@ao^T))@ai)
// ---------------------------------------------------------------------------
__global__ __launch_bounds__(256) void fused_adapt(
    const bf16_t* __restrict__ aib, const bf16_t* __restrict__ aob,
    const bf16_t* __restrict__ aiT, bf16_t* __restrict__ outp,
    int oLd, int oOff, float cscale) {
  constexpr int LDQ = 136;
  constexpr int LDP = 72;
  __shared__ alignas(16) bf16_t Qs[64 * LDQ];
  __shared__ alignas(16) bf16_t Os[64 * LDQ];
  __shared__ alignas(16) bf16_t Ps[64 * LDP];
  __shared__ alignas(16) bf16_t Vs[128 * LDP];

  const int tid = threadIdx.x;
  const int wave = tid >> 6, lane = tid & 63;
  const int wr = wave >> 1, wc = wave & 1;
  const int quad = lane >> 4, l16 = lane & 15;
  const int b = blockIdx.y;
  const int q0 = blockIdx.x * 64;

  for (int c = tid; c < 1024; c += 256) {
    int r = c >> 4, cc = c & 15;
    *reinterpret_cast<bf16x8*>(&Qs[r * LDQ + cc * 8]) =
        *reinterpret_cast<const bf16x8*>(&aib[((long)b * S + q0 + r) * A + cc * 8]);
  }

  f32x4 o[2][4] = {};

  for (int tt = 0; tt < S / 64; tt++) {
    const int t0 = tt * 64;
    __syncthreads();
    for (int c = tid; c < 1024; c += 256) {
      int r = c >> 4, cc = c & 15;
      *reinterpret_cast<bf16x8*>(&Os[r * LDQ + cc * 8]) =
          *reinterpret_cast<const bf16x8*>(&aob[((long)b * S + t0 + r) * A + cc * 8]);
    }
    for (int c = tid; c < 1024; c += 256) {
      int r = c >> 3, cc = c & 7;
      *reinterpret_cast<bf16x8*>(&Vs[r * LDP + cc * 8]) =
          *reinterpret_cast<const bf16x8*>(&aiT[((long)b * A + r) * S + t0 + cc * 8]);
    }
    __syncthreads();
    f32x4 p[2][2] = {};
#pragma unroll
    for (int ks = 0; ks < 4; ks++) {
      bf16x8 af[2], bfv[2];
#pragma unroll
      for (int i = 0; i < 2; i++)
        af[i] = *reinterpret_cast<bf16x8*>(&Qs[(wr * 32 + i * 16 + l16) * LDQ + ks * 32 + quad * 8]);
#pragma unroll
      for (int j = 0; j < 2; j++)
        bfv[j] = *reinterpret_cast<bf16x8*>(&Os[(wc * 32 + j * 16 + l16) * LDQ + ks * 32 + quad * 8]);
#pragma unroll
      for (int i = 0; i < 2; i++)
#pragma unroll
        for (int j = 0; j < 2; j++)
          p[i][j] = __builtin_amdgcn_mfma_f32_16x16x32_bf16(af[i], bfv[j], p[i][j], 0, 0, 0);
    }
#pragma unroll
    for (int i = 0; i < 2; i++)
#pragma unroll
      for (int j = 0; j < 2; j++)
#pragma unroll
        for (int r = 0; r < 4; r++) {
          int row = wr * 32 + i * 16 + quad * 4 + r;
          int col = wc * 32 + j * 16 + l16;
          float v = fminf(fmaxf(p[i][j][r], -5.f), 5.f);
          Ps[row * LDP + col] = f2b(siluf(v));
        }
    __syncthreads();
#pragma unroll
    for (int ks = 0; ks < 2; ks++) {
      bf16x8 paf[2], vbf[4];
#pragma unroll
      for (int i = 0; i < 2; i++)
        paf[i] = *reinterpret_cast<bf16x8*>(&Ps[(wr * 32 + i * 16 + l16) * LDP + ks * 32 + quad * 8]);
#pragma unroll
      for (int j = 0; j < 4; j++)
        vbf[j] = *reinterpret_cast<bf16x8*>(&Vs[(wc * 64 + j * 16 + l16) * LDP + ks * 32 + quad * 8]);
#pragma unroll
      for (int i = 0; i < 2; i++)
#pragma unroll
        for (int j = 0; j < 4; j++)
          o[i][j] = __builtin_amdgcn_mfma_f32_16x16x32_bf16(paf[i], vbf[j], o[i][j], 0, 0, 0);
    }
  }

#pragma unroll
  for (int i = 0; i < 2; i++)
#pragma unroll
    for (int j = 0; j < 4; j++)
#pragma unroll
      for (int r = 0; r < 4; r++) {
        int row = q0 + wr * 32 + i * 16 + quad * 4 + r;
        int col = wc * 64 + j * 16 + l16;
        long token = (long)b * S + row;
        outp[token * oLd + oOff + col] = f2b(o[i][j][r] * cscale);
      }
}

// ---------------------------------------------------------------------------
// [D,A] = Af32 @ Bbf16^T, split-K x8 into f32 partials (Mb and WdWap).
// ---------------------------------------------------------------------------
__global__ __launch_bounds__(256) void gemm_mb_splitk(
    const float* __restrict__ Ag, const bf16_t* __restrict__ Bg,
    float* __restrict__ Mp, int M, int Nn, int K) {
  constexpr int BM = 64, BN = 64, LDT = 40;
  __shared__ alignas(16) bf16_t As[BM * LDT];
  __shared__ alignas(16) bf16_t Bs[BN * LDT];
  const int tid = threadIdx.x;
  const int wave = tid >> 6, lane = tid & 63;
  const int wr = wave >> 1, wc = wave & 1;
  const int quad = lane >> 4, l16 = lane & 15;
  const int rowA0 = blockIdx.y * BM, rowB0 = blockIdx.x * BN;
  const int kz = blockIdx.z;
  const int ks0 = kz * (K / 8), ks1 = ks0 + K / 8;

  f32x4 acc[2][2] = {};
  for (int k0 = ks0; k0 < ks1; k0 += 32) {
    for (int c = tid; c < BM * 4; c += 256) {
      int r = c >> 2, kc = c & 3;
      *reinterpret_cast<bf16x8*>(&As[r * LDT + kc * 8]) =
          ld8f(Ag + (long)(rowA0 + r) * K + k0 + kc * 8);
    }
    for (int c = tid; c < BN * 4; c += 256) {
      int r = c >> 2, kc = c & 3;
      *reinterpret_cast<bf16x8*>(&Bs[r * LDT + kc * 8]) =
          *reinterpret_cast<const bf16x8*>(&Bg[(long)(rowB0 + r) * K + k0 + kc * 8]);
    }
    __syncthreads();
    bf16x8 af[2], bfv[2];
#pragma unroll
    for (int i = 0; i < 2; i++)
      af[i] = *reinterpret_cast<bf16x8*>(&As[(wr * 32 + i * 16 + l16) * LDT + quad * 8]);
#pragma unroll
    for (int j = 0; j < 2; j++)
      bfv[j] = *reinterpret_cast<bf16x8*>(&Bs[(wc * 32 + j * 16 + l16) * LDT + quad * 8]);
#pragma unroll
    for (int i = 0; i < 2; i++)
#pragma unroll
      for (int j = 0; j < 2; j++)
        acc[i][j] = __builtin_amdgcn_mfma_f32_16x16x32_bf16(af[i], bfv[j], acc[i][j], 0, 0, 0);
    __syncthreads();
  }
#pragma unroll
  for (int i = 0; i < 2; i++)
#pragma unroll
    for (int j = 0; j < 2; j++)
#pragma unroll
      for (int r = 0; r < 4; r++) {
        int row = rowA0 + wr * 32 + i * 16 + quad * 4 + r;
        int col = rowB0 + wc * 32 + j * 16 + l16;
        Mp[(long)kz * M * Nn + (long)row * Nn + col] = acc[i][j][r];
      }
}

// combine partials into strided bf16 destination: out[(i>>7)*ld + coff + (i&127)]
__global__ __launch_bounds__(256) void mb_combine(
    const float* __restrict__ Mp, bf16_t* __restrict__ outp, int total,
    int ld, int coff) {
  int i = blockIdx.x * 256 + threadIdx.x;
  if (i >= total) return;
  float s = 0.f;
#pragma unroll
  for (int z = 0; z < 8; z++) s += Mp[(long)z * total + i];
  outp[(long)(i >> 7) * ld + coff + (i & 127)] = f2b(s);
}

// ---------------------------------------------------------------------------
// Fallback-path kernels (f32 inputs, in-loop split) — unchanged, proven.
// ---------------------------------------------------------------------------
__global__ __launch_bounds__(256) void gemm_dn_hl(
    const float* __restrict__ Ag, const float* __restrict__ Bg,
    float* __restrict__ Cg, int M, int Nn, int K) {
  constexpr int BM = 128, BN = 128, LDT = 40;
  __shared__ alignas(16) bf16_t Ah[BM * LDT];
  __shared__ alignas(16) bf16_t Al[BM * LDT];
  __shared__ alignas(16) bf16_t Bh[BN * LDT];
  __shared__ alignas(16) bf16_t Bl[BN * LDT];

  const int tid = threadIdx.x;
  const int wave = tid >> 6, lane = tid & 63;
  const int wr = wave >> 1, wc = wave & 1;
  const int quad = lane >> 4, l16 = lane & 15;
  const int rowA0 = blockIdx.y * BM, rowB0 = blockIdx.x * BN;

  f32x4 acc[4][4] = {};

  for (int k0 = 0; k0 < K; k0 += 32) {
    for (int c = tid; c < BM * 4; c += 256) {
      int r = c >> 2, kc = c & 3;
      bf16x8 h, l;
      split8(&Ag[(long)(rowA0 + r) * K + k0 + kc * 8], h, l);
      *reinterpret_cast<bf16x8*>(&Ah[r * LDT + kc * 8]) = h;
      *reinterpret_cast<bf16x8*>(&Al[r * LDT + kc * 8]) = l;
    }
    for (int c = tid; c < BN * 4; c += 256) {
      int r = c >> 2, kc = c & 3;
      bf16x8 h, l;
      split8(&Bg[(long)(rowB0 + r) * K + k0 + kc * 8], h, l);
      *reinterpret_cast<bf16x8*>(&Bh[r * LDT + kc * 8]) = h;
      *reinterpret_cast<bf16x8*>(&Bl[r * LDT + kc * 8]) = l;
    }
    __syncthreads();
    bf16x8 afh[4], afl[4], bfh[4], bfl[4];
#pragma unroll
    for (int i = 0; i < 4; i++) {
      int ro = (wr * 64 + i * 16 + l16) * LDT + quad * 8;
      afh[i] = *reinterpret_cast<bf16x8*>(&Ah[ro]);
      afl[i] = *reinterpret_cast<bf16x8*>(&Al[ro]);
    }
#pragma unroll
    for (int j = 0; j < 4; j++) {
      int ro = (wc * 64 + j * 16 + l16) * LDT + quad * 8;
      bfh[j] = *reinterpret_cast<bf16x8*>(&Bh[ro]);
      bfl[j] = *reinterpret_cast<bf16x8*>(&Bl[ro]);
    }
#pragma unroll
    for (int i = 0; i < 4; i++)
#pragma unroll
      for (int j = 0; j < 4; j++) {
        acc[i][j] = __builtin_amdgcn_mfma_f32_16x16x32_bf16(afh[i], bfh[j], acc[i][j], 0, 0, 0);
        acc[i][j] = __builtin_amdgcn_mfma_f32_16x16x32_bf16(afh[i], bfl[j], acc[i][j], 0, 0, 0);
        acc[i][j] = __builtin_amdgcn_mfma_f32_16x16x32_bf16(afl[i], bfh[j], acc[i][j], 0, 0, 0);
      }
    __syncthreads();
  }

#pragma unroll
  for (int i = 0; i < 4; i++)
#pragma unroll
    for (int j = 0; j < 4; j++)
#pragma unroll
      for (int r = 0; r < 4; r++) {
        int row = rowA0 + wr * 64 + i * 16 + quad * 4 + r;
        int col = rowB0 + wc * 64 + j * 16 + l16;
        Cg[(long)row * Nn + col] = acc[i][j][r];
      }
}

__global__ __launch_bounds__(256) void gemm_gu_hl(
    const float* __restrict__ x, const float* __restrict__ Wg,
    const float* __restrict__ Wu, float* __restrict__ Cg, int M, int Nn, int K) {
  constexpr int BM = 128, BN = 64, LDT = 40;
  __shared__ alignas(16) bf16_t Ah[BM * LDT];
  __shared__ alignas(16) bf16_t Al[BM * LDT];
  __shared__ alignas(16) bf16_t B1h[BN * LDT];
  __shared__ alignas(16) bf16_t B1l[BN * LDT];
  __shared__ alignas(16) bf16_t B2h[BN * LDT];
  __shared__ alignas(16) bf16_t B2l[BN * LDT];

  const int tid = threadIdx.x;
  const int wave = tid >> 6, lane = tid & 63;
  const int wr = wave >> 1, wc = wave & 1;
  const int quad = lane >> 4, l16 = lane & 15;
  const int rowA0 = blockIdx.y * BM, rowB0 = blockIdx.x * BN;

  f32x4 ag[4][2] = {}, au[4][2] = {};

  for (int k0 = 0; k0 < K; k0 += 32) {
    for (int c = tid; c < BM * 4; c += 256) {
      int r = c >> 2, kc = c & 3;
      bf16x8 h, l;
      split8(&x[(long)(rowA0 + r) * K + k0 + kc * 8], h, l);
      *reinterpret_cast<bf16x8*>(&Ah[r * LDT + kc * 8]) = h;
      *reinterpret_cast<bf16x8*>(&Al[r * LDT + kc * 8]) = l;
    }
    for (int c = tid; c < BN * 4; c += 256) {
      int r = c >> 2, kc = c & 3;
      long idx = (long)(rowB0 + r) * K + k0 + kc * 8;
      bf16x8 h, l;
      split8(&Wg[idx], h, l);
      *reinterpret_cast<bf16x8*>(&B1h[r * LDT + kc * 8]) = h;
      *reinterpret_cast<bf16x8*>(&B1l[r * LDT + kc * 8]) = l;
      split8(&Wu[idx], h, l);
      *reinterpret_cast<bf16x8*>(&B2h[r * LDT + kc * 8]) = h;
      *reinterpret_cast<bf16x8*>(&B2l[r * LDT + kc * 8]) = l;
    }
    __syncthreads();
    bf16x8 afh[4], afl[4], b1h[2], b1l[2], b2h[2], b2l[2];
#pragma unroll
    for (int i = 0; i < 4; i++) {
      int ro = (wr * 64 + i * 16 + l16) * LDT + quad * 8;
      afh[i] = *reinterpret_cast<bf16x8*>(&Ah[ro]);
      afl[i] = *reinterpret_cast<bf16x8*>(&Al[ro]);
    }
#pragma unroll
    for (int j = 0; j < 2; j++) {
      int ro = (wc * 32 + j * 16 + l16) * LDT + quad * 8;
      b1h[j] = *reinterpret_cast<bf16x8*>(&B1h[ro]);
      b1l[j] = *reinterpret_cast<bf16x8*>(&B1l[ro]);
      b2h[j] = *reinterpret_cast<bf16x8*>(&B2h[ro]);
      b2l[j] = *reinterpret_cast<bf16x8*>(&B2l[ro]);
    }
#pragma unroll
    for (int i = 0; i < 4; i++)
#pragma unroll
      for (int j = 0; j < 2; j++) {
        ag[i][j] = __builtin_amdgcn_mfma_f32_16x16x32_bf16(afh[i], b1h[j], ag[i][j], 0, 0, 0);
        ag[i][j] = __builtin_amdgcn_mfma_f32_16x16x32_bf16(afh[i], b1l[j], ag[i][j], 0, 0, 0);
        ag[i][j] = __builtin_amdgcn_mfma_f32_16x16x32_bf16(afl[i], b1h[j], ag[i][j], 0, 0, 0);
        au[i][j] = __builtin_amdgcn_mfma_f32_16x16x32_bf16(afh[i], b2h[j], au[i][j], 0, 0, 0);
        au[i][j] = __builtin_amdgcn_mfma_f32_16x16x32_bf16(afh[i], b2l[j], au[i][j], 0, 0, 0);
        au[i][j] = __builtin_amdgcn_mfma_f32_16x16x32_bf16(afl[i], b2h[j], au[i][j], 0, 0, 0);
      }
    __syncthreads();
  }

#pragma unroll
  for (int i = 0; i < 4; i++)
#pragma unroll
    for (int j = 0; j < 2; j++)
#pragma unroll
      for (int r = 0; r < 4; r++) {
        int row = rowA0 + wr * 64 + i * 16 + quad * 4 + r;
        int col = rowB0 + wc * 32 + j * 16 + l16;
        Cg[(long)row * Nn + col] = siluf(ag[i][j][r]) * au[i][j][r];
      }
}

// ---------------------------------------------------------------------------
// Router (no global atomics, per-block partials).
// ---------------------------------------------------------------------------
__global__ __launch_bounds__(256) void router_kernel(
    const float* __restrict__ x, const float* __restrict__ Wgr,
    const float* __restrict__ Wer, int* __restrict__ eidx,
    float* __restrict__ fw, float* __restrict__ wsum,
    float* __restrict__ lpart) {
  __shared__ float part[4][12];
  const int wv = threadIdx.x >> 6;
  const int lane = threadIdx.x & 63;
  const int token = blockIdx.x * 4 + wv;
  if (lane < 12) part[wv][lane] = 0.f;
  const float* xp = x + (long)token * D;
  float xr[16];
#pragma unroll
  for (int i = 0; i < 16; i++) xr[i] = xp[lane + i * 64];
  float dots[6];
#pragma unroll
  for (int w = 0; w < 6; w++) {
    const float* wp = (w < 2) ? (Wgr + (long)w * D) : (Wer + (long)(w - 2) * D);
    float s = 0.f;
#pragma unroll
    for (int i = 0; i < 16; i++) s += xr[i] * wp[lane + i * 64];
#pragma unroll
    for (int off = 32; off; off >>= 1) s += __shfl_xor(s, off);
    dots[w] = s;
  }
  if (lane == 0) {
    float gl0 = dots[0], gl1 = dots[1];
    float mg = fmaxf(gl0, gl1);
    float e0 = expf(gl0 - mg), e1 = expf(gl1 - mg);
    float inv = 1.f / (e0 + e1);
    float gp0 = e0 * inv, gp1 = e1 * inv;
    int gi = (gp1 > gp0) ? 1 : 0;
    float gw = gi ? gp1 : gp0;
    float el[4] = {dots[2], dots[3], dots[4], dots[5]};
    float me = fmaxf(fmaxf(el[0], el[1]), fmaxf(el[2], el[3]));
    float ep[4], es = 0.f;
#pragma unroll
    for (int j = 0; j < 4; j++) { ep[j] = expf(el[j] - me); es += ep[j]; }
    float inve = 1.f / es;
#pragma unroll
    for (int j = 0; j < 4; j++) ep[j] *= inve;
    int i1 = 0;
    for (int j = 1; j < 4; j++) if (ep[j] > ep[i1]) i1 = j;
    int i2 = (i1 == 0) ? 1 : 0;
    for (int j = 0; j < 4; j++) if (j != i1 && j != i2 && ep[j] > ep[i2]) i2 = j;
    float l1 = ep[i1], l2 = ep[i2];
    float ils = 1.f / (l1 + l2 + 1e-7f);
    float f1 = gw * l1 * ils, f2 = gw * l2 * ils;
    eidx[token * 2] = gi * 4 + i1;
    eidx[token * 2 + 1] = gi * 4 + i2;
    fw[token * 2] = f1;
    fw[token * 2 + 1] = f2;
    wsum[token] = f1 + f2;
    part[wv][gi * 4 + i1] = f1;
    part[wv][gi * 4 + i2] = f2;
    part[wv][8] = gl0 * gl0 + gl1 * gl1;
    part[wv][9] = el[0] * el[0] + el[1] * el[1] + el[2] * el[2] + el[3] * el[3];
  }
  __syncthreads();
  if (threadIdx.x < 12) {
    lpart[(long)blockIdx.x * 12 + threadIdx.x] =
        part[0][threadIdx.x] + part[1][threadIdx.x] +
        part[2][threadIdx.x] + part[3][threadIdx.x];
  }
}

// ---------------------------------------------------------------------------
// Row LayerNorm over A=128 (bf16 in ws, f32 g/b, bf16 out).
// ---------------------------------------------------------------------------
__global__ __launch_bounds__(256) void ln_rows(
    const bf16_t* __restrict__ in, const float* __restrict__ g,
    const float* __restrict__ b, bf16_t* __restrict__ out) {
  const int row = blockIdx.x * 4 + (threadIdx.x >> 6);
  const int lane = threadIdx.x & 63;
  const bf16_t* p = in + (long)row * A;
  float x0 = b2f(p[lane]), x1 = b2f(p[lane + 64]);
  float s = x0 + x1;
#pragma unroll
  for (int off = 32; off; off >>= 1) s += __shfl_xor(s, off);
  float mean = s * (1.f / 128.f);
  float d0 = x0 - mean, d1 = x1 - mean;
  float q = d0 * d0 + d1 * d1;
#pragma unroll
  for (int off = 32; off; off >>= 1) q += __shfl_xor(q, off);
  float r = rsqrtf(q * (1.f / 128.f) + 1e-5f);
  bf16_t* po = out + (long)row * A;
  po[lane] = f2b(d0 * r * g[lane] + b[lane]);
  po[lane + 64] = f2b(d1 * r * g[lane + 64] + b[lane + 64]);
}

// ---------------------------------------------------------------------------
// Transpose [z,R,C] -> [z,C,R], bf16 out; input f32 (isf=1) or bf16.
// ---------------------------------------------------------------------------
__global__ __launch_bounds__(256) void transpose2d(
    const void* __restrict__ in, bf16_t* __restrict__ out, int R, int C, int isf) {
  __shared__ bf16_t t[32][33];
  const long zb = blockIdx.z;
  const long ib = zb * (long)R * C;
  bf16_t* op = out + zb * (long)R * C;
  const int r0 = blockIdx.y * 32, c0 = blockIdx.x * 32;
  const int tx = threadIdx.x & 31, ty = threadIdx.x >> 5;
#pragma unroll
  for (int i = 0; i < 4; i++) {
    long idx = ib + (long)(r0 + ty + i * 8) * C + c0 + tx;
    t[ty + i * 8][tx] = isf ? f2b(reinterpret_cast<const float*>(in)[idx])
                            : reinterpret_cast<const bf16_t*>(in)[idx];
  }
  __syncthreads();
#pragma unroll
  for (int i = 0; i < 4; i++) op[(long)(c0 + ty + i * 8) * R + r0 + tx] = t[tx][ty + i * 8];
}

// ---------------------------------------------------------------------------
// Expert branch: coalesced via WeaT[e][a][c]. Writes hw*(0.1/wsum) when wsc
// given (big path: concat-fold pre-scale), else raw (fallback).
// ---------------------------------------------------------------------------
__global__ __launch_bounds__(128) void expert_adapt(
    const bf16_t* __restrict__ h0, const bf16_t* __restrict__ WeaT,
    const float* __restrict__ ln_eg, const float* __restrict__ ln_eb,
    const int* __restrict__ eidx, const float* __restrict__ fw,
    bf16_t* __restrict__ hw, int ld, const float* __restrict__ wsc) {
  const int n = blockIdx.x;
  const int c = threadIdx.x;
  __shared__ float h0s[128];
  __shared__ float red[4];
  h0s[c] = b2f(h0[(long)n * A + c]);
  __syncthreads();
  float out = 0.f;
  for (int k = 0; k < 2; k++) {
    int e = eidx[n * 2 + k];
    e = min(max(e, 0), E - 1);
    float w = fw[n * 2 + k];
    const bf16_t* Wc = WeaT + (long)e * A * A + c;
    float t = 0.f;
#pragma unroll 8
    for (int a = 0; a < 128; a++) t += b2f(Wc[(long)a * A]) * h0s[a];
    float s = t, q = t * t;
#pragma unroll
    for (int off = 32; off; off >>= 1) { s += __shfl_xor(s, off); q += __shfl_xor(q, off); }
    if ((c & 63) == 0) { red[(c >> 6) * 2] = s; red[(c >> 6) * 2 + 1] = q; }
    __syncthreads();
    float Sx = red[0] + red[2], Qx = red[1] + red[3];
    float mean = Sx * (1.f / 128.f);
    float var = Qx * (1.f / 128.f) - mean * mean;
    float r = rsqrtf(var + 1e-5f);
    out += w * ((t - mean) * r * ln_eg[e * A + c] + ln_eb[e * A + c]);
    __syncthreads();
  }
  float sc = wsc ? (0.1f / wsc[n]) : 1.f;
  hw[(long)n * ld + c] = f2b(out * sc);
}

// ---------------------------------------------------------------------------
// Loss finalize.
// ---------------------------------------------------------------------------
__global__ __launch_bounds__(256) void finalize_loss(
    const float* __restrict__ lpart, int nblk, float* __restrict__ outv) {
  float acc[10] = {};
  for (int b = threadIdx.x; b < nblk; b += 256) {
    const float* p = lpart + (long)b * 12;
#pragma unroll
    for (int c = 0; c < 10; c++) acc[c] += p[c];
  }
  __shared__ float red[10][4];
  const int lane = threadIdx.x & 63, wv = threadIdx.x >> 6;
#pragma unroll
  for (int c = 0; c < 10; c++) {
    float s = acc[c];
#pragma unroll
    for (int off = 32; off; off >>= 1) s += __shfl_xor(s, off);
    if (lane == 0) red[c][wv] = s;
  }
  __syncthreads();
  if (threadIdx.x == 0) {
    float loss[10];
#pragma unroll
    for (int c = 0; c < 10; c++)
      loss[c] = red[c][0] + red[c][1] + red[c][2] + red[c][3];
    float tl = 0.f;
    for (int e = 0; e < 8; e++) tl += loss[e];
    float target = tl / 8.f;
    float mse = 0.f;
    for (int e = 0; e < 8; e++) { float d = loss[e] - target; mse += d * d; }
    mse *= (1.f / 8.f);
    outv[0] = 0.001f * (mse + loss[8] / (float)(N * 2) + loss[9] / (float)(N * 4));
  }
}

// ---------------------------------------------------------------------------
extern "C" void kernel_launch(void* const* d_in, const int* in_sizes, int n_in,
                              void* d_out, int out_size, void* d_ws, size_t ws_size,
                              hipStream_t stream) {
  const float* x = (const float*)d_in[0];
  const float* Wu = (const float*)d_in[1];
  const float* Wg = (const float*)d_in[2];
  const float* Wd = (const float*)d_in[3];
  const float* Wpre = (const float*)d_in[4];
  const float* Wpost = (const float*)d_in[5];
  const float* ln_g = (const float*)d_in[6];
  const float* ln_b = (const float*)d_in[7];
  const float* Wap = (const float*)d_in[8];
  const float* Wea = (const float*)d_in[9];
  const float* ln_eg = (const float*)d_in[10];
  const float* ln_eb = (const float*)d_in[11];
  const float* Wep = (const float*)d_in[12];
  const float* Wop = (const float*)d_in[13];
  const float* Wgr = (const float*)d_in[14];
  const float* Wer = (const float*)d_in[15];
  float* out = (float*)d_out;

  char* ws = (char*)d_ws;
  size_t off = 0;
  auto alloc = [&](size_t bytes) { char* p = ws + off; off += (bytes + 255) & ~size_t(255); return p; };
  // Common allocations (~18 MB)
  float* lpart = (float*)alloc((size_t)(N / 4) * 12 * 4);
  float* wsum = (float*)alloc((size_t)N * 4);
  float* fwb = (float*)alloc((size_t)N * 2 * 4);
  int* eidx = (int*)alloc((size_t)N * 2 * 4);
  bf16_t* Mb2 = (bf16_t*)alloc((size_t)D * 256 * 2);   // [D,256] = [Mb | WdWap]
  float* Mp = (float*)alloc((size_t)8 * D * A * 4);    // split-K partials (reused)
  bf16_t* WepT = (bf16_t*)alloc((size_t)H * A * 2);
  bf16_t* WapT = (bf16_t*)alloc((size_t)H * A * 2);
  bf16_t* hw2 = (bf16_t*)alloc((size_t)N * 256 * 2);   // [N,256] = [hw' | adpre']
  bf16_t* h0b = (bf16_t*)alloc((size_t)N * A * 2);
  bf16_t* aib = (bf16_t*)alloc((size_t)N * A * 2);
  bf16_t* scrA = (bf16_t*)alloc((size_t)N * A * 2);
  bf16_t* aob = (bf16_t*)alloc((size_t)N * A * 2);
  bf16_t* WeaT = (bf16_t*)alloc((size_t)E * A * A * 2);
  bf16_t* aopre = scrA;
  bf16_t* aiT = scrA;

  // Big path: pre-split TILED hi/lo buffers (+120 MiB; total ~137.5 MiB).
  const bool big = ws_size >= ((size_t)140 << 20);
  float* hiddenF = nullptr;
  bf16_t *xh = nullptr, *xl = nullptr;
  bf16_t *Wgh = nullptr, *Wgl = nullptr, *Wuh = nullptr, *Wul = nullptr;
  bf16_t *Wdh = nullptr, *Wdl = nullptr, *Hh = nullptr, *Hl = nullptr;
  if (big) {
    xh = (bf16_t*)alloc((size_t)N * D * 2);
    xl = (bf16_t*)alloc((size_t)N * D * 2);
    Wgh = (bf16_t*)alloc((size_t)H * D * 2);
    Wgl = (bf16_t*)alloc((size_t)H * D * 2);
    Wuh = (bf16_t*)alloc((size_t)H * D * 2);
    Wul = (bf16_t*)alloc((size_t)H * D * 2);
    Wdh = (bf16_t*)alloc((size_t)D * H * 2);
    Wdl = (bf16_t*)alloc((size_t)D * H * 2);
    Hh = (bf16_t*)alloc((size_t)N * H * 2);
    Hl = (bf16_t*)alloc((size_t)N * H * 2);
  } else {
    hiddenF = (float*)alloc((size_t)N * H * 4);
  }
  (void)ws_size; (void)in_sizes; (void)n_in; (void)out_size;

  const dim3 blk(256);

  router_kernel<<<dim3(N / 4), blk, 0, stream>>>(x, Wgr, Wer, eidx, fwb, wsum, lpart);
  transpose2d<<<dim3(A / 32, A / 32, E), blk, 0, stream>>>(Wea, WeaT, A, A, 1);

  if (big) {
    // tiled splits: x TR=128 K=D; Wg+Wu merged TR=64 K=D; Wd TR=128 K=H
    split_tiled<7, 5><<<dim3(2048), blk, 0, stream>>>(x, xh, xl, (long)N * D / 8, D);
    split_tiled2<6, 5><<<dim3(512, 1, 2), blk, 0, stream>>>(
        Wg, Wgh, Wgl, Wu, Wuh, Wul, (long)H * D / 8, D);
    split_tiled<7, 6><<<dim3(512), blk, 0, stream>>>(Wd, Wdh, Wdl, (long)D * H / 8, H);
    // hidden0 (tiled Hh/Hl) = silu(x@Wg^T)*(x@Wu^T)
    gemm_gu_g<<<dim3(H / 64, N / 128), blk, 0, stream>>>(
        xh, xl, Wgh, Wgl, Wuh, Wul, Hh, Hl);
    // h0 = x@Wpre^T  (A from tiled xh)
    gemm_nt_b<16, 32, 0><<<dim3(A / 64, N / 32), blk, 0, stream>>>(
        xh, Wpre, h0b, N, A, D, nullptr, 2, 1);
    ln_rows<<<dim3(N / 4), blk, 0, stream>>>(h0b, ln_g, ln_b, aib);
    // ao_pre = hidden0@Wpost^T
    gemm_nt_b<16, 32, 0><<<dim3(A / 64, N / 32), blk, 0, stream>>>(
        Hh, Wpost, aopre, N, A, H, nullptr, 2, 1);
    ln_rows<<<dim3(N / 4), blk, 0, stream>>>(aopre, ln_g, ln_b, aob);
    transpose2d<<<dim3(A / 32, S / 32, Bb), blk, 0, stream>>>(aib, aiT, S, A, 0);
    // Mb2 = [Wop@Wep | Wd@Wap]
    transpose2d<<<dim3(A / 32, H / 32, 1), blk, 0, stream>>>(Wep, WepT, H, A, 1);
    transpose2d<<<dim3(A / 32, H / 32, 1), blk, 0, stream>>>(Wap, WapT, H, A, 1);
    gemm_mb_splitk<<<dim3(A / 64, D / 64, 8), blk, 0, stream>>>(Wop, WepT, Mp, D, A, H);
    mb_combine<<<dim3((D * A + 255) / 256), blk, 0, stream>>>(Mp, Mb2, D * A, 256, 0);
    gemm_mb_splitk<<<dim3(A / 64, D / 64, 8), blk, 0, stream>>>(Wd, WapT, Mp, D, A, H);
    mb_combine<<<dim3((D * A + 255) / 256), blk, 0, stream>>>(Mp, Mb2, D * A, 256, 128);
    // hw2 = [0.1/wsum * hw | 0.1 * adpre]
    fused_adapt<<<dim3(S / 64, Bb), blk, 0, stream>>>(
        aib, aob, aiT, hw2, 256, 128, 0.1f);
    expert_adapt<<<dim3(N), dim3(128), 0, stream>>>(
        h0b, WeaT, ln_eg, ln_eb, eidx, fwb, hw2, 256, wsum);
    // out = wsum * (hidden0@Wd^T + hw2'@Mb2^T)  (concat folded into dn)
    gemm_dn_g<<<dim3(D / 128, N / 128), blk, 0, stream>>>(
        Hh, Hl, Wdh, Wdl, hw2, Mb2, wsum, out);
  } else {
    bf16_t* adpreb = hw2 + (size_t)N * A;  // second half of hw2 as [N,A]
    gemm_gu_hl<<<dim3(H / 64, N / 128), blk, 0, stream>>>(x, Wg, Wu, hiddenF, N, H, D);
    gemm_nt_b<16, 32, 0><<<dim3(A / 64, N / 32), blk, 0, stream>>>(
        x, Wpre, h0b, N, A, D, nullptr, 1, 1);
    ln_rows<<<dim3(N / 4), blk, 0, stream>>>(h0b, ln_g, ln_b, aib);
    gemm_nt_b<16, 32, 0><<<dim3(A / 64, N / 32), blk, 0, stream>>>(
        hiddenF, Wpost, aopre, N, A, H, nullptr, 1, 1);
    ln_rows<<<dim3(N / 4), blk, 0, stream>>>(aopre, ln_g, ln_b, aob);
    transpose2d<<<dim3(A / 32, S / 32, Bb), blk, 0, stream>>>(aib, aiT, S, A, 0);
    fused_adapt<<<dim3(S / 64, Bb), blk, 0, stream>>>(
        aib, aob, aiT, adpreb, 128, 0, 1.f);
    gemm_nt_b<64, 64, 2><<<dim3(H / 128, N / 128), blk, 0, stream>>>(
        adpreb, Wap, hiddenF, N, H, A, nullptr, 0, 1);
    gemm_dn_hl<<<dim3(D / 128, N / 128), blk, 0, stream>>>(hiddenF, Wd, out, N, D, H);
    transpose2d<<<dim3(A / 32, H / 32, 1), blk, 0, stream>>>(Wep, WepT, H, A, 1);
    gemm_mb_splitk<<<dim3(A / 64, D / 64, 8), blk, 0, stream>>>(Wop, WepT, Mp, D, A, H);
    mb_combine<<<dim3((D * A + 255) / 256), blk, 0, stream>>>(Mp, Mb2, D * A, 128, 0);
    expert_adapt<<<dim3(N), dim3(128), 0, stream>>>(
        h0b, WeaT, ln_eg, ln_eb, eidx, fwb, hw2, 128, nullptr);
    gemm_nt_b<64, 64, 3><<<dim3(D / 128, N / 128), blk, 0, stream>>>(
        hw2, Mb2, out, N, D, A, wsum, 0, 0);
  }

  finalize_loss<<<dim3(1), blk, 0, stream>>>(lpart, N / 4, out + (size_t)N * D);
}

// Round 9
// 678.960 us; speedup vs baseline: 1.1899x; 1.0774x over previous
//
#include <hip/hip_runtime.h>
#include <math.h>

// ---------------------------------------------------------------------------
// MoE layer, round 16. Base = R15 (731.5us).
// R15 post-mortem: gu XCD swizzle raised FETCH 164->278MB (HBM 23%, not
// bottleneck; time flat-to-better) -- kept. Concat fold gave most of -41us.
// Changes (all additive / bit-identical):
//  1. fused_adapt QBLK 64->32: grid 128->256 blocks (was leaving half the
//     256 CUs idle). Same per-element math + accumulation order.
//  2. Wpre/Wpost pre-converted to bf16 once (same f2b rounding as ld8f);
//     h0/aopre GEMMs use bF=0 -> staging is pure copies, no per-block f32
//     re-read + convert.
//  3. WepT/WapT transposes merged into one launch.
// B=4, S=2048, D=1024, H=2048, A=128, E=8, N=8192.
// ---------------------------------------------------------------------------

typedef __bf16 bf16_t;
typedef __attribute__((ext_vector_type(8))) __bf16 bf16x8;
typedef __attribute__((ext_vector_type(4))) float f32x4;

__device__ __forceinline__ float b2f(bf16_t v) { return (float)v; }
__device__ __forceinline__ bf16_t f2b(float v) { return (bf16_t)v; }
__device__ __forceinline__ float siluf(float v) { return v / (1.f + expf(-v)); }

static constexpr int Bb = 4, S = 2048, D = 1024, H = 2048, A = 128, E = 8;
static constexpr int N = Bb * S;

// async global->LDS, 16B per lane; LDS dest = wave-uniform base + lane*16
typedef __attribute__((address_space(1))) void gvoid;
typedef __attribute__((address_space(3))) void svoid;
__device__ __forceinline__ void gll16(const bf16_t* g, bf16_t* l) {
  __builtin_amdgcn_global_load_lds((gvoid*)g, (svoid*)l, 16, 0, 0);
}

// tiled-chunk element index: layout [R/TR][K/32][TR][4 chunks x 8]
// chunk slot p holds source chunk q = p ^ ((r>>1)&3)  (XOR involution)
__device__ __forceinline__ long tidx(int row, int k, int K, int lgTR) {
  int TRm = (1 << lgTR) - 1;
  int q = (k >> 3) & 3;
  int p = q ^ ((row >> 1) & 3);
  return ((((long)(row >> lgTR) * (K >> 5) + (k >> 5)) << lgTR) + (row & TRm)) * 32 +
         ((long)p << 3);
}

// 8 consecutive f32 -> bf16 (plain round)
__device__ __forceinline__ bf16x8 ld8f(const float* p) {
  float4 a = *reinterpret_cast<const float4*>(p);
  float4 b = *reinterpret_cast<const float4*>(p + 4);
  bf16x8 r;
  r[0] = f2b(a.x); r[1] = f2b(a.y); r[2] = f2b(a.z); r[3] = f2b(a.w);
  r[4] = f2b(b.x); r[5] = f2b(b.y); r[6] = f2b(b.z); r[7] = f2b(b.w);
  return r;
}
// 8 consecutive f32 -> hi/lo bf16 split
__device__ __forceinline__ void split8(const float* p, bf16x8& h, bf16x8& l) {
  float4 a = *reinterpret_cast<const float4*>(p);
  float4 b = *reinterpret_cast<const float4*>(p + 4);
  float v[8] = {a.x, a.y, a.z, a.w, b.x, b.y, b.z, b.w};
#pragma unroll
  for (int j = 0; j < 8; j++) {
    bf16_t hh = f2b(v[j]);
    h[j] = hh;
    l[j] = f2b(v[j] - b2f(hh));
  }
}
// staging loader: 0 = bf16 row-major, 1 = f32 row-major, 2 = tiled bf16 TR=128
__device__ __forceinline__ bf16x8 ld8m(const void* p, int row, int k, int K, int m) {
  if (m == 1) return ld8f(reinterpret_cast<const float*>(p) + (long)row * K + k);
  if (m == 2)
    return *reinterpret_cast<const bf16x8*>(
        reinterpret_cast<const bf16_t*>(p) + tidx(row, k, K, 7));
  return *reinterpret_cast<const bf16x8*>(
      reinterpret_cast<const bf16_t*>(p) + (long)row * K + k);
}

// ---------------------------------------------------------------------------
// f32 -> hi/lo bf16 split into TILED chunk-swizzled layout.
// ---------------------------------------------------------------------------
template <int LGTR, int LGNKS>
__global__ __launch_bounds__(256) void split_tiled(
    const float* __restrict__ in, bf16_t* __restrict__ hi,
    bf16_t* __restrict__ lo, long total, int K) {
  long stride = (long)gridDim.x * 256;
  for (long o = (long)blockIdx.x * 256 + threadIdx.x; o < total; o += stride) {
    int p = (int)(o & 3);
    long t = o >> 2;
    int r = (int)(t & ((1 << LGTR) - 1));
    long t2 = t >> LGTR;
    int ks = (int)(t2 & ((1 << LGNKS) - 1));
    long rt = t2 >> LGNKS;
    long row = (rt << LGTR) + r;
    int k = (ks << 5) + ((p ^ ((r >> 1) & 3)) << 3);
    bf16x8 h, l;
    split8(in + row * K + k, h, l);
    reinterpret_cast<bf16x8*>(hi)[o] = h;
    reinterpret_cast<bf16x8*>(lo)[o] = l;
  }
}

// two equally-shaped splits in one launch (Wg, Wu), selected by blockIdx.z
template <int LGTR, int LGNKS>
__global__ __launch_bounds__(256) void split_tiled2(
    const float* __restrict__ s0, bf16_t* __restrict__ h0, bf16_t* __restrict__ l0,
    const float* __restrict__ s1, bf16_t* __restrict__ h1, bf16_t* __restrict__ l1,
    long total, int K) {
  const float* in = blockIdx.z ? s1 : s0;
  bf16_t* hi = blockIdx.z ? h1 : h0;
  bf16_t* lo = blockIdx.z ? l1 : l0;
  long stride = (long)gridDim.x * 256;
  for (long o = (long)blockIdx.x * 256 + threadIdx.x; o < total; o += stride) {
    int p = (int)(o & 3);
    long t = o >> 2;
    int r = (int)(t & ((1 << LGTR) - 1));
    long t2 = t >> LGTR;
    int ks = (int)(t2 & ((1 << LGNKS) - 1));
    long rt = t2 >> LGNKS;
    long row = (rt << LGTR) + r;
    int k = (ks << 5) + ((p ^ ((r >> 1) & 3)) << 3);
    bf16x8 h, l;
    split8(in + row * K + k, h, l);
    reinterpret_cast<bf16x8*>(hi)[o] = h;
    reinterpret_cast<bf16x8*>(lo)[o] = l;
  }
}

// plain f32 -> bf16 conversion for two row-major arrays (groups of 8)
__global__ __launch_bounds__(256) void cvt_bf16_2(
    const float* __restrict__ s0, bf16_t* __restrict__ d0, long n0,
    const float* __restrict__ s1, bf16_t* __restrict__ d1, long n1) {
  long total = n0 + n1;
  long stride = (long)gridDim.x * 256;
  for (long i = (long)blockIdx.x * 256 + threadIdx.x; i < total; i += stride) {
    if (i < n0) reinterpret_cast<bf16x8*>(d0)[i] = ld8f(s0 + i * 8);
    else reinterpret_cast<bf16x8*>(d1)[i - n0] = ld8f(s1 + (i - n0) * 8);
  }
}

// ---------------------------------------------------------------------------
// Plain-bf16 NT GEMM (verified layout).
// MODE: 0 bf16 store; 1 silu(clip(v,-5,5)) bf16; 2 f32 RMW C += 0.1*v;
//       3 f32 RMW C = C*aux[row] + 0.1*v
// ---------------------------------------------------------------------------
template <int WM, int WN, int MODE>
__global__ __launch_bounds__(256) void gemm_nt_b(
    const void* __restrict__ Ag, const void* __restrict__ Bg,
    void* __restrict__ Cv, int M, int Nn, int K,
    const float* __restrict__ aux, int aF, int bF) {
  constexpr int BM = 2 * WM, BN = 2 * WN, AM = WM / 16, AN = WN / 16;
  constexpr int LDT = 40;
  __shared__ alignas(16) bf16_t As[BM * LDT];
  __shared__ alignas(16) bf16_t Bs[BN * LDT];

  const int tid = threadIdx.x;
  const int wave = tid >> 6, lane = tid & 63;
  const int wr = wave >> 1, wc = wave & 1;
  const int quad = lane >> 4, l16 = lane & 15;
  const int rowA0 = blockIdx.y * BM, rowB0 = blockIdx.x * BN;

  f32x4 acc[AM][AN] = {};

  for (int k0 = 0; k0 < K; k0 += 32) {
    for (int c = tid; c < BM * 4; c += 256) {
      int r = c >> 2, kc = c & 3;
      *reinterpret_cast<bf16x8*>(&As[r * LDT + kc * 8]) =
          ld8m(Ag, rowA0 + r, k0 + kc * 8, K, aF);
    }
    for (int c = tid; c < BN * 4; c += 256) {
      int r = c >> 2, kc = c & 3;
      *reinterpret_cast<bf16x8*>(&Bs[r * LDT + kc * 8]) =
          ld8m(Bg, rowB0 + r, k0 + kc * 8, K, bF);
    }
    __syncthreads();
    bf16x8 af[AM], bfv[AN];
#pragma unroll
    for (int i = 0; i < AM; i++)
      af[i] = *reinterpret_cast<bf16x8*>(&As[(wr * WM + i * 16 + l16) * LDT + quad * 8]);
#pragma unroll
    for (int j = 0; j < AN; j++)
      bfv[j] = *reinterpret_cast<bf16x8*>(&Bs[(wc * WN + j * 16 + l16) * LDT + quad * 8]);
#pragma unroll
    for (int i = 0; i < AM; i++)
#pragma unroll
      for (int j = 0; j < AN; j++)
        acc[i][j] = __builtin_amdgcn_mfma_f32_16x16x32_bf16(af[i], bfv[j], acc[i][j], 0, 0, 0);
    __syncthreads();
  }

  // C/D: col = lane&15, row = quad*4 + reg
#pragma unroll
  for (int i = 0; i < AM; i++)
#pragma unroll
    for (int j = 0; j < AN; j++)
#pragma unroll
      for (int r = 0; r < 4; r++) {
        int row = rowA0 + wr * WM + i * 16 + quad * 4 + r;
        int col = rowB0 + wc * WN + j * 16 + l16;
        long o = (long)row * Nn + col;
        float v = acc[i][j][r];
        if constexpr (MODE == 0) {
          reinterpret_cast<bf16_t*>(Cv)[o] = f2b(v);
        } else if constexpr (MODE == 1) {
          v = fminf(fmaxf(v, -5.f), 5.f);
          reinterpret_cast<bf16_t*>(Cv)[o] = f2b(siluf(v));
        } else if constexpr (MODE == 2) {
          float* C = reinterpret_cast<float*>(Cv);
          C[o] = C[o] + 0.1f * v;
        } else {
          float* C = reinterpret_cast<float*>(Cv);
          C[o] = C[o] * aux[row] + 0.1f * v;
        }
      }
}

// ---------------------------------------------------------------------------
// Fused gate/up, TILED inputs, gll16 staging, single buffer + XCD swizzle.
// ---------------------------------------------------------------------------
__global__ __launch_bounds__(256) void gemm_gu_g(
    const bf16_t* __restrict__ xhT, const bf16_t* __restrict__ xlT,
    const bf16_t* __restrict__ WghT, const bf16_t* __restrict__ WglT,
    const bf16_t* __restrict__ WuhT, const bf16_t* __restrict__ WulT,
    bf16_t* __restrict__ Hh, bf16_t* __restrict__ Hl) {
  __shared__ alignas(16) bf16_t Ah[128 * 32];
  __shared__ alignas(16) bf16_t Al[128 * 32];
  __shared__ alignas(16) bf16_t B1h[64 * 32];
  __shared__ alignas(16) bf16_t B1l[64 * 32];
  __shared__ alignas(16) bf16_t B2h[64 * 32];
  __shared__ alignas(16) bf16_t B2l[64 * 32];

  const int tid = threadIdx.x;
  const int wave = tid >> 6, lane = tid & 63;
  const int wr = wave >> 1, wc = wave & 1;
  const int quad = lane >> 4, l16 = lane & 15;
  const int sw = (quad ^ ((l16 >> 1) & 3)) << 3;
  // XCD swizzle: each XCD gets contiguous bm rows (grid 32x64=2048, %8==0)
  const int lid = blockIdx.y * gridDim.x + blockIdx.x;
  const int nper = (gridDim.x * gridDim.y) >> 3;
  const int nl = (lid & 7) * nper + (lid >> 3);
  const int bm = nl >> 5, bn = nl & 31;  // gridDim.x == 32
  constexpr int nks = D / 32;
  const int wo = wave << 9;

  f32x4 ag[4][2] = {}, au[4][2] = {};

  for (int ks = 0; ks < nks; ks++) {
    long ao = (((long)bm * nks + ks) << 12) + wo + lane * 8;
    long bo = (((long)bn * nks + ks) << 11) + wo + lane * 8;
    gll16(xhT + ao, Ah + wo);
    gll16(xhT + ao + 2048, Ah + wo + 2048);
    gll16(xlT + ao, Al + wo);
    gll16(xlT + ao + 2048, Al + wo + 2048);
    gll16(WghT + bo, B1h + wo);
    gll16(WglT + bo, B1l + wo);
    gll16(WuhT + bo, B2h + wo);
    gll16(WulT + bo, B2l + wo);
    __syncthreads();  // drains vmcnt -> LDS ready
    bf16x8 afh[4], afl[4], b1h[2], b1l[2], b2h[2], b2l[2];
#pragma unroll
    for (int i = 0; i < 4; i++) {
      int ro = (wr * 64 + i * 16 + l16) * 32 + sw;
      afh[i] = *reinterpret_cast<bf16x8*>(&Ah[ro]);
      afl[i] = *reinterpret_cast<bf16x8*>(&Al[ro]);
    }
#pragma unroll
    for (int j = 0; j < 2; j++) {
      int ro = (wc * 32 + j * 16 + l16) * 32 + sw;
      b1h[j] = *reinterpret_cast<bf16x8*>(&B1h[ro]);
      b1l[j] = *reinterpret_cast<bf16x8*>(&B1l[ro]);
      b2h[j] = *reinterpret_cast<bf16x8*>(&B2h[ro]);
      b2l[j] = *reinterpret_cast<bf16x8*>(&B2l[ro]);
    }
#pragma unroll
    for (int i = 0; i < 4; i++)
#pragma unroll
      for (int j = 0; j < 2; j++) {
        ag[i][j] = __builtin_amdgcn_mfma_f32_16x16x32_bf16(afh[i], b1h[j], ag[i][j], 0, 0, 0);
        ag[i][j] = __builtin_amdgcn_mfma_f32_16x16x32_bf16(afh[i], b1l[j], ag[i][j], 0, 0, 0);
        ag[i][j] = __builtin_amdgcn_mfma_f32_16x16x32_bf16(afl[i], b1h[j], ag[i][j], 0, 0, 0);
        au[i][j] = __builtin_amdgcn_mfma_f32_16x16x32_bf16(afh[i], b2h[j], au[i][j], 0, 0, 0);
        au[i][j] = __builtin_amdgcn_mfma_f32_16x16x32_bf16(afh[i], b2l[j], au[i][j], 0, 0, 0);
        au[i][j] = __builtin_amdgcn_mfma_f32_16x16x32_bf16(afl[i], b2h[j], au[i][j], 0, 0, 0);
      }
    __syncthreads();
  }

#pragma unroll
  for (int i = 0; i < 4; i++)
#pragma unroll
    for (int j = 0; j < 2; j++)
#pragma unroll
      for (int r = 0; r < 4; r++) {
        int row = bm * 128 + wr * 64 + i * 16 + quad * 4 + r;
        int col = bn * 64 + wc * 32 + j * 16 + l16;
        long o = tidx(row, col, H, 7) + (col & 7);
        float v = siluf(ag[i][j][r]) * au[i][j][r];
        bf16_t hh = f2b(v);
        Hh[o] = hh;
        Hl[o] = f2b(v - b2f(hh));
      }
}

// ---------------------------------------------------------------------------
// Down-proj + folded concat, XCD swizzle.
// out[n,d] = wsum[n] * ( hidden@Wd^T  +  hw2'@Mb2'^T )
// ---------------------------------------------------------------------------
__global__ __launch_bounds__(256) void gemm_dn_g(
    const bf16_t* __restrict__ HhT, const bf16_t* __restrict__ HlT,
    const bf16_t* __restrict__ WdhT, const bf16_t* __restrict__ WdlT,
    const bf16_t* __restrict__ hw2, const bf16_t* __restrict__ Mb2,
    const float* __restrict__ wsum, float* __restrict__ Cg) {
  __shared__ alignas(16) bf16_t Ah[128 * 32];
  __shared__ alignas(16) bf16_t Al[128 * 32];
  __shared__ alignas(16) bf16_t Bh[128 * 32];
  __shared__ alignas(16) bf16_t Bl[128 * 32];

  const int tid = threadIdx.x;
  const int wave = tid >> 6, lane = tid & 63;
  const int wr = wave >> 1, wc = wave & 1;
  const int quad = lane >> 4, l16 = lane & 15;
  const int sw = (quad ^ ((l16 >> 1) & 3)) << 3;
  // XCD swizzle (grid 8x64=512, %8==0)
  const int lid = blockIdx.y * gridDim.x + blockIdx.x;
  const int nper = (gridDim.x * gridDim.y) >> 3;
  const int nl = (lid & 7) * nper + (lid >> 3);
  const int by = nl >> 3, bx = nl & 7;  // gridDim.x == 8
  constexpr int nks = H / 32;
  const int wo = wave << 9;

  f32x4 acc[4][4] = {};

  for (int ks = 0; ks < nks; ks++) {
    long ao = (((long)by * nks + ks) << 12) + wo + lane * 8;
    long bo = (((long)bx * nks + ks) << 12) + wo + lane * 8;
    gll16(HhT + ao, Ah + wo);
    gll16(HhT + ao + 2048, Ah + wo + 2048);
    gll16(HlT + ao, Al + wo);
    gll16(HlT + ao + 2048, Al + wo + 2048);
    gll16(WdhT + bo, Bh + wo);
    gll16(WdhT + bo + 2048, Bh + wo + 2048);
    gll16(WdlT + bo, Bl + wo);
    gll16(WdlT + bo + 2048, Bl + wo + 2048);
    __syncthreads();
    bf16x8 afh[4], afl[4], bfh[4], bfl[4];
#pragma unroll
    for (int i = 0; i < 4; i++) {
      int ro = (wr * 64 + i * 16 + l16) * 32 + sw;
      afh[i] = *reinterpret_cast<bf16x8*>(&Ah[ro]);
      afl[i] = *reinterpret_cast<bf16x8*>(&Al[ro]);
    }
#pragma unroll
    for (int j = 0; j < 4; j++) {
      int ro = (wc * 64 + j * 16 + l16) * 32 + sw;
      bfh[j] = *reinterpret_cast<bf16x8*>(&Bh[ro]);
      bfl[j] = *reinterpret_cast<bf16x8*>(&Bl[ro]);
    }
#pragma unroll
    for (int i = 0; i < 4; i++)
#pragma unroll
      for (int j = 0; j < 4; j++) {
        acc[i][j] = __builtin_amdgcn_mfma_f32_16x16x32_bf16(afh[i], bfh[j], acc[i][j], 0, 0, 0);
        acc[i][j] = __builtin_amdgcn_mfma_f32_16x16x32_bf16(afh[i], bfl[j], acc[i][j], 0, 0, 0);
        acc[i][j] = __builtin_amdgcn_mfma_f32_16x16x32_bf16(afl[i], bfh[j], acc[i][j], 0, 0, 0);
      }
    __syncthreads();
  }

  // --- concat phase: 8 ksteps over K2=256, single-MFMA (plain bf16) ---
  {
    const int rrow = wave * 16 + (lane >> 2);  // LDS row this lane fills
    const int pp = lane & 3;                   // LDS chunk slot
    for (int ck = 0; ck < 8; ck++) {
      int r0 = rrow, r1 = rrow + 64;
      int q0 = (pp ^ ((r0 >> 1) & 3)) << 3;
      int q1 = (pp ^ ((r1 >> 1) & 3)) << 3;
      gll16(hw2 + ((long)(by * 128 + r0) * 256 + ck * 32 + q0), Ah + wo);
      gll16(hw2 + ((long)(by * 128 + r1) * 256 + ck * 32 + q1), Ah + wo + 2048);
      gll16(Mb2 + ((long)(bx * 128 + r0) * 256 + ck * 32 + q0), Bh + wo);
      gll16(Mb2 + ((long)(bx * 128 + r1) * 256 + ck * 32 + q1), Bh + wo + 2048);
      __syncthreads();
      bf16x8 af2[4], bf2[4];
#pragma unroll
      for (int i = 0; i < 4; i++)
        af2[i] = *reinterpret_cast<bf16x8*>(&Ah[(wr * 64 + i * 16 + l16) * 32 + sw]);
#pragma unroll
      for (int j = 0; j < 4; j++)
        bf2[j] = *reinterpret_cast<bf16x8*>(&Bh[(wc * 64 + j * 16 + l16) * 32 + sw]);
#pragma unroll
      for (int i = 0; i < 4; i++)
#pragma unroll
        for (int j = 0; j < 4; j++)
          acc[i][j] = __builtin_amdgcn_mfma_f32_16x16x32_bf16(af2[i], bf2[j], acc[i][j], 0, 0, 0);
      __syncthreads();
    }
  }

#pragma unroll
  for (int i = 0; i < 4; i++)
#pragma unroll
    for (int j = 0; j < 4; j++)
#pragma unroll
      for (int r = 0; r < 4; r++) {
        int row = by * 128 + wr * 64 + i * 16 + quad * 4 + r;
        int col = bx * 128 + wc * 64 + j * 16 + l16;
        Cg[(long)row * D + col] = wsum[row] * acc[i][j][r];
      }
}

// ---------------------------------------------------------------------------
// Fused adapt attention, QBLK=32 (grid S/32 x Bb = 256 blocks -> full GPU).
// outp[token][oOff+col] = cscale * (silu(clip(ai@ao^T))@ai)
// Per-element math and accumulation order identical to QBLK=64 version.
// ---------------------------------------------------------------------------
__global__ __launch_bounds__(256) void fused_adapt(
    const bf16_t* __restrict__ aib, const bf16_t* __restrict__ aob,
    const bf16_t* __restrict__ aiT, bf16_t* __restrict__ outp,
    int oLd, int oOff, float cscale) {
  constexpr int LDQ = 136;
  constexpr int LDP = 72;
  __shared__ alignas(16) bf16_t Qs[32 * LDQ];
  __shared__ alignas(16) bf16_t Os[64 * LDQ];
  __shared__ alignas(16) bf16_t Ps[32 * LDP];
  __shared__ alignas(16) bf16_t Vs[128 * LDP];

  const int tid = threadIdx.x;
  const int wave = tid >> 6, lane = tid & 63;
  const int wr = wave >> 1, wc = wave & 1;
  const int quad = lane >> 4, l16 = lane & 15;
  const int b = blockIdx.y;
  const int q0 = blockIdx.x * 32;

  for (int c = tid; c < 512; c += 256) {
    int r = c >> 4, cc = c & 15;
    *reinterpret_cast<bf16x8*>(&Qs[r * LDQ + cc * 8]) =
        *reinterpret_cast<const bf16x8*>(&aib[((long)b * S + q0 + r) * A + cc * 8]);
  }

  f32x4 o[4] = {};  // wave: 16q x 64a

  for (int tt = 0; tt < S / 64; tt++) {
    const int t0 = tt * 64;
    __syncthreads();
    for (int c = tid; c < 1024; c += 256) {
      int r = c >> 4, cc = c & 15;
      *reinterpret_cast<bf16x8*>(&Os[r * LDQ + cc * 8]) =
          *reinterpret_cast<const bf16x8*>(&aob[((long)b * S + t0 + r) * A + cc * 8]);
    }
    for (int c = tid; c < 1024; c += 256) {
      int r = c >> 3, cc = c & 7;
      *reinterpret_cast<bf16x8*>(&Vs[r * LDP + cc * 8]) =
          *reinterpret_cast<const bf16x8*>(&aiT[((long)b * A + r) * S + t0 + cc * 8]);
    }
    __syncthreads();
    // QK^T: P[32q,64t]; wave covers 16q x 32t
    f32x4 p[2] = {};
#pragma unroll
    for (int ks = 0; ks < 4; ks++) {
      bf16x8 af =
          *reinterpret_cast<bf16x8*>(&Qs[(wr * 16 + l16) * LDQ + ks * 32 + quad * 8]);
      bf16x8 bfv[2];
#pragma unroll
      for (int j = 0; j < 2; j++)
        bfv[j] = *reinterpret_cast<bf16x8*>(&Os[(wc * 32 + j * 16 + l16) * LDQ + ks * 32 + quad * 8]);
#pragma unroll
      for (int j = 0; j < 2; j++)
        p[j] = __builtin_amdgcn_mfma_f32_16x16x32_bf16(af, bfv[j], p[j], 0, 0, 0);
    }
#pragma unroll
    for (int j = 0; j < 2; j++)
#pragma unroll
      for (int r = 0; r < 4; r++) {
        int row = wr * 16 + quad * 4 + r;
        int col = wc * 32 + j * 16 + l16;
        float v = fminf(fmaxf(p[j][r], -5.f), 5.f);
        Ps[row * LDP + col] = f2b(siluf(v));
      }
    __syncthreads();
    // PV: o[32q,128a] += P[32q,64t] @ V[128a,64t]^T; wave: 16q x 64a
#pragma unroll
    for (int ks = 0; ks < 2; ks++) {
      bf16x8 paf =
          *reinterpret_cast<bf16x8*>(&Ps[(wr * 16 + l16) * LDP + ks * 32 + quad * 8]);
      bf16x8 vbf[4];
#pragma unroll
      for (int j = 0; j < 4; j++)
        vbf[j] = *reinterpret_cast<bf16x8*>(&Vs[(wc * 64 + j * 16 + l16) * LDP + ks * 32 + quad * 8]);
#pragma unroll
      for (int j = 0; j < 4; j++)
        o[j] = __builtin_amdgcn_mfma_f32_16x16x32_bf16(paf, vbf[j], o[j], 0, 0, 0);
    }
  }

#pragma unroll
  for (int j = 0; j < 4; j++)
#pragma unroll
    for (int r = 0; r < 4; r++) {
      int row = q0 + wr * 16 + quad * 4 + r;
      int col = wc * 64 + j * 16 + l16;
      long token = (long)b * S + row;
      outp[token * oLd + oOff + col] = f2b(o[j][r] * cscale);
    }
}

// ---------------------------------------------------------------------------
// [D,A] = Af32 @ Bbf16^T, split-K x8 into f32 partials (Mb and WdWap).
// ---------------------------------------------------------------------------
__global__ __launch_bounds__(256) void gemm_mb_splitk(
    const float* __restrict__ Ag, const bf16_t* __restrict__ Bg,
    float* __restrict__ Mp, int M, int Nn, int K) {
  constexpr int BM = 64, BN = 64, LDT = 40;
  __shared__ alignas(16) bf16_t As[BM * LDT];
  __shared__ alignas(16) bf16_t Bs[BN * LDT];
  const int tid = threadIdx.x;
  const int wave = tid >> 6, lane = tid & 63;
  const int wr = wave >> 1, wc = wave & 1;
  const int quad = lane >> 4, l16 = lane & 15;
  const int rowA0 = blockIdx.y * BM, rowB0 = blockIdx.x * BN;
  const int kz = blockIdx.z;
  const int ks0 = kz * (K / 8), ks1 = ks0 + K / 8;

  f32x4 acc[2][2] = {};
  for (int k0 = ks0; k0 < ks1; k0 += 32) {
    for (int c = tid; c < BM * 4; c += 256) {
      int r = c >> 2, kc = c & 3;
      *reinterpret_cast<bf16x8*>(&As[r * LDT + kc * 8]) =
          ld8f(Ag + (long)(rowA0 + r) * K + k0 + kc * 8);
    }
    for (int c = tid; c < BN * 4; c += 256) {
      int r = c >> 2, kc = c & 3;
      *reinterpret_cast<bf16x8*>(&Bs[r * LDT + kc * 8]) =
          *reinterpret_cast<const bf16x8*>(&Bg[(long)(rowB0 + r) * K + k0 + kc * 8]);
    }
    __syncthreads();
    bf16x8 af[2], bfv[2];
#pragma unroll
    for (int i = 0; i < 2; i++)
      af[i] = *reinterpret_cast<bf16x8*>(&As[(wr * 32 + i * 16 + l16) * LDT + quad * 8]);
#pragma unroll
    for (int j = 0; j < 2; j++)
      bfv[j] = *reinterpret_cast<bf16x8*>(&Bs[(wc * 32 + j * 16 + l16) * LDT + quad * 8]);
#pragma unroll
    for (int i = 0; i < 2; i++)
#pragma unroll
      for (int j = 0; j < 2; j++)
        acc[i][j] = __builtin_amdgcn_mfma_f32_16x16x32_bf16(af[i], bfv[j], acc[i][j], 0, 0, 0);
    __syncthreads();
  }
#pragma unroll
  for (int i = 0; i < 2; i++)
#pragma unroll
    for (int j = 0; j < 2; j++)
#pragma unroll
      for (int r = 0; r < 4; r++) {
        int row = rowA0 + wr * 32 + i * 16 + quad * 4 + r;
        int col = rowB0 + wc * 32 + j * 16 + l16;
        Mp[(long)kz * M * Nn + (long)row * Nn + col] = acc[i][j][r];
      }
}

// combine partials into strided bf16 destination: out[(i>>7)*ld + coff + (i&127)]
__global__ __launch_bounds__(256) void mb_combine(
    const float* __restrict__ Mp, bf16_t* __restrict__ outp, int total,
    int ld, int coff) {
  int i = blockIdx.x * 256 + threadIdx.x;
  if (i >= total) return;
  float s = 0.f;
#pragma unroll
  for (int z = 0; z < 8; z++) s += Mp[(long)z * total + i];
  outp[(long)(i >> 7) * ld + coff + (i & 127)] = f2b(s);
}

// ---------------------------------------------------------------------------
// Fallback-path kernels (f32 inputs, in-loop split) — unchanged, proven.
// ---------------------------------------------------------------------------
__global__ __launch_bounds__(256) void gemm_dn_hl(
    const float* __restrict__ Ag, const float* __restrict__ Bg,
    float* __restrict__ Cg, int M, int Nn, int K) {
  constexpr int BM = 128, BN = 128, LDT = 40;
  __shared__ alignas(16) bf16_t Ah[BM * LDT];
  __shared__ alignas(16) bf16_t Al[BM * LDT];
  __shared__ alignas(16) bf16_t Bh[BN * LDT];
  __shared__ alignas(16) bf16_t Bl[BN * LDT];

  const int tid = threadIdx.x;
  const int wave = tid >> 6, lane = tid & 63;
  const int wr = wave >> 1, wc = wave & 1;
  const int quad = lane >> 4, l16 = lane & 15;
  const int rowA0 = blockIdx.y * BM, rowB0 = blockIdx.x * BN;

  f32x4 acc[4][4] = {};

  for (int k0 = 0; k0 < K; k0 += 32) {
    for (int c = tid; c < BM * 4; c += 256) {
      int r = c >> 2, kc = c & 3;
      bf16x8 h, l;
      split8(&Ag[(long)(rowA0 + r) * K + k0 + kc * 8], h, l);
      *reinterpret_cast<bf16x8*>(&Ah[r * LDT + kc * 8]) = h;
      *reinterpret_cast<bf16x8*>(&Al[r * LDT + kc * 8]) = l;
    }
    for (int c = tid; c < BN * 4; c += 256) {
      int r = c >> 2, kc = c & 3;
      bf16x8 h, l;
      split8(&Bg[(long)(rowB0 + r) * K + k0 + kc * 8], h, l);
      *reinterpret_cast<bf16x8*>(&Bh[r * LDT + kc * 8]) = h;
      *reinterpret_cast<bf16x8*>(&Bl[r * LDT + kc * 8]) = l;
    }
    __syncthreads();
    bf16x8 afh[4], afl[4], bfh[4], bfl[4];
#pragma unroll
    for (int i = 0; i < 4; i++) {
      int ro = (wr * 64 + i * 16 + l16) * LDT + quad * 8;
      afh[i] = *reinterpret_cast<bf16x8*>(&Ah[ro]);
      afl[i] = *reinterpret_cast<bf16x8*>(&Al[ro]);
    }
#pragma unroll
    for (int j = 0; j < 4; j++) {
      int ro = (wc * 64 + j * 16 + l16) * LDT + quad * 8;
      bfh[j] = *reinterpret_cast<bf16x8*>(&Bh[ro]);
      bfl[j] = *reinterpret_cast<bf16x8*>(&Bl[ro]);
    }
#pragma unroll
    for (int i = 0; i < 4; i++)
#pragma unroll
      for (int j = 0; j < 4; j++) {
        acc[i][j] = __builtin_amdgcn_mfma_f32_16x16x32_bf16(afh[i], bfh[j], acc[i][j], 0, 0, 0);
        acc[i][j] = __builtin_amdgcn_mfma_f32_16x16x32_bf16(afh[i], bfl[j], acc[i][j], 0, 0, 0);
        acc[i][j] = __builtin_amdgcn_mfma_f32_16x16x32_bf16(afl[i], bfh[j], acc[i][j], 0, 0, 0);
      }
    __syncthreads();
  }

#pragma unroll
  for (int i = 0; i < 4; i++)
#pragma unroll
    for (int j = 0; j < 4; j++)
#pragma unroll
      for (int r = 0; r < 4; r++) {
        int row = rowA0 + wr * 64 + i * 16 + quad * 4 + r;
        int col = rowB0 + wc * 64 + j * 16 + l16;
        Cg[(long)row * Nn + col] = acc[i][j][r];
      }
}

__global__ __launch_bounds__(256) void gemm_gu_hl(
    const float* __restrict__ x, const float* __restrict__ Wg,
    const float* __restrict__ Wu, float* __restrict__ Cg, int M, int Nn, int K) {
  constexpr int BM = 128, BN = 64, LDT = 40;
  __shared__ alignas(16) bf16_t Ah[BM * LDT];
  __shared__ alignas(16) bf16_t Al[BM * LDT];
  __shared__ alignas(16) bf16_t B1h[BN * LDT];
  __shared__ alignas(16) bf16_t B1l[BN * LDT];
  __shared__ alignas(16) bf16_t B2h[BN * LDT];
  __shared__ alignas(16) bf16_t B2l[BN * LDT];

  const int tid = threadIdx.x;
  const int wave = tid >> 6, lane = tid & 63;
  const int wr = wave >> 1, wc = wave & 1;
  const int quad = lane >> 4, l16 = lane & 15;
  const int rowA0 = blockIdx.y * BM, rowB0 = blockIdx.x * BN;

  f32x4 ag[4][2] = {}, au[4][2] = {};

  for (int k0 = 0; k0 < K; k0 += 32) {
    for (int c = tid; c < BM * 4; c += 256) {
      int r = c >> 2, kc = c & 3;
      bf16x8 h, l;
      split8(&x[(long)(rowA0 + r) * K + k0 + kc * 8], h, l);
      *reinterpret_cast<bf16x8*>(&Ah[r * LDT + kc * 8]) = h;
      *reinterpret_cast<bf16x8*>(&Al[r * LDT + kc * 8]) = l;
    }
    for (int c = tid; c < BN * 4; c += 256) {
      int r = c >> 2, kc = c & 3;
      long idx = (long)(rowB0 + r) * K + k0 + kc * 8;
      bf16x8 h, l;
      split8(&Wg[idx], h, l);
      *reinterpret_cast<bf16x8*>(&B1h[r * LDT + kc * 8]) = h;
      *reinterpret_cast<bf16x8*>(&B1l[r * LDT + kc * 8]) = l;
      split8(&Wu[idx], h, l);
      *reinterpret_cast<bf16x8*>(&B2h[r * LDT + kc * 8]) = h;
      *reinterpret_cast<bf16x8*>(&B2l[r * LDT + kc * 8]) = l;
    }
    __syncthreads();
    bf16x8 afh[4], afl[4], b1h[2], b1l[2], b2h[2], b2l[2];
#pragma unroll
    for (int i = 0; i < 4; i++) {
      int ro = (wr * 64 + i * 16 + l16) * LDT + quad * 8;
      afh[i] = *reinterpret_cast<bf16x8*>(&Ah[ro]);
      afl[i] = *reinterpret_cast<bf16x8*>(&Al[ro]);
    }
#pragma unroll
    for (int j = 0; j < 2; j++) {
      int ro = (wc * 32 + j * 16 + l16) * LDT + quad * 8;
      b1h[j] = *reinterpret_cast<bf16x8*>(&B1h[ro]);
      b1l[j] = *reinterpret_cast<bf16x8*>(&B1l[ro]);
      b2h[j] = *reinterpret_cast<bf16x8*>(&B2h[ro]);
      b2l[j] = *reinterpret_cast<bf16x8*>(&B2l[ro]);
    }
#pragma unroll
    for (int i = 0; i < 4; i++)
#pragma unroll
      for (int j = 0; j < 2; j++) {
        ag[i][j] = __builtin_amdgcn_mfma_f32_16x16x32_bf16(afh[i], b1h[j], ag[i][j], 0, 0, 0);
        ag[i][j] = __builtin_amdgcn_mfma_f32_16x16x32_bf16(afh[i], b1l[j], ag[i][j], 0, 0, 0);
        ag[i][j] = __builtin_amdgcn_mfma_f32_16x16x32_bf16(afl[i], b1h[j], ag[i][j], 0, 0, 0);
        au[i][j] = __builtin_amdgcn_mfma_f32_16x16x32_bf16(afh[i], b2h[j], au[i][j], 0, 0, 0);
        au[i][j] = __builtin_amdgcn_mfma_f32_16x16x32_bf16(afh[i], b2l[j], au[i][j], 0, 0, 0);
        au[i][j] = __builtin_amdgcn_mfma_f32_16x16x32_bf16(afl[i], b2h[j], au[i][j], 0, 0, 0);
      }
    __syncthreads();
  }

#pragma unroll
  for (int i = 0; i < 4; i++)
#pragma unroll
    for (int j = 0; j < 2; j++)
#pragma unroll
      for (int r = 0; r < 4; r++) {
        int row = rowA0 + wr * 64 + i * 16 + quad * 4 + r;
        int col = rowB0 + wc * 32 + j * 16 + l16;
        Cg[(long)row * Nn + col] = siluf(ag[i][j][r]) * au[i][j][r];
      }
}

// ---------------------------------------------------------------------------
// Router (no global atomics, per-block partials).
// ---------------------------------------------------------------------------
__global__ __launch_bounds__(256) void router_kernel(
    const float* __restrict__ x, const float* __restrict__ Wgr,
    const float* __restrict__ Wer, int* __restrict__ eidx,
    float* __restrict__ fw, float* __restrict__ wsum,
    float* __restrict__ lpart) {
  __shared__ float part[4][12];
  const int wv = threadIdx.x >> 6;
  const int lane = threadIdx.x & 63;
  const int token = blockIdx.x * 4 + wv;
  if (lane < 12) part[wv][lane] = 0.f;
  const float* xp = x + (long)token * D;
  float xr[16];
#pragma unroll
  for (int i = 0; i < 16; i++) xr[i] = xp[lane + i * 64];
  float dots[6];
#pragma unroll
  for (int w = 0; w < 6; w++) {
    const float* wp = (w < 2) ? (Wgr + (long)w * D) : (Wer + (long)(w - 2) * D);
    float s = 0.f;
#pragma unroll
    for (int i = 0; i < 16; i++) s += xr[i] * wp[lane + i * 64];
#pragma unroll
    for (int off = 32; off; off >>= 1) s += __shfl_xor(s, off);
    dots[w] = s;
  }
  if (lane == 0) {
    float gl0 = dots[0], gl1 = dots[1];
    float mg = fmaxf(gl0, gl1);
    float e0 = expf(gl0 - mg), e1 = expf(gl1 - mg);
    float inv = 1.f / (e0 + e1);
    float gp0 = e0 * inv, gp1 = e1 * inv;
    int gi = (gp1 > gp0) ? 1 : 0;
    float gw = gi ? gp1 : gp0;
    float el[4] = {dots[2], dots[3], dots[4], dots[5]};
    float me = fmaxf(fmaxf(el[0], el[1]), fmaxf(el[2], el[3]));
    float ep[4], es = 0.f;
#pragma unroll
    for (int j = 0; j < 4; j++) { ep[j] = expf(el[j] - me); es += ep[j]; }
    float inve = 1.f / es;
#pragma unroll
    for (int j = 0; j < 4; j++) ep[j] *= inve;
    int i1 = 0;
    for (int j = 1; j < 4; j++) if (ep[j] > ep[i1]) i1 = j;
    int i2 = (i1 == 0) ? 1 : 0;
    for (int j = 0; j < 4; j++) if (j != i1 && j != i2 && ep[j] > ep[i2]) i2 = j;
    float l1 = ep[i1], l2 = ep[i2];
    float ils = 1.f / (l1 + l2 + 1e-7f);
    float f1 = gw * l1 * ils, f2 = gw * l2 * ils;
    eidx[token * 2] = gi * 4 + i1;
    eidx[token * 2 + 1] = gi * 4 + i2;
    fw[token * 2] = f1;
    fw[token * 2 + 1] = f2;
    wsum[token] = f1 + f2;
    part[wv][gi * 4 + i1] = f1;
    part[wv][gi * 4 + i2] = f2;
    part[wv][8] = gl0 * gl0 + gl1 * gl1;
    part[wv][9] = el[0] * el[0] + el[1] * el[1] + el[2] * el[2] + el[3] * el[3];
  }
  __syncthreads();
  if (threadIdx.x < 12) {
    lpart[(long)blockIdx.x * 12 + threadIdx.x] =
        part[0][threadIdx.x] + part[1][threadIdx.x] +
        part[2][threadIdx.x] + part[3][threadIdx.x];
  }
}

// ---------------------------------------------------------------------------
// Row LayerNorm over A=128 (bf16 in ws, f32 g/b, bf16 out).
// ---------------------------------------------------------------------------
__global__ __launch_bounds__(256) void ln_rows(
    const bf16_t* __restrict__ in, const float* __restrict__ g,
    const float* __restrict__ b, bf16_t* __restrict__ out) {
  const int row = blockIdx.x * 4 + (threadIdx.x >> 6);
  const int lane = threadIdx.x & 63;
  const bf16_t* p = in + (long)row * A;
  float x0 = b2f(p[lane]), x1 = b2f(p[lane + 64]);
  float s = x0 + x1;
#pragma unroll
  for (int off = 32; off; off >>= 1) s += __shfl_xor(s, off);
  float mean = s * (1.f / 128.f);
  float d0 = x0 - mean, d1 = x1 - mean;
  float q = d0 * d0 + d1 * d1;
#pragma unroll
  for (int off = 32; off; off >>= 1) q += __shfl_xor(q, off);
  float r = rsqrtf(q * (1.f / 128.f) + 1e-5f);
  bf16_t* po = out + (long)row * A;
  po[lane] = f2b(d0 * r * g[lane] + b[lane]);
  po[lane + 64] = f2b(d1 * r * g[lane + 64] + b[lane + 64]);
}

// ---------------------------------------------------------------------------
// Transpose [z,R,C] -> [z,C,R], bf16 out; input f32 (isf=1) or bf16.
// ---------------------------------------------------------------------------
__global__ __launch_bounds__(256) void transpose2d(
    const void* __restrict__ in, bf16_t* __restrict__ out, int R, int C, int isf) {
  __shared__ bf16_t t[32][33];
  const long zb = blockIdx.z;
  const long ib = zb * (long)R * C;
  bf16_t* op = out + zb * (long)R * C;
  const int r0 = blockIdx.y * 32, c0 = blockIdx.x * 32;
  const int tx = threadIdx.x & 31, ty = threadIdx.x >> 5;
#pragma unroll
  for (int i = 0; i < 4; i++) {
    long idx = ib + (long)(r0 + ty + i * 8) * C + c0 + tx;
    t[ty + i * 8][tx] = isf ? f2b(reinterpret_cast<const float*>(in)[idx])
                            : reinterpret_cast<const bf16_t*>(in)[idx];
  }
  __syncthreads();
#pragma unroll
  for (int i = 0; i < 4; i++) op[(long)(c0 + ty + i * 8) * R + r0 + tx] = t[tx][ty + i * 8];
}

// pair transpose: z selects (in0->out0) or (in1->out1); f32 input, same R,C
__global__ __launch_bounds__(256) void transpose2d_pair(
    const float* __restrict__ in0, bf16_t* __restrict__ out0,
    const float* __restrict__ in1, bf16_t* __restrict__ out1, int R, int C) {
  __shared__ bf16_t t[32][33];
  const float* in = blockIdx.z ? in1 : in0;
  bf16_t* op = blockIdx.z ? out1 : out0;
  const int r0 = blockIdx.y * 32, c0 = blockIdx.x * 32;
  const int tx = threadIdx.x & 31, ty = threadIdx.x >> 5;
#pragma unroll
  for (int i = 0; i < 4; i++) {
    long idx = (long)(r0 + ty + i * 8) * C + c0 + tx;
    t[ty + i * 8][tx] = f2b(in[idx]);
  }
  __syncthreads();
#pragma unroll
  for (int i = 0; i < 4; i++) op[(long)(c0 + ty + i * 8) * R + r0 + tx] = t[tx][ty + i * 8];
}

// ---------------------------------------------------------------------------
// Expert branch: coalesced via WeaT[e][a][c]. Writes hw*(0.1/wsum) when wsc
// given (big path: concat-fold pre-scale), else raw (fallback).
// ---------------------------------------------------------------------------
__global__ __launch_bounds__(128) void expert_adapt(
    const bf16_t* __restrict__ h0, const bf16_t* __restrict__ WeaT,
    const float* __restrict__ ln_eg, const float* __restrict__ ln_eb,
    const int* __restrict__ eidx, const float* __restrict__ fw,
    bf16_t* __restrict__ hw, int ld, const float* __restrict__ wsc) {
  const int n = blockIdx.x;
  const int c = threadIdx.x;
  __shared__ float h0s[128];
  __shared__ float red[4];
  h0s[c] = b2f(h0[(long)n * A + c]);
  __syncthreads();
  float out = 0.f;
  for (int k = 0; k < 2; k++) {
    int e = eidx[n * 2 + k];
    e = min(max(e, 0), E - 1);
    float w = fw[n * 2 + k];
    const bf16_t* Wc = WeaT + (long)e * A * A + c;
    float t = 0.f;
#pragma unroll 8
    for (int a = 0; a < 128; a++) t += b2f(Wc[(long)a * A]) * h0s[a];
    float s = t, q = t * t;
#pragma unroll
    for (int off = 32; off; off >>= 1) { s += __shfl_xor(s, off); q += __shfl_xor(q, off); }
    if ((c & 63) == 0) { red[(c >> 6) * 2] = s; red[(c >> 6) * 2 + 1] = q; }
    __syncthreads();
    float Sx = red[0] + red[2], Qx = red[1] + red[3];
    float mean = Sx * (1.f / 128.f);
    float var = Qx * (1.f / 128.f) - mean * mean;
    float r = rsqrtf(var + 1e-5f);
    out += w * ((t - mean) * r * ln_eg[e * A + c] + ln_eb[e * A + c]);
    __syncthreads();
  }
  float sc = wsc ? (0.1f / wsc[n]) : 1.f;
  hw[(long)n * ld + c] = f2b(out * sc);
}

// ---------------------------------------------------------------------------
// Loss finalize.
// ---------------------------------------------------------------------------
__global__ __launch_bounds__(256) void finalize_loss(
    const float* __restrict__ lpart, int nblk, float* __restrict__ outv) {
  float acc[10] = {};
  for (int b = threadIdx.x; b < nblk; b += 256) {
    const float* p = lpart + (long)b * 12;
#pragma unroll
    for (int c = 0; c < 10; c++) acc[c] += p[c];
  }
  __shared__ float red[10][4];
  const int lane = threadIdx.x & 63, wv = threadIdx.x >> 6;
#pragma unroll
  for (int c = 0; c < 10; c++) {
    float s = acc[c];
#pragma unroll
    for (int off = 32; off; off >>= 1) s += __shfl_xor(s, off);
    if (lane == 0) red[c][wv] = s;
  }
  __syncthreads();
  if (threadIdx.x == 0) {
    float loss[10];
#pragma unroll
    for (int c = 0; c < 10; c++)
      loss[c] = red[c][0] + red[c][1] + red[c][2] + red[c][3];
    float tl = 0.f;
    for (int e = 0; e < 8; e++) tl += loss[e];
    float target = tl / 8.f;
    float mse = 0.f;
    for (int e = 0; e < 8; e++) { float d = loss[e] - target; mse += d * d; }
    mse *= (1.f / 8.f);
    outv[0] = 0.001f * (mse + loss[8] / (float)(N * 2) + loss[9] / (float)(N * 4));
  }
}

// ---------------------------------------------------------------------------
extern "C" void kernel_launch(void* const* d_in, const int* in_sizes, int n_in,
                              void* d_out, int out_size, void* d_ws, size_t ws_size,
                              hipStream_t stream) {
  const float* x = (const float*)d_in[0];
  const float* Wu = (const float*)d_in[1];
  const float* Wg = (const float*)d_in[2];
  const float* Wd = (const float*)d_in[3];
  const float* Wpre = (const float*)d_in[4];
  const float* Wpost = (const float*)d_in[5];
  const float* ln_g = (const float*)d_in[6];
  const float* ln_b = (const float*)d_in[7];
  const float* Wap = (const float*)d_in[8];
  const float* Wea = (const float*)d_in[9];
  const float* ln_eg = (const float*)d_in[10];
  const float* ln_eb = (const float*)d_in[11];
  const float* Wep = (const float*)d_in[12];
  const float* Wop = (const float*)d_in[13];
  const float* Wgr = (const float*)d_in[14];
  const float* Wer = (const float*)d_in[15];
  float* out = (float*)d_out;

  char* ws = (char*)d_ws;
  size_t off = 0;
  auto alloc = [&](size_t bytes) { char* p = ws + off; off += (bytes + 255) & ~size_t(255); return p; };
  // Common allocations (~18.8 MB)
  float* lpart = (float*)alloc((size_t)(N / 4) * 12 * 4);
  float* wsum = (float*)alloc((size_t)N * 4);
  float* fwb = (float*)alloc((size_t)N * 2 * 4);
  int* eidx = (int*)alloc((size_t)N * 2 * 4);
  bf16_t* Mb2 = (bf16_t*)alloc((size_t)D * 256 * 2);   // [D,256] = [Mb | WdWap]
  float* Mp = (float*)alloc((size_t)8 * D * A * 4);    // split-K partials (reused)
  bf16_t* WepT = (bf16_t*)alloc((size_t)H * A * 2);
  bf16_t* WapT = (bf16_t*)alloc((size_t)H * A * 2);
  bf16_t* Wpre_b = (bf16_t*)alloc((size_t)A * D * 2);  // 256 KB plain-bf16
  bf16_t* Wpost_b = (bf16_t*)alloc((size_t)A * H * 2); // 512 KB plain-bf16
  bf16_t* hw2 = (bf16_t*)alloc((size_t)N * 256 * 2);   // [N,256] = [hw' | adpre']
  bf16_t* h0b = (bf16_t*)alloc((size_t)N * A * 2);
  bf16_t* aib = (bf16_t*)alloc((size_t)N * A * 2);
  bf16_t* scrA = (bf16_t*)alloc((size_t)N * A * 2);
  bf16_t* aob = (bf16_t*)alloc((size_t)N * A * 2);
  bf16_t* WeaT = (bf16_t*)alloc((size_t)E * A * A * 2);
  bf16_t* aopre = scrA;
  bf16_t* aiT = scrA;

  // Big path: pre-split TILED hi/lo buffers (+120 MiB; total ~138.3 MiB).
  const bool big = ws_size >= ((size_t)140 << 20);
  float* hiddenF = nullptr;
  bf16_t *xh = nullptr, *xl = nullptr;
  bf16_t *Wgh = nullptr, *Wgl = nullptr, *Wuh = nullptr, *Wul = nullptr;
  bf16_t *Wdh = nullptr, *Wdl = nullptr, *Hh = nullptr, *Hl = nullptr;
  if (big) {
    xh = (bf16_t*)alloc((size_t)N * D * 2);
    xl = (bf16_t*)alloc((size_t)N * D * 2);
    Wgh = (bf16_t*)alloc((size_t)H * D * 2);
    Wgl = (bf16_t*)alloc((size_t)H * D * 2);
    Wuh = (bf16_t*)alloc((size_t)H * D * 2);
    Wul = (bf16_t*)alloc((size_t)H * D * 2);
    Wdh = (bf16_t*)alloc((size_t)D * H * 2);
    Wdl = (bf16_t*)alloc((size_t)D * H * 2);
    Hh = (bf16_t*)alloc((size_t)N * H * 2);
    Hl = (bf16_t*)alloc((size_t)N * H * 2);
  } else {
    hiddenF = (float*)alloc((size_t)N * H * 4);
  }
  (void)ws_size; (void)in_sizes; (void)n_in; (void)out_size;

  const dim3 blk(256);

  router_kernel<<<dim3(N / 4), blk, 0, stream>>>(x, Wgr, Wer, eidx, fwb, wsum, lpart);
  transpose2d<<<dim3(A / 32, A / 32, E), blk, 0, stream>>>(Wea, WeaT, A, A, 1);

  if (big) {
    // tiled splits: x TR=128 K=D; Wg+Wu merged TR=64 K=D; Wd TR=128 K=H
    split_tiled<7, 5><<<dim3(2048), blk, 0, stream>>>(x, xh, xl, (long)N * D / 8, D);
    split_tiled2<6, 5><<<dim3(512, 1, 2), blk, 0, stream>>>(
        Wg, Wgh, Wgl, Wu, Wuh, Wul, (long)H * D / 8, D);
    split_tiled<7, 6><<<dim3(512), blk, 0, stream>>>(Wd, Wdh, Wdl, (long)D * H / 8, H);
    // Wpre/Wpost plain bf16 (same rounding as ld8f -> bit-identical GEMMs)
    cvt_bf16_2<<<dim3(192), blk, 0, stream>>>(
        Wpre, Wpre_b, (long)A * D / 8, Wpost, Wpost_b, (long)A * H / 8);
    // hidden0 (tiled Hh/Hl) = silu(x@Wg^T)*(x@Wu^T)
    gemm_gu_g<<<dim3(H / 64, N / 128), blk, 0, stream>>>(
        xh, xl, Wgh, Wgl, Wuh, Wul, Hh, Hl);
    // h0 = x@Wpre^T  (A tiled, B plain bf16)
    gemm_nt_b<16, 32, 0><<<dim3(A / 64, N / 32), blk, 0, stream>>>(
        xh, Wpre_b, h0b, N, A, D, nullptr, 2, 0);
    ln_rows<<<dim3(N / 4), blk, 0, stream>>>(h0b, ln_g, ln_b, aib);
    // ao_pre = hidden0@Wpost^T
    gemm_nt_b<16, 32, 0><<<dim3(A / 64, N / 32), blk, 0, stream>>>(
        Hh, Wpost_b, aopre, N, A, H, nullptr, 2, 0);
    ln_rows<<<dim3(N / 4), blk, 0, stream>>>(aopre, ln_g, ln_b, aob);
    transpose2d<<<dim3(A / 32, S / 32, Bb), blk, 0, stream>>>(aib, aiT, S, A, 0);
    // Mb2 = [Wop@Wep | Wd@Wap]
    transpose2d_pair<<<dim3(A / 32, H / 32, 2), blk, 0, stream>>>(
        Wep, WepT, Wap, WapT, H, A);
    gemm_mb_splitk<<<dim3(A / 64, D / 64, 8), blk, 0, stream>>>(Wop, WepT, Mp, D, A, H);
    mb_combine<<<dim3((D * A + 255) / 256), blk, 0, stream>>>(Mp, Mb2, D * A, 256, 0);
    gemm_mb_splitk<<<dim3(A / 64, D / 64, 8), blk, 0, stream>>>(Wd, WapT, Mp, D, A, H);
    mb_combine<<<dim3((D * A + 255) / 256), blk, 0, stream>>>(Mp, Mb2, D * A, 256, 128);
    // hw2 = [0.1/wsum * hw | 0.1 * adpre]
    fused_adapt<<<dim3(S / 32, Bb), blk, 0, stream>>>(
        aib, aob, aiT, hw2, 256, 128, 0.1f);
    expert_adapt<<<dim3(N), dim3(128), 0, stream>>>(
        h0b, WeaT, ln_eg, ln_eb, eidx, fwb, hw2, 256, wsum);
    // out = wsum * (hidden0@Wd^T + hw2'@Mb2^T)  (concat folded into dn)
    gemm_dn_g<<<dim3(D / 128, N / 128), blk, 0, stream>>>(
        Hh, Hl, Wdh, Wdl, hw2, Mb2, wsum, out);
  } else {
    bf16_t* adpreb = hw2 + (size_t)N * A;  // second half of hw2 as [N,A]
    gemm_gu_hl<<<dim3(H / 64, N / 128), blk, 0, stream>>>(x, Wg, Wu, hiddenF, N, H, D);
    gemm_nt_b<16, 32, 0><<<dim3(A / 64, N / 32), blk, 0, stream>>>(
        x, Wpre, h0b, N, A, D, nullptr, 1, 1);
    ln_rows<<<dim3(N / 4), blk, 0, stream>>>(h0b, ln_g, ln_b, aib);
    gemm_nt_b<16, 32, 0><<<dim3(A / 64, N / 32), blk, 0, stream>>>(
        hiddenF, Wpost, aopre, N, A, H, nullptr, 1, 1);
    ln_rows<<<dim3(N / 4), blk, 0, stream>>>(aopre, ln_g, ln_b, aob);
    transpose2d<<<dim3(A / 32, S / 32, Bb), blk, 0, stream>>>(aib, aiT, S, A, 0);
    fused_adapt<<<dim3(S / 32, Bb), blk, 0, stream>>>(
        aib, aob, aiT, adpreb, 128, 0, 1.f);
    gemm_nt_b<64, 64, 2><<<dim3(H / 128, N / 128), blk, 0, stream>>>(
        adpreb, Wap, hiddenF, N, H, A, nullptr, 0, 1);
    gemm_dn_hl<<<dim3(D / 128, N / 128), blk, 0, stream>>>(hiddenF, Wd, out, N, D, H);
    transpose2d<<<dim3(A / 32, H / 32, 1), blk, 0, stream>>>(Wep, WepT, H, A, 1);
    gemm_mb_splitk<<<dim3(A / 64, D / 64, 8), blk, 0, stream>>>(Wop, WepT, Mp, D, A, H);
    mb_combine<<<dim3((D * A + 255) / 256), blk, 0, stream>>>(Mp, Mb2, D * A, 128, 0);
    expert_adapt<<<dim3(N), dim3(128), 0, stream>>>(
        h0b, WeaT, ln_eg, ln_eb, eidx, fwb, hw2, 128, nullptr);
    gemm_nt_b<64, 64, 3><<<dim3(D / 128, N / 128), blk, 0, stream>>>(
        hw2, Mb2, out, N, D, A, wsum, 0, 0);
  }

  finalize_loss<<<dim3(1), blk, 0, stream>>>(lpart, N / 4, out + (size_t)N * D);
}